// Round 11
// baseline (2672.337 us; speedup 1.0000x reference)
//
#include <hip/hip_runtime.h>
#include <hip/hip_cooperative_groups.h>
#include <hip/hip_bf16.h>

typedef unsigned short u16;
typedef unsigned int u32;
typedef unsigned long long u64;

#define NN 8192
#define PXC 2560
#define MAXD 36
#define GY 64
#define GYM 32

typedef __attribute__((ext_vector_type(8))) short bf16x8;
typedef __attribute__((ext_vector_type(4))) float f32x4;

// ---------------- workspace layout (bytes) ----------------
static constexpr size_t SZ_PX  = (size_t)(NN + 1) * PXC * 2;
static constexpr size_t SZ_ACC = (size_t)(NN + 1) * 512 * 4;
static constexpr size_t SZ_HB  = (size_t)(NN + 1) * 512 * 2;
static constexpr size_t SZ_G   = (size_t)(NN + 1) * 1536 * 4;
static constexpr size_t SZ_NW  = (size_t)5242880 * 2;

static constexpr size_t OFF_PX    = 0;
static constexpr size_t OFF_QX    = OFF_PX + SZ_PX;
static constexpr size_t OFF_ACCH  = OFF_QX + SZ_PX;
static constexpr size_t OFF_ACCF  = OFF_ACCH + SZ_ACC;
static constexpr size_t OFF_ACCZ  = OFF_ACCF + SZ_ACC;
static constexpr size_t OFF_C     = OFF_ACCZ + SZ_ACC;         // c_all (chain), f32
static constexpr size_t OFF_HB    = OFF_C + SZ_ACC;            // h_all (chain), bf16
static constexpr size_t OFF_ZB    = OFF_HB + SZ_HB;            // chain ZB, bf16 (fallback path only)
static constexpr size_t OFF_G     = OFF_ZB + SZ_HB;            // per-node scratch / transient normalized inputs
static constexpr size_t OFF_NW    = OFF_G + SZ_G;
static constexpr size_t OFF_DEPTH = OFF_NW + SZ_NW;
static constexpr size_t OFF_ORDER = OFF_DEPTH + (size_t)NN * 4;
static constexpr size_t OFF_MISC  = OFF_ORDER + (size_t)NN * 4;
static constexpr size_t OFF_LVL   = OFF_MISC + 1024;
static constexpr size_t OFF_NB    = OFF_LVL + 512;
static constexpr size_t OFF_PN    = OFF_NB + 20480;
static constexpr size_t OFF_PMAX  = OFF_PN + (size_t)NN * 4;
static constexpr size_t OFF_BAR   = OFF_PMAX + (size_t)128 * 512 * 4;
static constexpr size_t WS_TOTAL  = OFF_BAR + 32768;

#define NW_CSWX  0
#define NW_CHWX  1310720
#define NW_CSWIO 2621440
#define NW_CSWFZ 3145728
#define NW_CSWUM 3670016
#define NW_CHWH  3932160
#define NW_CHWUM 4980736

#define NB_CSBX  0
#define NB_CSBIO 2560
#define NB_CSBFZ 3584
#define NB_CSBUM 4608
#define NB_CHBX  5120
#define NB_CHBH  7680
#define NB_CHBUM 9728

// ---------------- helpers ----------------
__device__ __forceinline__ float bfu(u16 u) { return __uint_as_float(((u32)u) << 16); }
__device__ __forceinline__ u16 f2bf(float f) {
    u32 u = __float_as_uint(f);
    u += 0x7fffu + ((u >> 16) & 1u);
    return (u16)(u >> 16);
}
__device__ __forceinline__ float sigf(float x) {
    x = fminf(fmaxf(x, -30.f), 30.f);
    return 1.f / (1.f + __expf(-x));
}
__device__ __forceinline__ float tanhq(float x) {
    x = fminf(fmaxf(x, -15.f), 15.f);
    return 1.f - 2.f / (__expf(2.f * x) + 1.f);
}
__device__ __forceinline__ bf16x8 cvt8(const float* p) {
    float4 a = *(const float4*)p;
    float4 b = *(const float4*)(p + 4);
    union { u32 u[4]; bf16x8 v; } r;
    r.u[0] = ((__float_as_uint(a.x) + 0x8000u) >> 16) | ((__float_as_uint(a.y) + 0x8000u) & 0xffff0000u);
    r.u[1] = ((__float_as_uint(a.z) + 0x8000u) >> 16) | ((__float_as_uint(a.w) + 0x8000u) & 0xffff0000u);
    r.u[2] = ((__float_as_uint(b.x) + 0x8000u) >> 16) | ((__float_as_uint(b.y) + 0x8000u) & 0xffff0000u);
    r.u[3] = ((__float_as_uint(b.z) + 0x8000u) >> 16) | ((__float_as_uint(b.w) + 0x8000u) & 0xffff0000u);
    return r.v;
}

// -------- agent-scope (XCD-coherent) accessors for mutable state --------
__device__ __forceinline__ u64 cld64(const void* p) {
    return __hip_atomic_load((const u64*)p, __ATOMIC_RELAXED, __HIP_MEMORY_SCOPE_AGENT);
}
__device__ __forceinline__ float cldf(const float* p) {
    return __hip_atomic_load(p, __ATOMIC_RELAXED, __HIP_MEMORY_SCOPE_AGENT);
}
__device__ __forceinline__ void cstf(float* p, float v) {
    __hip_atomic_store(p, v, __ATOMIC_RELAXED, __HIP_MEMORY_SCOPE_AGENT);
}
__device__ __forceinline__ void cst16(u16* p, u16 v) {
    __hip_atomic_store(p, v, __ATOMIC_RELAXED, __HIP_MEMORY_SCOPE_AGENT);
}
__device__ __forceinline__ bf16x8 cvt8a(const float* p) {  // 32B f32 coherent load -> bf16x8
    union { u64 u; u32 w[2]; } a, b, c, d;
    a.u = cld64(p); b.u = cld64(p + 2); c.u = cld64(p + 4); d.u = cld64(p + 6);
    union { u32 u[4]; bf16x8 v; } r;
    r.u[0] = ((a.w[0] + 0x8000u) >> 16) | ((a.w[1] + 0x8000u) & 0xffff0000u);
    r.u[1] = ((b.w[0] + 0x8000u) >> 16) | ((b.w[1] + 0x8000u) & 0xffff0000u);
    r.u[2] = ((c.w[0] + 0x8000u) >> 16) | ((c.w[1] + 0x8000u) & 0xffff0000u);
    r.u[3] = ((d.w[0] + 0x8000u) >> 16) | ((d.w[1] + 0x8000u) & 0xffff0000u);
    return r.v;
}

// ---- contention-free GRID barrier (256 blocks), monotonic flags (round-10 verified) ----
__device__ __forceinline__ void grid_bar(u32* B, int bid, u32 tgt) {
    __syncthreads();                       // all waves drain their stores here
    int tid = threadIdx.x;
    if (tid == 0)
        __hip_atomic_store(B + 16 + bid * 16, tgt, __ATOMIC_RELAXED, __HIP_MEMORY_SCOPE_AGENT);
    if (blockIdx.x == 0) {
        if (tid < 256) {
            while (__hip_atomic_load(B + 16 + tid * 16, __ATOMIC_RELAXED, __HIP_MEMORY_SCOPE_AGENT) < tgt)
                __builtin_amdgcn_s_sleep(2);
        }
        __syncthreads();
        if (tid == 0)
            __hip_atomic_store(B, tgt, __ATOMIC_RELAXED, __HIP_MEMORY_SCOPE_AGENT);
    }
    if (tid == 0) {
        while (__hip_atomic_load(B, __ATOMIC_RELAXED, __HIP_MEMORY_SCOPE_AGENT) < tgt)
            __builtin_amdgcn_s_sleep(2);
        asm volatile("" ::: "memory");
    }
    __syncthreads();
}

// ---------------- dtype detection (+ barrier zeroing) ----------------
__global__ void k_detect(const u32* __restrict__ fin, const u32* __restrict__ pin,
                         int* __restrict__ fcnt, int* __restrict__ pcnt,
                         u32* __restrict__ barz) {
    int i = blockIdx.x * 256 + threadIdx.x;
    if (i < 8192) barz[i] = 0u;
    if (i < 4096) {
        u32 w = fin[i];
        int e = (w >> 7) & 0xFF;
        if (w != 0u && e >= 0x70 && e <= 0x8F) atomicAdd(fcnt, 1);
    }
    if (i >= 1 && i < 4096) {
        if (pin[2 * i - 1] != 0u) atomicAdd(pcnt, 1);
    }
}

// fused: parent normalize + depth chase + sentinel-row init
__global__ void k_pnorm_depth(const u32* __restrict__ pin, const int* __restrict__ pcnt,
                              int* __restrict__ pnorm, int* __restrict__ depth,
                              u16* __restrict__ HB, float* __restrict__ Call) {
    int i = blockIdx.x * 256 + threadIdx.x;
    if (i < 512) {
        HB[(size_t)NN * 512 + i] = 0;
        Call[(size_t)NN * 512 + i] = 0.f;
    }
    if (i >= NN) return;
    bool is64 = (*pcnt < 100);
    int p = (int)(is64 ? pin[2 * i] : pin[i]);
    pnorm[i] = p;
    int d = 0;
    while (p != NN && p >= 0 && p < NN && d < 9000) {
        d++;
        p = (int)(is64 ? pin[2 * p] : pin[p]);
    }
    depth[i] = d;
}

// fused hist + scan + scatter, single block; also computes D* -> lvl[80]
__global__ __launch_bounds__(1024) void k_levels(const int* __restrict__ depth,
                                                 int* __restrict__ lvl, int* __restrict__ order) {
    __shared__ int cnts[64];
    __shared__ int cur[64];
    int t = threadIdx.x;
    if (t < 64) cnts[t] = 0;
    __syncthreads();
    for (int i = t; i < NN; i += 1024) {
        int d = depth[i]; if (d > 63) d = 63;
        atomicAdd(&cnts[d], 1);
    }
    __syncthreads();
    if (t == 0) {
        int s = 0; lvl[0] = 0;
        for (int d = 0; d < 64; ++d) { cur[d] = s; s += cnts[d]; lvl[d + 1] = s; }
        int D = 1;
        for (int d = 63; d >= 0; --d) if (cnts[d] > 0) { D = d + 1; break; }
        lvl[80] = D;                        // number of nonempty levels
    }
    __syncthreads();
    for (int i = t; i < NN; i += 1024) {
        int d = depth[i]; if (d > 63) d = 63;
        int pos = atomicAdd(&cur[d], 1);
        order[pos] = i;
    }
}

struct NormSrcs { const void* p[15]; };
__global__ __launch_bounds__(256) void k_norm_all(NormSrcs s, u16* __restrict__ NGI,
                                                  u16* __restrict__ NW, u16* __restrict__ NB,
                                                  const int* __restrict__ fcnt) {
    const int cum[16] = {0, 1048576, 1376256, 1703936, 1835008, 1966080, 2031616, 2293760,
                         2359296, 2359936, 2360192, 2360448, 2360576, 2361216, 2361728, 2361856};
    const int dof[15] = {0, NW_CSWX / 4, NW_CHWX / 4, NW_CSWIO / 4, NW_CSWFZ / 4, NW_CSWUM / 4,
                         NW_CHWH / 4, NW_CHWUM / 4, NB_CSBX / 4, NB_CSBIO / 4, NB_CSBFZ / 4,
                         NB_CSBUM / 4, NB_CHBX / 4, NB_CHBH / 4, NB_CHBUM / 4};
    bool isbf = (*fcnt > 2048);
    int total = 2361856;
    int istart = isbf ? cum[8] : 0;
    for (int i = istart + blockIdx.x * 256 + threadIdx.x; i < total; i += gridDim.x * 256) {
        int seg = 0;
#pragma unroll
        for (int k = 1; k < 15; ++k) if (i >= cum[k]) seg = k;
        int off = i - cum[seg];
        u16* dbase = (seg == 0) ? NGI : (seg < 8 ? NW : NB);
        ushort4* dst = (ushort4*)dbase + dof[seg] + off;
        if (isbf) {
            *dst = ((const ushort4*)s.p[seg])[off];
        } else {
            float4 v = ((const float4*)s.p[seg])[off];
            ushort4 o; o.x = f2bf(v.x); o.y = f2bf(v.y); o.z = f2bf(v.z); o.w = f2bf(v.w);
            *dst = o;
        }
    }
}

// ---------------- input-projection GEMM ----------------
#define ASTR 528
__global__ __launch_bounds__(256) void k_gemm_in(
    const u16* __restrict__ Ao, const u16* __restrict__ An,
    const u16* __restrict__ Wcs_o, const u16* __restrict__ Wcs_n,
    const u16* __restrict__ Wch_o, const u16* __restrict__ Wch_n,
    const u16* __restrict__ bcs, const u16* __restrict__ bch,
    u16* __restrict__ Ccs, u16* __restrict__ Cch,
    const int* __restrict__ fcnt)
{
    __shared__ __align__(16) u16 AS[64 * ASTR];
    bool isbf = (*fcnt > 2048);
    int z = blockIdx.z;
    const u16* A = isbf ? Ao : An;
    const u16* W = z ? (isbf ? Wch_o : Wch_n) : (isbf ? Wcs_o : Wcs_n);
    const u16* bias = z ? bch : bcs;
    u16* C = z ? Cch : Ccs;

    int m0 = blockIdx.y * 64;
    for (int e = threadIdx.x; e < 64 * 64; e += 256) {
        int row = e >> 6, c8 = e & 63;
        *(uint4*)&AS[row * ASTR + c8 * 8] = *(const uint4*)(A + (size_t)(m0 + row) * 512 + c8 * 8);
    }
    __syncthreads();

    int wv = threadIdx.x >> 6;
    int lane = threadIdx.x & 63;
    int r = lane & 15, q = lane >> 4;
    int n0 = blockIdx.x * 256 + wv * 64;
    const u16* pb[4];
#pragma unroll
    for (int jt = 0; jt < 4; ++jt) pb[jt] = W + (size_t)(n0 + jt * 16 + r) * 512 + q * 8;
    f32x4 acc[4][4] = {};
#pragma unroll 2
    for (int k0 = 0; k0 < 512; k0 += 32) {
        bf16x8 a[4], b[4];
#pragma unroll
        for (int mi = 0; mi < 4; ++mi)
            a[mi] = *(const bf16x8*)&AS[(mi * 16 + r) * ASTR + k0 + q * 8];
#pragma unroll
        for (int jt = 0; jt < 4; ++jt) b[jt] = *(const bf16x8*)(pb[jt] + k0);
#pragma unroll
        for (int mi = 0; mi < 4; ++mi)
#pragma unroll
            for (int jt = 0; jt < 4; ++jt)
                acc[mi][jt] = __builtin_amdgcn_mfma_f32_16x16x32_bf16(a[mi], b[jt], acc[mi][jt], 0, 0, 0);
    }
#pragma unroll
    for (int jt = 0; jt < 4; ++jt) {
        int c = n0 + jt * 16 + r;
        float bv = bfu(bias[c]);
#pragma unroll
        for (int mi = 0; mi < 4; ++mi) {
            size_t b0 = (size_t)(m0 + mi * 16 + q * 4) * PXC + c;
#pragma unroll
            for (int i = 0; i < 4; ++i)
                C[b0 + (size_t)i * PXC] = f2bf(acc[mi][jt][i] + bv);
        }
    }
}

// ================= persistent level loop: full-tile s1 per block (redundant compute),
// NO sibling exchange — h/ZT live in block-local LDS =================
// bid: z=bid&1 plane, cgi=(bid>>1)&3 owned col slice, ty=bid>>3 (0..31).
// s1 computes ALL 512 cols (4 fragments/wave, frag f = cols w*16+f*128+r);
// h (cs) / zt (ch) written straight into swizzled LDS; __syncthreads; s2 runs on the
// block's own 128-col slice (fragment f==cgi owns the atomics / outputs).
// ONE grid barrier per level; mini-barrier and Gh/ZB global round-trips eliminated.
__global__ __launch_bounds__(512) void comb_mega7(
    const int* __restrict__ order, const int* __restrict__ lvl, const int* __restrict__ parent,
    float* __restrict__ acc_h, float* __restrict__ acc_fc, float* __restrict__ acc_zc,
    const u16* __restrict__ Wio_o, const u16* __restrict__ Wio_n,
    const u16* __restrict__ Wum_o, const u16* __restrict__ Wum_n,
    const u16* __restrict__ Wfz_o, const u16* __restrict__ Wfz_n,
    const u16* __restrict__ bio, const u16* __restrict__ bum, const u16* __restrict__ bfz,
    const u16* __restrict__ px,
    u16* __restrict__ HB, float* __restrict__ Call,
    const u16* __restrict__ Wh_o, const u16* __restrict__ Wh_n,
    const u16* __restrict__ Wu2_o, const u16* __restrict__ Wu2_n,
    const u16* __restrict__ bh, const u16* __restrict__ bu2,
    const u16* __restrict__ qx, u16* __restrict__ ZB,
    float* __restrict__ G,
    void* __restrict__ outv, const int* __restrict__ fcnt,
    u32* __restrict__ BAR)
{
    __shared__ __align__(16) u16 LS[24576];   // 48KB: AH@0, AZ@16K, HT/ZT@32K(cs)/16K(ch)
    __shared__ int ndl[16], pl[16];
    bool isbf = (*fcnt > 2048);
    int tid = threadIdx.x;
    int w = tid >> 6, lane = tid & 63;
    int r = lane & 15, q = lane >> 4;
    int rsw = (r & 7) << 4;
    int bid = blockIdx.x;
    int z = bid & 1;
    int cgi = (bid >> 1) & 3;
    int ty = bid >> 3;                        // 0..31
    int colw = w * 16 + r;                    // fragment-0 column
    int col = colw + cgi * 128;               // owned column (s2, atomics, outputs)
    char* LB = (char*)LS;
    int Dmax = lvl[80];
    u32 tgt = 0;

    // hoisted plane invariants: s1 fragment-base weight ptrs (frag f = + f*65536 u16),
    // per-fragment biases, s2 own-col ptrs/biases.
    const u16 *p1a, *p1b, *p1c, *p1d;
    const u16 *p2a, *p2b;
    float b1a[4], b1b[4], b1c[4], b1d[4];
    float bd, be;
    if (z == 0) {
        const u16* Wio = isbf ? Wio_o : Wio_n;
        const u16* Wum = isbf ? Wum_o : Wum_n;
        const u16* Wfz = isbf ? Wfz_o : Wfz_n;
        p1a = Wio + (size_t)colw * 512 + q * 8;            // i
        p1b = Wio + (size_t)(512 + colw) * 512 + q * 8;    // o
        p1c = Wum + (size_t)colw * 512 + q * 8;            // u
        p1d = p1c;
        p2a = Wfz + (size_t)col * 512 + q * 8;             // f (own col)
        p2b = Wfz + (size_t)(512 + col) * 512 + q * 8;     // z (own col)
#pragma unroll
        for (int f = 0; f < 4; ++f) {
            int cf = colw + f * 128;
            b1a[f] = bfu(bio[cf]); b1b[f] = bfu(bio[512 + cf]); b1c[f] = bfu(bum[cf]);
            b1d[f] = 0.f;
        }
        bd = bfu(bfz[col]); be = bfu(bfz[512 + col]);
    } else {
        const u16* Wh = isbf ? Wh_o : Wh_n;
        const u16* Wu = isbf ? Wu2_o : Wu2_n;
        p1a = Wh + (size_t)colw * 512 + q * 8;             // i
        p1b = Wh + (size_t)(512 + colw) * 512 + q * 8;     // o
        p1c = Wh + (size_t)(1024 + colw) * 512 + q * 8;    // f
        p1d = Wh + (size_t)(1536 + colw) * 512 + q * 8;    // z
        p2a = Wu + (size_t)col * 512 + q * 8;              // u (own col)
        p2b = p2a;
#pragma unroll
        for (int f = 0; f < 4; ++f) {
            int cf = colw + f * 128;
            b1a[f] = bfu(bh[cf]); b1b[f] = bfu(bh[512 + cf]);
            b1c[f] = bfu(bh[1024 + cf]); b1d[f] = bfu(bh[1536 + cf]);
        }
        bd = 0.f; be = bfu(bu2[col]);
    }

    for (int it = 0; it < Dmax; ++it) {
        int d = z ? it : (Dmax - 1 - it);
        int start = lvl[d], cnt = lvl[d + 1] - start;
        int ntiles = (cnt + 15) >> 4;

        for (int tile = ty; tile < ntiles; tile += GYM) {
            __syncthreads();
            if (tid < 16) {
                int tr = tile * 16 + tid;
                int nd = (tr < cnt) ? order[start + tr] : -1;
                ndl[tid] = nd;
                pl[tid] = (nd >= 0) ? parent[nd] : NN;
            }
            __syncthreads();

            if (z == 0) {
                // ---------- cs s1 (ALL cols): stage AH/AZ, gates i,o,u -> c(own regs), h->LDS HT ----------
                for (int e = tid; e < 1024; e += 512) {
                    int slot = e >> 6, c8 = e & 63;
                    int nd = ndl[slot]; int nn = (nd < 0) ? NN : nd;
                    int boff = slot * 1024 + ((c8 * 16) ^ ((slot & 7) << 4));
                    *(bf16x8*)(LB + boff) = cvt8a(acc_h + (size_t)nn * 512 + c8 * 8);
                    *(bf16x8*)(LB + 16384 + boff) = cvt8a(acc_zc + (size_t)nn * 512 + c8 * 8);
                }
                __syncthreads();
                f32x4 ai[4] = {}, ao[4] = {}, au[4] = {};
#pragma unroll 2
                for (int ko = 0; ko < 512; ko += 32) {
                    int abo = ((ko + q * 8) * 2) ^ rsw;
                    bf16x8 ah = *(const bf16x8*)(LB + r * 1024 + abo);
                    bf16x8 az = *(const bf16x8*)(LB + 16384 + r * 1024 + abo);
#pragma unroll
                    for (int f = 0; f < 4; ++f) {
                        ai[f] = __builtin_amdgcn_mfma_f32_16x16x32_bf16(ah, *(const bf16x8*)(p1a + f * 65536 + ko), ai[f], 0, 0, 0);
                        ao[f] = __builtin_amdgcn_mfma_f32_16x16x32_bf16(ah, *(const bf16x8*)(p1b + f * 65536 + ko), ao[f], 0, 0, 0);
                        au[f] = __builtin_amdgcn_mfma_f32_16x16x32_bf16(az, *(const bf16x8*)(p1c + f * 65536 + ko), au[f], 0, 0, 0);
                    }
                }
                float ccv[4];
#pragma unroll
                for (int i2 = 0; i2 < 4; ++i2) {
                    int slot = q * 4 + i2;
                    int ni = ndl[slot];
                    ccv[i2] = 0.f;
                    if (ni < 0) continue;
                    int p = pl[slot];
                    size_t pxb = (size_t)ni * PXC, nb = (size_t)ni * 512;
#pragma unroll
                    for (int f = 0; f < 4; ++f) {
                        int cf = colw + f * 128;
                        float ig = sigf(bfu(px[pxb + cf]) + ai[f][i2] + b1a[f]);
                        float og = sigf(bfu(px[pxb + 1024 + cf]) + ao[f][i2] + b1b[f]);
                        float uu = tanhq(bfu(px[pxb + 2048 + cf]) + au[f][i2] + b1c[f]);
                        float cc = ig * uu + cldf(acc_fc + nb + cf);
                        float h = og * tanhq(cc);
                        *(u16*)(LB + 32768 + slot * 1024 + ((cf * 2) ^ ((slot & 7) << 4))) = f2bf(h);
                        if (f == cgi) {
                            ccv[i2] = cc;
                            atomicAdd(&acc_h[(size_t)p * 512 + cf], h);
                            if (ni == 0) {
                                if (isbf) ((u16*)outv)[cf] = f2bf(h);
                                else ((float*)outv)[cf] = h;
                            }
                        }
                    }
                }
                __syncthreads();            // HT complete block-wide
                // ---------- cs s2 (own slice): f,z gates from LDS HT -> scatter ----------
                f32x4 af0 = {}, af1 = {}, az0 = {}, az1 = {};
#pragma unroll 4
                for (int ko = 0; ko < 256; ko += 32) {
                    int ab0 = ((ko + q * 8) * 2) ^ rsw;
                    int ab1 = ((ko + 256 + q * 8) * 2) ^ rsw;
                    bf16x8 h0 = *(const bf16x8*)(LB + 32768 + r * 1024 + ab0);
                    bf16x8 h1 = *(const bf16x8*)(LB + 32768 + r * 1024 + ab1);
                    af0 = __builtin_amdgcn_mfma_f32_16x16x32_bf16(h0, *(const bf16x8*)(p2a + ko), af0, 0, 0, 0);
                    az0 = __builtin_amdgcn_mfma_f32_16x16x32_bf16(h0, *(const bf16x8*)(p2b + ko), az0, 0, 0, 0);
                    af1 = __builtin_amdgcn_mfma_f32_16x16x32_bf16(h1, *(const bf16x8*)(p2a + 256 + ko), af1, 0, 0, 0);
                    az1 = __builtin_amdgcn_mfma_f32_16x16x32_bf16(h1, *(const bf16x8*)(p2b + 256 + ko), az1, 0, 0, 0);
                }
                f32x4 af = af0 + af1, az = az0 + az1;
#pragma unroll
                for (int i2 = 0; i2 < 4; ++i2) {
                    int slot = q * 4 + i2;
                    int ni = ndl[slot];
                    if (ni < 0) continue;
                    int p = pl[slot];
                    size_t pb = (size_t)p * 512, ppx = (size_t)p * PXC;
                    float cT = ccv[i2];
                    float f = sigf(bfu(px[ppx + 512 + col]) + af[i2] + bd);
                    atomicAdd(&acc_fc[pb + col], f * cT);
                    float zf = sigf(bfu(px[ppx + 1536 + col]) + az[i2] + be);
                    atomicAdd(&acc_zc[pb + col], zf * tanhq(cT));
                }
            } else {
                // ---------- ch s1 (ALL cols): stage AP=HB[parent], gates i,o,f,z; zt -> LDS ZT ----------
                for (int e = tid; e < 1024; e += 512) {
                    int slot = e >> 6, c8 = e & 63;
                    int boff = slot * 1024 + ((c8 * 16) ^ ((slot & 7) << 4));
                    *(bf16x8*)(LB + boff) = *(const bf16x8*)(HB + (size_t)pl[slot] * 512 + c8 * 8);
                }
                __syncthreads();
                f32x4 gi[4] = {}, go[4] = {}, gf[4] = {}, gz[4] = {};
#pragma unroll 2
                for (int ko = 0; ko < 512; ko += 32) {
                    int abo = ((ko + q * 8) * 2) ^ rsw;
                    bf16x8 a = *(const bf16x8*)(LB + r * 1024 + abo);
#pragma unroll
                    for (int f = 0; f < 4; ++f) {
                        gi[f] = __builtin_amdgcn_mfma_f32_16x16x32_bf16(a, *(const bf16x8*)(p1a + f * 65536 + ko), gi[f], 0, 0, 0);
                        go[f] = __builtin_amdgcn_mfma_f32_16x16x32_bf16(a, *(const bf16x8*)(p1b + f * 65536 + ko), go[f], 0, 0, 0);
                        gf[f] = __builtin_amdgcn_mfma_f32_16x16x32_bf16(a, *(const bf16x8*)(p1c + f * 65536 + ko), gf[f], 0, 0, 0);
                        gz[f] = __builtin_amdgcn_mfma_f32_16x16x32_bf16(a, *(const bf16x8*)(p1d + f * 65536 + ko), gz[f], 0, 0, 0);
                    }
                }
                float siR[4], soR[4], sfR[4], pcR[4];
#pragma unroll
                for (int i2 = 0; i2 < 4; ++i2) {
                    int slot = q * 4 + i2;
                    int ni = ndl[slot];
                    siR[i2] = 0.f; soR[i2] = 0.f; sfR[i2] = 0.f; pcR[i2] = 0.f;
                    if (ni < 0) continue;
                    int p = pl[slot];
                    size_t qb = (size_t)ni * PXC;
#pragma unroll
                    for (int f = 0; f < 4; ++f) {
                        int cf = colw + f * 128;
                        float zg = sigf(bfu(qx[qb + 1536 + cf]) + gz[f][i2] + b1d[f]);
                        float pc = Call[(size_t)p * 512 + cf];   // write-once + reuse: plain
                        *(u16*)(LB + 16384 + slot * 1024 + ((cf * 2) ^ ((slot & 7) << 4))) = f2bf(zg * tanhq(pc));
                        if (f == cgi) {
                            siR[i2] = sigf(bfu(qx[qb + cf]) + gi[f][i2] + b1a[f]);
                            soR[i2] = sigf(bfu(qx[qb + 512 + cf]) + go[f][i2] + b1b[f]);
                            sfR[i2] = sigf(bfu(qx[qb + 1024 + cf]) + gf[f][i2] + b1c[f]);
                            pcR[i2] = pc;
                        }
                    }
                }
                __syncthreads();            // ZT complete block-wide
                // ---------- ch s2 (own slice): u gate from LDS ZT -> c,h writeback ----------
                f32x4 a0 = {}, a1 = {}, a2 = {}, a3 = {};
#pragma unroll 4
                for (int ko = 0; ko < 128; ko += 32) {
                    int b0 = ((ko + q * 8) * 2) ^ rsw;
                    int b1 = ((ko + 128 + q * 8) * 2) ^ rsw;
                    int b2 = ((ko + 256 + q * 8) * 2) ^ rsw;
                    int b3 = ((ko + 384 + q * 8) * 2) ^ rsw;
                    a0 = __builtin_amdgcn_mfma_f32_16x16x32_bf16(*(const bf16x8*)(LB + 16384 + r * 1024 + b0),
                                                                 *(const bf16x8*)(p2a + ko), a0, 0, 0, 0);
                    a1 = __builtin_amdgcn_mfma_f32_16x16x32_bf16(*(const bf16x8*)(LB + 16384 + r * 1024 + b1),
                                                                 *(const bf16x8*)(p2a + 128 + ko), a1, 0, 0, 0);
                    a2 = __builtin_amdgcn_mfma_f32_16x16x32_bf16(*(const bf16x8*)(LB + 16384 + r * 1024 + b2),
                                                                 *(const bf16x8*)(p2a + 256 + ko), a2, 0, 0, 0);
                    a3 = __builtin_amdgcn_mfma_f32_16x16x32_bf16(*(const bf16x8*)(LB + 16384 + r * 1024 + b3),
                                                                 *(const bf16x8*)(p2a + 384 + ko), a3, 0, 0, 0);
                }
                f32x4 auv = (a0 + a1) + (a2 + a3);
#pragma unroll
                for (int i2 = 0; i2 < 4; ++i2) {
                    int slot = q * 4 + i2;
                    int ni = ndl[slot];
                    if (ni < 0) continue;
                    size_t qb = (size_t)ni * PXC, nb = (size_t)ni * 512;
                    float uu = tanhq(bfu(qx[qb + 2048 + col]) + auv[i2] + be);
                    float cc = siR[i2] * uu + sfR[i2] * pcR[i2];
                    float h = soR[i2] * tanhq(cc);
                    cstf(&Call[nb + col], cc);
                    cst16(&HB[nb + col], f2bf(h));
                }
            }
        }
        ++tgt; grid_bar(BAR, bid, tgt);
    }
}

// ---------------- fallback per-level kernels (round-3, verified) ----------------
__global__ __launch_bounds__(512) void comb_s1(
    int iter,
    const int* __restrict__ order, const int* __restrict__ lvl, const int* __restrict__ parent,
    float* acc_h, const float* __restrict__ acc_fc, const float* __restrict__ acc_zc,
    const u16* __restrict__ Wio_o, const u16* __restrict__ Wio_n,
    const u16* __restrict__ Wum_o, const u16* __restrict__ Wum_n,
    const u16* __restrict__ bio, const u16* __restrict__ bum,
    const u16* __restrict__ px,
    const u16* __restrict__ HB, const float* __restrict__ Call,
    const u16* __restrict__ Wh_o, const u16* __restrict__ Wh_n,
    const u16* __restrict__ bh,
    const u16* __restrict__ qx, u16* __restrict__ ZB,
    float* __restrict__ G,
    void* __restrict__ outv, const int* __restrict__ fcnt)
{
    __shared__ __align__(16) u16 LS[16384];
    __shared__ int ndl[16], pl[16];
    bool isbf = (*fcnt > 2048);
    int tid = threadIdx.x;
    int w = tid >> 6, lane = tid & 63;
    int r = lane & 15, q = lane >> 4;
    int rsw = (r & 7) << 4;
    int col = (blockIdx.x * 8 + w) * 16 + r;
    u16* Gh = (u16*)G;
    char* LB = (char*)LS;
    int Dmax = lvl[80];
    int d = blockIdx.z ? iter : (Dmax - 1 - iter);
    if (d < 0 || d >= Dmax) return;
    int start = lvl[d], cnt = lvl[d + 1] - start;
    if (cnt <= 0) return;
    int ntiles = (cnt + 15) >> 4;

    if (blockIdx.z == 0) {
        const u16* Wio = isbf ? Wio_o : Wio_n;
        const u16* Wum = isbf ? Wum_o : Wum_n;
        const u16* pbi = Wio + (size_t)col * 512 + q * 8;
        const u16* pbo = Wio + (size_t)(512 + col) * 512 + q * 8;
        const u16* pbu = Wum + (size_t)col * 512 + q * 8;
        for (int tile = blockIdx.y; tile < ntiles; tile += GY) {
            __syncthreads();
            if (tid < 16) {
                int tr = tile * 16 + tid;
                int nd = (tr < cnt) ? order[start + tr] : -1;
                ndl[tid] = nd;
                pl[tid] = (nd >= 0) ? parent[nd] : NN;
            }
            __syncthreads();
            for (int e = tid; e < 1024; e += 512) {
                int slot = e >> 6, c8 = e & 63;
                int nd = ndl[slot]; int nn = (nd < 0) ? NN : nd;
                int boff = slot * 1024 + ((c8 * 16) ^ ((slot & 7) << 4));
                *(bf16x8*)(LB + boff) = cvt8(acc_h + (size_t)nn * 512 + c8 * 8);
                *(bf16x8*)(LB + 16384 + boff) = cvt8(acc_zc + (size_t)nn * 512 + c8 * 8);
            }
            __syncthreads();
            f32x4 ai = {}, ao = {}, au = {};
#pragma unroll 4
            for (int ko = 0; ko < 512; ko += 32) {
                int abo = ((ko + q * 8) * 2) ^ rsw;
                bf16x8 ah = *(const bf16x8*)(LB + r * 1024 + abo);
                bf16x8 az = *(const bf16x8*)(LB + 16384 + r * 1024 + abo);
                ai = __builtin_amdgcn_mfma_f32_16x16x32_bf16(ah, *(const bf16x8*)(pbi + ko), ai, 0, 0, 0);
                ao = __builtin_amdgcn_mfma_f32_16x16x32_bf16(ah, *(const bf16x8*)(pbo + ko), ao, 0, 0, 0);
                au = __builtin_amdgcn_mfma_f32_16x16x32_bf16(az, *(const bf16x8*)(pbu + ko), au, 0, 0, 0);
            }
            float bi_ = bfu(bio[col]), bo_ = bfu(bio[512 + col]), bu_ = bfu(bum[col]);
#pragma unroll
            for (int i2 = 0; i2 < 4; ++i2) {
                int slot = q * 4 + i2;
                int ni = ndl[slot];
                if (ni < 0) continue;
                int p = pl[slot];
                size_t pxb = (size_t)ni * PXC, nb = (size_t)ni * 512;
                float ig = sigf(bfu(px[pxb + col]) + ai[i2] + bi_);
                float og = sigf(bfu(px[pxb + 1024 + col]) + ao[i2] + bo_);
                float uu = tanhq(bfu(px[pxb + 2048 + col]) + au[i2] + bu_);
                float cc = ig * uu + acc_fc[nb + col];
                float h = og * tanhq(cc);
                G[(size_t)ni * 1536 + col] = cc;
                Gh[(size_t)ni * 3072 + 1024 + col] = f2bf(h);
                atomicAdd(&acc_h[(size_t)p * 512 + col], h);
                if (ni == 0) {
                    if (isbf) ((u16*)outv)[col] = f2bf(h);
                    else ((float*)outv)[col] = h;
                }
            }
        }
    } else {
        const u16* Wh = isbf ? Wh_o : Wh_n;
        const u16* pbi = Wh + (size_t)col * 512 + q * 8;
        const u16* pbo = Wh + (size_t)(512 + col) * 512 + q * 8;
        const u16* pbf = Wh + (size_t)(1024 + col) * 512 + q * 8;
        const u16* pbz = Wh + (size_t)(1536 + col) * 512 + q * 8;
        for (int tile = blockIdx.y; tile < ntiles; tile += GY) {
            __syncthreads();
            if (tid < 16) {
                int tr = tile * 16 + tid;
                int nd = (tr < cnt) ? order[start + tr] : -1;
                ndl[tid] = nd;
                pl[tid] = (nd >= 0) ? parent[nd] : NN;
            }
            __syncthreads();
            for (int e = tid; e < 1024; e += 512) {
                int slot = e >> 6, c8 = e & 63;
                int boff = slot * 1024 + ((c8 * 16) ^ ((slot & 7) << 4));
                *(bf16x8*)(LB + boff) = *(const bf16x8*)(HB + (size_t)pl[slot] * 512 + c8 * 8);
            }
            __syncthreads();
            f32x4 gi = {}, go = {}, gf = {}, gz = {};
#pragma unroll 4
            for (int ko = 0; ko < 512; ko += 32) {
                int abo = ((ko + q * 8) * 2) ^ rsw;
                bf16x8 a = *(const bf16x8*)(LB + r * 1024 + abo);
                gi = __builtin_amdgcn_mfma_f32_16x16x32_bf16(a, *(const bf16x8*)(pbi + ko), gi, 0, 0, 0);
                go = __builtin_amdgcn_mfma_f32_16x16x32_bf16(a, *(const bf16x8*)(pbo + ko), go, 0, 0, 0);
                gf = __builtin_amdgcn_mfma_f32_16x16x32_bf16(a, *(const bf16x8*)(pbf + ko), gf, 0, 0, 0);
                gz = __builtin_amdgcn_mfma_f32_16x16x32_bf16(a, *(const bf16x8*)(pbz + ko), gz, 0, 0, 0);
            }
            float bi_ = bfu(bh[col]), bo_ = bfu(bh[512 + col]);
            float bf_ = bfu(bh[1024 + col]), bz_ = bfu(bh[1536 + col]);
#pragma unroll
            for (int i2 = 0; i2 < 4; ++i2) {
                int slot = q * 4 + i2;
                int ni = ndl[slot];
                if (ni < 0) continue;
                int p = pl[slot];
                size_t qb = (size_t)ni * PXC, gb = (size_t)ni * 1536, nb = (size_t)ni * 512;
                float si = sigf(bfu(qx[qb + col]) + gi[i2] + bi_);
                float so = sigf(bfu(qx[qb + 512 + col]) + go[i2] + bo_);
                float sf = sigf(bfu(qx[qb + 1024 + col]) + gf[i2] + bf_);
                float zg = sigf(bfu(qx[qb + 1536 + col]) + gz[i2] + bz_);
                G[gb + col] = si;
                G[gb + 512 + col] = so;
                G[gb + 1024 + col] = sf;
                ZB[nb + col] = f2bf(zg * tanhq(Call[(size_t)p * 512 + col]));
            }
        }
    }
}

__global__ __launch_bounds__(512) void comb_s2(
    int iter,
    const int* __restrict__ order, const int* __restrict__ lvl, const int* __restrict__ parent,
    const u16* __restrict__ Wfz_o, const u16* __restrict__ Wfz_n,
    const u16* __restrict__ bfz,
    const u16* __restrict__ px,
    float* __restrict__ acc_fc, float* __restrict__ acc_zc,
    const u16* __restrict__ ZB, const u16* __restrict__ qx,
    const u16* __restrict__ Wum_o, const u16* __restrict__ Wum_n,
    const u16* __restrict__ bum,
    float* __restrict__ Call, u16* __restrict__ HB,
    float* __restrict__ G, const int* __restrict__ fcnt)
{
    __shared__ __align__(16) u16 LS[8192];
    __shared__ int ndl[16], pl[16];
    bool isbf = (*fcnt > 2048);
    int tid = threadIdx.x;
    int w = tid >> 6, lane = tid & 63;
    int r = lane & 15, q = lane >> 4;
    int rsw = (r & 7) << 4;
    int col = (blockIdx.x * 8 + w) * 16 + r;
    const u16* Gh = (const u16*)G;
    char* LB = (char*)LS;
    int Dmax = lvl[80];
    int d = blockIdx.z ? iter : (Dmax - 1 - iter);
    if (d < 0 || d >= Dmax) return;
    int start = lvl[d], cnt = lvl[d + 1] - start;
    if (cnt <= 0) return;
    int ntiles = (cnt + 15) >> 4;

    if (blockIdx.z == 0) {
        const u16* Wfz = isbf ? Wfz_o : Wfz_n;
        const u16* pbf = Wfz + (size_t)col * 512 + q * 8;
        const u16* pbz = Wfz + (size_t)(512 + col) * 512 + q * 8;
        for (int tile = blockIdx.y; tile < ntiles; tile += GY) {
            __syncthreads();
            if (tid < 16) {
                int tr = tile * 16 + tid;
                int nd = (tr < cnt) ? order[start + tr] : -1;
                ndl[tid] = nd;
                pl[tid] = (nd >= 0) ? parent[nd] : NN;
            }
            __syncthreads();
            for (int e = tid; e < 1024; e += 512) {
                int slot = e >> 6, c8 = e & 63;
                int nd = ndl[slot]; int nn = (nd < 0) ? NN : nd;
                int boff = slot * 1024 + ((c8 * 16) ^ ((slot & 7) << 4));
                *(bf16x8*)(LB + boff) = *(const bf16x8*)(Gh + (size_t)nn * 3072 + 1024 + c8 * 8);
            }
            __syncthreads();
            f32x4 af0 = {}, af1 = {}, az0 = {}, az1 = {};
#pragma unroll 4
            for (int ko = 0; ko < 256; ko += 32) {
                int ab0 = ((ko + q * 8) * 2) ^ rsw;
                int ab1 = ((ko + 256 + q * 8) * 2) ^ rsw;
                bf16x8 h0 = *(const bf16x8*)(LB + r * 1024 + ab0);
                bf16x8 h1 = *(const bf16x8*)(LB + r * 1024 + ab1);
                af0 = __builtin_amdgcn_mfma_f32_16x16x32_bf16(h0, *(const bf16x8*)(pbf + ko), af0, 0, 0, 0);
                az0 = __builtin_amdgcn_mfma_f32_16x16x32_bf16(h0, *(const bf16x8*)(pbz + ko), az0, 0, 0, 0);
                af1 = __builtin_amdgcn_mfma_f32_16x16x32_bf16(h1, *(const bf16x8*)(pbf + 256 + ko), af1, 0, 0, 0);
                az1 = __builtin_amdgcn_mfma_f32_16x16x32_bf16(h1, *(const bf16x8*)(pbz + 256 + ko), az1, 0, 0, 0);
            }
            f32x4 af = af0 + af1, az = az0 + az1;
            float bf_ = bfu(bfz[col]), bz_ = bfu(bfz[512 + col]);
#pragma unroll
            for (int i2 = 0; i2 < 4; ++i2) {
                int slot = q * 4 + i2;
                int ni = ndl[slot];
                if (ni < 0) continue;
                int p = pl[slot];
                size_t pb = (size_t)p * 512, ppx = (size_t)p * PXC;
                float cT = G[(size_t)ni * 1536 + col];
                float f = sigf(bfu(px[ppx + 512 + col]) + af[i2] + bf_);
                atomicAdd(&acc_fc[pb + col], f * cT);
                float zf = sigf(bfu(px[ppx + 1536 + col]) + az[i2] + bz_);
                atomicAdd(&acc_zc[pb + col], zf * tanhq(cT));
            }
        }
    } else {
        const u16* Wum = isbf ? Wum_o : Wum_n;
        const u16* pbu = Wum + (size_t)col * 512 + q * 8;
        for (int tile = blockIdx.y; tile < ntiles; tile += GY) {
            __syncthreads();
            if (tid < 16) {
                int tr = tile * 16 + tid;
                int nd = (tr < cnt) ? order[start + tr] : -1;
                ndl[tid] = nd;
                pl[tid] = (nd >= 0) ? parent[nd] : NN;
            }
            __syncthreads();
            for (int e = tid; e < 1024; e += 512) {
                int slot = e >> 6, c8 = e & 63;
                int nd = ndl[slot]; int nn = (nd < 0) ? NN : nd;
                int boff = slot * 1024 + ((c8 * 16) ^ ((slot & 7) << 4));
                *(bf16x8*)(LB + boff) = *(const bf16x8*)(ZB + (size_t)nn * 512 + c8 * 8);
            }
            __syncthreads();
            f32x4 a0 = {}, a1 = {}, a2 = {}, a3 = {};
#pragma unroll 4
            for (int ko = 0; ko < 128; ko += 32) {
                int b0 = ((ko + q * 8) * 2) ^ rsw;
                int b1 = ((ko + 128 + q * 8) * 2) ^ rsw;
                int b2 = ((ko + 256 + q * 8) * 2) ^ rsw;
                int b3 = ((ko + 384 + q * 8) * 2) ^ rsw;
                a0 = __builtin_amdgcn_mfma_f32_16x16x32_bf16(*(const bf16x8*)(LB + r * 1024 + b0),
                                                             *(const bf16x8*)(pbu + ko), a0, 0, 0, 0);
                a1 = __builtin_amdgcn_mfma_f32_16x16x32_bf16(*(const bf16x8*)(LB + r * 1024 + b1),
                                                             *(const bf16x8*)(pbu + 128 + ko), a1, 0, 0, 0);
                a2 = __builtin_amdgcn_mfma_f32_16x16x32_bf16(*(const bf16x8*)(LB + r * 1024 + b2),
                                                             *(const bf16x8*)(pbu + 256 + ko), a2, 0, 0, 0);
                a3 = __builtin_amdgcn_mfma_f32_16x16x32_bf16(*(const bf16x8*)(LB + r * 1024 + b3),
                                                             *(const bf16x8*)(pbu + 384 + ko), a3, 0, 0, 0);
            }
            f32x4 au = (a0 + a1) + (a2 + a3);
            float bu_ = bfu(bum[col]);
#pragma unroll
            for (int i2 = 0; i2 < 4; ++i2) {
                int slot = q * 4 + i2;
                int ni = ndl[slot];
                if (ni < 0) continue;
                int p = pl[slot];
                size_t qb = (size_t)ni * PXC, gb = (size_t)ni * 1536, nb = (size_t)ni * 512;
                float uu = tanhq(bfu(qx[qb + 2048 + col]) + au[i2] + bu_);
                float si = G[gb + col];
                float so = G[gb + 512 + col];
                float sf = G[gb + 1024 + col];
                float pc = Call[(size_t)p * 512 + col];
                float cc = si * uu + sf * pc;
                float h = so * tanhq(cc);
                Call[nb + col] = cc;
                HB[nb + col] = f2bf(h);
            }
        }
    }
}

// ---------------- final max reduce ----------------
__global__ __launch_bounds__(256) void k_maxA(const u16* __restrict__ HB, float* __restrict__ pmax) {
    int b = blockIdx.x, t = threadIdx.x;
    float m1 = -1e30f, m2 = -1e30f;
    for (int rr = b * 128; rr < b * 128 + 128; ++rr) {
        m1 = fmaxf(m1, bfu(HB[(size_t)rr * 512 + t]));
        m2 = fmaxf(m2, bfu(HB[(size_t)rr * 512 + t + 256]));
    }
    pmax[(size_t)b * 512 + t] = m1; pmax[(size_t)b * 512 + t + 256] = m2;
}
__global__ void k_maxB(const float* __restrict__ pmax, void* __restrict__ outv,
                       const int* __restrict__ fcnt) {
    int j = threadIdx.x;
    float m = -1e30f;
    for (int b = 0; b < 64; ++b) m = fmaxf(m, pmax[(size_t)b * 512 + j]);
    bool isbf = (*fcnt > 2048);
    if (isbf) ((u16*)outv)[512 + j] = f2bf(m);
    else ((float*)outv)[512 + j] = m;
}

__global__ void k_wsfail(u16* out) {
    int i = blockIdx.x * 256 + threadIdx.x;
    if (i < 1024) out[i] = f2bf(12345.f);
}

// ---------------- launch ----------------
extern "C" void kernel_launch(void* const* d_in, const int* in_sizes, int n_in,
                              void* d_out, int out_size, void* d_ws, size_t ws_size,
                              hipStream_t stream) {
    char* base = (char*)d_ws;
    u16* px = (u16*)(base + OFF_PX);
    u16* qx = (u16*)(base + OFF_QX);
    float* acc_h = (float*)(base + OFF_ACCH);
    float* acc_fc = (float*)(base + OFF_ACCF);
    float* acc_zc = (float*)(base + OFF_ACCZ);
    float* Call = (float*)(base + OFF_C);
    u16* HB = (u16*)(base + OFF_HB);
    u16* ZB = (u16*)(base + OFF_ZB);
    float* G = (float*)(base + OFF_G);
    u16* NGI = (u16*)(base + OFF_G);
    u16* NW = (u16*)(base + OFF_NW);
    int* depth = (int*)(base + OFF_DEPTH);
    int* order = (int*)(base + OFF_ORDER);
    int* counts = (int*)(base + OFF_MISC);
    int* fcnt = counts + 128;
    int* pcnt = counts + 129;
    int* lvl = (int*)(base + OFF_LVL);
    u16* NB = (u16*)(base + OFF_NB);
    int* pnorm = (int*)(base + OFF_PN);
    float* pmax = (float*)(base + OFF_PMAX);
    u32* BAR = (u32*)(base + OFF_BAR);

    const u16* in_bf   = (const u16*)d_in[0];
    const u16* csWx_o  = (const u16*)d_in[2];
    const u16* csWio_o = (const u16*)d_in[4];
    const u16* csWfz_o = (const u16*)d_in[6];
    const u16* csWum_o = (const u16*)d_in[8];
    const u16* chWx_o  = (const u16*)d_in[10];
    const u16* chWh_o  = (const u16*)d_in[12];
    const u16* chWum_o = (const u16*)d_in[14];

    if (ws_size < WS_TOTAL) { k_wsfail<<<4, 256, 0, stream>>>((u16*)d_out); return; }

    hipMemsetAsync(base + OFF_MISC, 0, 1024, stream);
    hipMemsetAsync(base + OFF_ACCH, 0, 3 * SZ_ACC, stream);   // acc_h/fc/zc (+ sentinel rows)

    // dtype detect + barrier zero + fused setup
    k_detect<<<32, 256, 0, stream>>>((const u32*)d_in[0], (const u32*)d_in[1], fcnt, pcnt, BAR);
    k_pnorm_depth<<<32, 256, 0, stream>>>((const u32*)d_in[1], pcnt, pnorm, depth, HB, Call);
    k_levels<<<1, 1024, 0, stream>>>(depth, lvl, order);

    NormSrcs srcs;
    srcs.p[0] = d_in[0];  srcs.p[1] = d_in[2];  srcs.p[2] = d_in[10]; srcs.p[3] = d_in[4];
    srcs.p[4] = d_in[6];  srcs.p[5] = d_in[8];  srcs.p[6] = d_in[12]; srcs.p[7] = d_in[14];
    srcs.p[8] = d_in[3];  srcs.p[9] = d_in[5];  srcs.p[10] = d_in[7]; srcs.p[11] = d_in[9];
    srcs.p[12] = d_in[11]; srcs.p[13] = d_in[13]; srcs.p[14] = d_in[15];
    k_norm_all<<<2048, 256, 0, stream>>>(srcs, NGI, NW, NB, fcnt);

    // input projections
    dim3 gg(PXC / 256, NN / 64, 2);
    k_gemm_in<<<gg, 256, 0, stream>>>(in_bf, NGI,
                                      csWx_o, NW + NW_CSWX, chWx_o, NW + NW_CHWX,
                                      NB + NB_CSBX, NB + NB_CHBX, px, qx, fcnt);

    // persistent level loop (full-tile s1 per block, no sibling exchange, one grid
    // barrier per level); fallback: per-level kernels
    {
        const u16* nWio = NW + NW_CSWIO; const u16* nWum = NW + NW_CSWUM;
        const u16* nWfz = NW + NW_CSWFZ; const u16* nWh = NW + NW_CHWH;
        const u16* nWu2 = NW + NW_CHWUM;
        const u16* b_io = NB + NB_CSBIO; const u16* b_um = NB + NB_CSBUM;
        const u16* b_fz = NB + NB_CSBFZ; const u16* b_h = NB + NB_CHBH;
        const u16* b_u2 = NB + NB_CHBUM;
        const int* order_c = order; const int* lvl_c = lvl; const int* par_c = pnorm;
        const u16* px_c = px; const u16* qx_c = qx;
        void* outp = d_out; const int* fcnt_c = fcnt;
        u32* bar_c = BAR;
        void* margs[] = {
            (void*)&order_c, (void*)&lvl_c, (void*)&par_c,
            (void*)&acc_h, (void*)&acc_fc, (void*)&acc_zc,
            (void*)&csWio_o, (void*)&nWio, (void*)&csWum_o, (void*)&nWum,
            (void*)&csWfz_o, (void*)&nWfz,
            (void*)&b_io, (void*)&b_um, (void*)&b_fz,
            (void*)&px_c, (void*)&HB, (void*)&Call,
            (void*)&chWh_o, (void*)&nWh, (void*)&chWum_o, (void*)&nWu2,
            (void*)&b_h, (void*)&b_u2,
            (void*)&qx_c, (void*)&ZB, (void*)&G,
            (void*)&outp, (void*)&fcnt_c, (void*)&bar_c
        };
        hipError_t ce = hipLaunchCooperativeKernel((const void*)comb_mega7,
                                                   dim3(256), dim3(512), margs, 0, stream);
        if (ce != hipSuccess) {
            (void)hipGetLastError();
            dim3 gl(4, GY, 2);
            for (int i = 0; i < MAXD; ++i) {
                comb_s1<<<gl, 512, 0, stream>>>(i, order, lvl, pnorm,
                                                acc_h, acc_fc, acc_zc,
                                                csWio_o, NW + NW_CSWIO, csWum_o, NW + NW_CSWUM,
                                                NB + NB_CSBIO, NB + NB_CSBUM, px,
                                                HB, Call, chWh_o, NW + NW_CHWH, NB + NB_CHBH,
                                                qx, ZB, G, d_out, fcnt);
                comb_s2<<<gl, 512, 0, stream>>>(i, order, lvl, pnorm,
                                                csWfz_o, NW + NW_CSWFZ, NB + NB_CSBFZ, px,
                                                acc_fc, acc_zc,
                                                ZB, qx, chWum_o, NW + NW_CHWUM, NB + NB_CHBUM,
                                                Call, HB, G, fcnt);
            }
        }
    }

    // brep
    k_maxA<<<64, 256, 0, stream>>>(HB, pmax);
    k_maxB<<<1, 512, 0, stream>>>(pmax, d_out, fcnt);
}

// Round 12
// 1127.490 us; speedup vs baseline: 2.3702x; 2.3702x over previous
//
#include <hip/hip_runtime.h>
#include <hip/hip_cooperative_groups.h>
#include <hip/hip_bf16.h>

typedef unsigned short u16;
typedef unsigned int u32;
typedef unsigned long long u64;

#define NN 8192
#define PXC 2560
#define MAXD 36
#define GY 64
#define GYM 32

typedef __attribute__((ext_vector_type(8))) short bf16x8;
typedef __attribute__((ext_vector_type(4))) float f32x4;

// ---------------- workspace layout (bytes) ----------------
static constexpr size_t SZ_PX  = (size_t)(NN + 1) * PXC * 2;
static constexpr size_t SZ_ACC = (size_t)(NN + 1) * 512 * 4;
static constexpr size_t SZ_HB  = (size_t)(NN + 1) * 512 * 2;
static constexpr size_t SZ_G   = (size_t)(NN + 1) * 1536 * 4;
static constexpr size_t SZ_NW  = (size_t)5242880 * 2;

static constexpr size_t OFF_PX    = 0;
static constexpr size_t OFF_QX    = OFF_PX + SZ_PX;
static constexpr size_t OFF_ACCH  = OFF_QX + SZ_PX;
static constexpr size_t OFF_ACCF  = OFF_ACCH + SZ_ACC;
static constexpr size_t OFF_ACCZ  = OFF_ACCF + SZ_ACC;
static constexpr size_t OFF_C     = OFF_ACCZ + SZ_ACC;         // c_all (chain), f32
static constexpr size_t OFF_HB    = OFF_C + SZ_ACC;            // h_all (chain), bf16
static constexpr size_t OFF_ZB    = OFF_HB + SZ_HB;            // chain ZB, bf16
static constexpr size_t OFF_G     = OFF_ZB + SZ_HB;            // per-node scratch / transient normalized inputs
static constexpr size_t OFF_NW    = OFF_G + SZ_G;
static constexpr size_t OFF_DEPTH = OFF_NW + SZ_NW;
static constexpr size_t OFF_ORDER = OFF_DEPTH + (size_t)NN * 4;
static constexpr size_t OFF_MISC  = OFF_ORDER + (size_t)NN * 4;
static constexpr size_t OFF_LVL   = OFF_MISC + 1024;
static constexpr size_t OFF_NB    = OFF_LVL + 512;
static constexpr size_t OFF_PN    = OFF_NB + 20480;
static constexpr size_t OFF_PMAX  = OFF_PN + (size_t)NN * 4;
static constexpr size_t OFF_BAR   = OFF_PMAX + (size_t)128 * 512 * 4;
static constexpr size_t WS_TOTAL  = OFF_BAR + 32768;

#define NW_CSWX  0
#define NW_CHWX  1310720
#define NW_CSWIO 2621440
#define NW_CSWFZ 3145728
#define NW_CSWUM 3670016
#define NW_CHWH  3932160
#define NW_CHWUM 4980736

#define NB_CSBX  0
#define NB_CSBIO 2560
#define NB_CSBFZ 3584
#define NB_CSBUM 4608
#define NB_CHBX  5120
#define NB_CHBH  7680
#define NB_CHBUM 9728

// ---------------- helpers ----------------
__device__ __forceinline__ float bfu(u16 u) { return __uint_as_float(((u32)u) << 16); }
__device__ __forceinline__ u16 f2bf(float f) {
    u32 u = __float_as_uint(f);
    u += 0x7fffu + ((u >> 16) & 1u);
    return (u16)(u >> 16);
}
__device__ __forceinline__ float sigf(float x) {
    x = fminf(fmaxf(x, -30.f), 30.f);
    return 1.f / (1.f + __expf(-x));
}
__device__ __forceinline__ float tanhq(float x) {
    x = fminf(fmaxf(x, -15.f), 15.f);
    return 1.f - 2.f / (__expf(2.f * x) + 1.f);
}
__device__ __forceinline__ bf16x8 cvt8(const float* p) {
    float4 a = *(const float4*)p;
    float4 b = *(const float4*)(p + 4);
    union { u32 u[4]; bf16x8 v; } r;
    r.u[0] = ((__float_as_uint(a.x) + 0x8000u) >> 16) | ((__float_as_uint(a.y) + 0x8000u) & 0xffff0000u);
    r.u[1] = ((__float_as_uint(a.z) + 0x8000u) >> 16) | ((__float_as_uint(a.w) + 0x8000u) & 0xffff0000u);
    r.u[2] = ((__float_as_uint(b.x) + 0x8000u) >> 16) | ((__float_as_uint(b.y) + 0x8000u) & 0xffff0000u);
    r.u[3] = ((__float_as_uint(b.z) + 0x8000u) >> 16) | ((__float_as_uint(b.w) + 0x8000u) & 0xffff0000u);
    return r.v;
}

// -------- agent-scope (XCD-coherent) accessors for mutable state --------
__device__ __forceinline__ u64 cld64(const void* p) {
    return __hip_atomic_load((const u64*)p, __ATOMIC_RELAXED, __HIP_MEMORY_SCOPE_AGENT);
}
__device__ __forceinline__ float cldf(const float* p) {
    return __hip_atomic_load(p, __ATOMIC_RELAXED, __HIP_MEMORY_SCOPE_AGENT);
}
__device__ __forceinline__ void cstf(float* p, float v) {
    __hip_atomic_store(p, v, __ATOMIC_RELAXED, __HIP_MEMORY_SCOPE_AGENT);
}
__device__ __forceinline__ void cst16(u16* p, u16 v) {
    __hip_atomic_store(p, v, __ATOMIC_RELAXED, __HIP_MEMORY_SCOPE_AGENT);
}
__device__ __forceinline__ bf16x8 cvt8a(const float* p) {  // 32B f32 coherent load -> bf16x8
    union { u64 u; u32 w[2]; } a, b, c, d;
    a.u = cld64(p); b.u = cld64(p + 2); c.u = cld64(p + 4); d.u = cld64(p + 6);
    union { u32 u[4]; bf16x8 v; } r;
    r.u[0] = ((a.w[0] + 0x8000u) >> 16) | ((a.w[1] + 0x8000u) & 0xffff0000u);
    r.u[1] = ((b.w[0] + 0x8000u) >> 16) | ((b.w[1] + 0x8000u) & 0xffff0000u);
    r.u[2] = ((c.w[0] + 0x8000u) >> 16) | ((c.w[1] + 0x8000u) & 0xffff0000u);
    r.u[3] = ((d.w[0] + 0x8000u) >> 16) | ((d.w[1] + 0x8000u) & 0xffff0000u);
    return r.v;
}

// ---- contention-free GRID barrier (256 blocks), monotonic flags ----
// Arrival: one relaxed store per block (64B-spaced flags). Block 0 polls all 256 in
// parallel, then fans the release out across 8 64B-spaced gen copies; each block
// polls copy (bid&7) — cuts the single-line release broadcast serialization.
__device__ __forceinline__ void grid_bar(u32* B, int bid, u32 tgt) {
    __syncthreads();                       // all waves drain their stores here
    int tid = threadIdx.x;
    if (tid == 0)
        __hip_atomic_store(B + 16 + bid * 16, tgt, __ATOMIC_RELAXED, __HIP_MEMORY_SCOPE_AGENT);
    if (blockIdx.x == 0) {
        if (tid < 256) {
            while (__hip_atomic_load(B + 16 + tid * 16, __ATOMIC_RELAXED, __HIP_MEMORY_SCOPE_AGENT) < tgt)
                __builtin_amdgcn_s_sleep(1);
        }
        __syncthreads();
        if (tid < 8)
            __hip_atomic_store(B + 4608 + tid * 16, tgt, __ATOMIC_RELAXED, __HIP_MEMORY_SCOPE_AGENT);
    }
    if (tid == 0) {
        while (__hip_atomic_load(B + 4608 + (bid & 7) * 16, __ATOMIC_RELAXED, __HIP_MEMORY_SCOPE_AGENT) < tgt)
            __builtin_amdgcn_s_sleep(1);
        asm volatile("" ::: "memory");
    }
    __syncthreads();
}

// 4-sibling mini-barrier: 4 private flags (16B apart), monotonic; no RMW.
__device__ __forceinline__ void mini_bar(u32* MF, int cgi, u32 tgt) {
    __syncthreads();                       // drains this block's stores
    if (threadIdx.x == 0) {
        __hip_atomic_store(MF + cgi * 4, tgt, __ATOMIC_RELAXED, __HIP_MEMORY_SCOPE_AGENT);
        for (;;) {
            u32 a = __hip_atomic_load(MF + 0,  __ATOMIC_RELAXED, __HIP_MEMORY_SCOPE_AGENT);
            u32 b = __hip_atomic_load(MF + 4,  __ATOMIC_RELAXED, __HIP_MEMORY_SCOPE_AGENT);
            u32 c = __hip_atomic_load(MF + 8,  __ATOMIC_RELAXED, __HIP_MEMORY_SCOPE_AGENT);
            u32 d = __hip_atomic_load(MF + 12, __ATOMIC_RELAXED, __HIP_MEMORY_SCOPE_AGENT);
            if (a >= tgt && b >= tgt && c >= tgt && d >= tgt) break;
            __builtin_amdgcn_s_sleep(1);
        }
        asm volatile("" ::: "memory");
    }
    __syncthreads();
}

// ---------------- dtype detection (+ barrier zeroing) ----------------
__global__ void k_detect(const u32* __restrict__ fin, const u32* __restrict__ pin,
                         int* __restrict__ fcnt, int* __restrict__ pcnt,
                         u32* __restrict__ barz) {
    int i = blockIdx.x * 256 + threadIdx.x;
    if (i < 8192) barz[i] = 0u;
    if (i < 4096) {
        u32 w = fin[i];
        int e = (w >> 7) & 0xFF;
        if (w != 0u && e >= 0x70 && e <= 0x8F) atomicAdd(fcnt, 1);
    }
    if (i >= 1 && i < 4096) {
        if (pin[2 * i - 1] != 0u) atomicAdd(pcnt, 1);
    }
}

// fused: parent normalize + depth chase + sentinel-row init
__global__ void k_pnorm_depth(const u32* __restrict__ pin, const int* __restrict__ pcnt,
                              int* __restrict__ pnorm, int* __restrict__ depth,
                              u16* __restrict__ HB, float* __restrict__ Call) {
    int i = blockIdx.x * 256 + threadIdx.x;
    if (i < 512) {
        HB[(size_t)NN * 512 + i] = 0;
        Call[(size_t)NN * 512 + i] = 0.f;
    }
    if (i >= NN) return;
    bool is64 = (*pcnt < 100);
    int p = (int)(is64 ? pin[2 * i] : pin[i]);
    pnorm[i] = p;
    int d = 0;
    while (p != NN && p >= 0 && p < NN && d < 9000) {
        d++;
        p = (int)(is64 ? pin[2 * p] : pin[p]);
    }
    depth[i] = d;
}

// fused hist + scan + scatter, single block; also computes D* -> lvl[80]
__global__ __launch_bounds__(1024) void k_levels(const int* __restrict__ depth,
                                                 int* __restrict__ lvl, int* __restrict__ order) {
    __shared__ int cnts[64];
    __shared__ int cur[64];
    int t = threadIdx.x;
    if (t < 64) cnts[t] = 0;
    __syncthreads();
    for (int i = t; i < NN; i += 1024) {
        int d = depth[i]; if (d > 63) d = 63;
        atomicAdd(&cnts[d], 1);
    }
    __syncthreads();
    if (t == 0) {
        int s = 0; lvl[0] = 0;
        for (int d = 0; d < 64; ++d) { cur[d] = s; s += cnts[d]; lvl[d + 1] = s; }
        int D = 1;
        for (int d = 63; d >= 0; --d) if (cnts[d] > 0) { D = d + 1; break; }
        lvl[80] = D;                        // number of nonempty levels
    }
    __syncthreads();
    for (int i = t; i < NN; i += 1024) {
        int d = depth[i]; if (d > 63) d = 63;
        int pos = atomicAdd(&cur[d], 1);
        order[pos] = i;
    }
}

struct NormSrcs { const void* p[15]; };
__global__ __launch_bounds__(256) void k_norm_all(NormSrcs s, u16* __restrict__ NGI,
                                                  u16* __restrict__ NW, u16* __restrict__ NB,
                                                  const int* __restrict__ fcnt) {
    const int cum[16] = {0, 1048576, 1376256, 1703936, 1835008, 1966080, 2031616, 2293760,
                         2359296, 2359936, 2360192, 2360448, 2360576, 2361216, 2361728, 2361856};
    const int dof[15] = {0, NW_CSWX / 4, NW_CHWX / 4, NW_CSWIO / 4, NW_CSWFZ / 4, NW_CSWUM / 4,
                         NW_CHWH / 4, NW_CHWUM / 4, NB_CSBX / 4, NB_CSBIO / 4, NB_CSBFZ / 4,
                         NB_CSBUM / 4, NB_CHBX / 4, NB_CHBH / 4, NB_CHBUM / 4};
    bool isbf = (*fcnt > 2048);
    int total = 2361856;
    int istart = isbf ? cum[8] : 0;
    for (int i = istart + blockIdx.x * 256 + threadIdx.x; i < total; i += gridDim.x * 256) {
        int seg = 0;
#pragma unroll
        for (int k = 1; k < 15; ++k) if (i >= cum[k]) seg = k;
        int off = i - cum[seg];
        u16* dbase = (seg == 0) ? NGI : (seg < 8 ? NW : NB);
        ushort4* dst = (ushort4*)dbase + dof[seg] + off;
        if (isbf) {
            *dst = ((const ushort4*)s.p[seg])[off];
        } else {
            float4 v = ((const float4*)s.p[seg])[off];
            ushort4 o; o.x = f2bf(v.x); o.y = f2bf(v.y); o.z = f2bf(v.z); o.w = f2bf(v.w);
            *dst = o;
        }
    }
}

// ---------------- input-projection GEMM ----------------
#define ASTR 528
__global__ __launch_bounds__(256) void k_gemm_in(
    const u16* __restrict__ Ao, const u16* __restrict__ An,
    const u16* __restrict__ Wcs_o, const u16* __restrict__ Wcs_n,
    const u16* __restrict__ Wch_o, const u16* __restrict__ Wch_n,
    const u16* __restrict__ bcs, const u16* __restrict__ bch,
    u16* __restrict__ Ccs, u16* __restrict__ Cch,
    const int* __restrict__ fcnt)
{
    __shared__ __align__(16) u16 AS[64 * ASTR];
    bool isbf = (*fcnt > 2048);
    int z = blockIdx.z;
    const u16* A = isbf ? Ao : An;
    const u16* W = z ? (isbf ? Wch_o : Wch_n) : (isbf ? Wcs_o : Wcs_n);
    const u16* bias = z ? bch : bcs;
    u16* C = z ? Cch : Ccs;

    int m0 = blockIdx.y * 64;
    for (int e = threadIdx.x; e < 64 * 64; e += 256) {
        int row = e >> 6, c8 = e & 63;
        *(uint4*)&AS[row * ASTR + c8 * 8] = *(const uint4*)(A + (size_t)(m0 + row) * 512 + c8 * 8);
    }
    __syncthreads();

    int wv = threadIdx.x >> 6;
    int lane = threadIdx.x & 63;
    int r = lane & 15, q = lane >> 4;
    int n0 = blockIdx.x * 256 + wv * 64;
    const u16* pb[4];
#pragma unroll
    for (int jt = 0; jt < 4; ++jt) pb[jt] = W + (size_t)(n0 + jt * 16 + r) * 512 + q * 8;
    f32x4 acc[4][4] = {};
#pragma unroll 2
    for (int k0 = 0; k0 < 512; k0 += 32) {
        bf16x8 a[4], b[4];
#pragma unroll
        for (int mi = 0; mi < 4; ++mi)
            a[mi] = *(const bf16x8*)&AS[(mi * 16 + r) * ASTR + k0 + q * 8];
#pragma unroll
        for (int jt = 0; jt < 4; ++jt) b[jt] = *(const bf16x8*)(pb[jt] + k0);
#pragma unroll
        for (int mi = 0; mi < 4; ++mi)
#pragma unroll
            for (int jt = 0; jt < 4; ++jt)
                acc[mi][jt] = __builtin_amdgcn_mfma_f32_16x16x32_bf16(a[mi], b[jt], acc[mi][jt], 0, 0, 0);
    }
#pragma unroll
    for (int jt = 0; jt < 4; ++jt) {
        int c = n0 + jt * 16 + r;
        float bv = bfu(bias[c]);
#pragma unroll
        for (int mi = 0; mi < 4; ++mi) {
            size_t b0 = (size_t)(m0 + mi * 16 + q * 4) * PXC + c;
#pragma unroll
            for (int i = 0; i < 4; ++i)
                C[b0 + (size_t)i * PXC] = f2bf(acc[mi][jt][i] + bv);
        }
    }
}

// ================= persistent level loop: round-10 verified shape + epilogue prefetch =================
// bid: z=bid&1 plane, cgi=(bid>>1)&3 col slice, ty=bid>>3 (0..31).
// Per tile: s1 -> 4-sibling mini-barrier -> s2.  ONE grid barrier per level.
// All epilogue operands (px/qx gate inputs, acc_fc, Call[parent]) are PREFETCHED into
// registers right after ndl/pl is known, overlapping their HBM/L3 latency with
// staging + MFMA instead of extending the per-tile serial chain.
__global__ __launch_bounds__(512, 2) void comb_mega8(
    const int* __restrict__ order, const int* __restrict__ lvl, const int* __restrict__ parent,
    float* __restrict__ acc_h, float* __restrict__ acc_fc, float* __restrict__ acc_zc,
    const u16* __restrict__ Wio_o, const u16* __restrict__ Wio_n,
    const u16* __restrict__ Wum_o, const u16* __restrict__ Wum_n,
    const u16* __restrict__ Wfz_o, const u16* __restrict__ Wfz_n,
    const u16* __restrict__ bio, const u16* __restrict__ bum, const u16* __restrict__ bfz,
    const u16* __restrict__ px,
    u16* __restrict__ HB, float* __restrict__ Call,
    const u16* __restrict__ Wh_o, const u16* __restrict__ Wh_n,
    const u16* __restrict__ Wu2_o, const u16* __restrict__ Wu2_n,
    const u16* __restrict__ bh, const u16* __restrict__ bu2,
    const u16* __restrict__ qx, u16* __restrict__ ZB,
    float* __restrict__ G,
    void* __restrict__ outv, const int* __restrict__ fcnt,
    u32* __restrict__ BAR)
{
    __shared__ __align__(16) u16 LS[16384];   // 32KB: 2 x [16][512] bf16 panels
    __shared__ int ndl[16], pl[16];
    bool isbf = (*fcnt > 2048);
    int tid = threadIdx.x;
    int w = tid >> 6, lane = tid & 63;
    int r = lane & 15, q = lane >> 4;
    int rsw = (r & 7) << 4;
    int bid = blockIdx.x;
    int z = bid & 1;
    int cgi = (bid >> 1) & 3;
    int ty = bid >> 3;                        // 0..31
    int col = (cgi * 8 + w) * 16 + r;
    u16* Gh = (u16*)G;
    char* LB = (char*)LS;
    int Dmax = lvl[80];
    u32* MF = BAR + 5120 + (size_t)((z << 5) + ty) * 16;  // 4 flags, 16B apart
    u32 tgt = 0, mtgt = 0;

    // hoisted plane invariants
    const u16 *p1a, *p1b, *p1c, *p1d;
    const u16 *p2a, *p2b;
    float ba, bb, bc, bd, be;
    if (z == 0) {
        const u16* Wio = isbf ? Wio_o : Wio_n;
        const u16* Wum = isbf ? Wum_o : Wum_n;
        const u16* Wfz = isbf ? Wfz_o : Wfz_n;
        p1a = Wio + (size_t)col * 512 + q * 8;
        p1b = Wio + (size_t)(512 + col) * 512 + q * 8;
        p1c = Wum + (size_t)col * 512 + q * 8;
        p1d = p1c;
        p2a = Wfz + (size_t)col * 512 + q * 8;
        p2b = Wfz + (size_t)(512 + col) * 512 + q * 8;
        ba = bfu(bio[col]); bb = bfu(bio[512 + col]); bc = bfu(bum[col]);
        bd = bfu(bfz[col]); be = bfu(bfz[512 + col]);
    } else {
        const u16* Wh = isbf ? Wh_o : Wh_n;
        const u16* Wu = isbf ? Wu2_o : Wu2_n;
        p1a = Wh + (size_t)col * 512 + q * 8;
        p1b = Wh + (size_t)(512 + col) * 512 + q * 8;
        p1c = Wh + (size_t)(1024 + col) * 512 + q * 8;
        p1d = Wh + (size_t)(1536 + col) * 512 + q * 8;
        p2a = Wu + (size_t)col * 512 + q * 8;
        p2b = p2a;
        ba = bfu(bh[col]); bb = bfu(bh[512 + col]);
        bc = bfu(bh[1024 + col]); bd = bfu(bh[1536 + col]);
        be = bfu(bu2[col]);
    }

    for (int it = 0; it < Dmax; ++it) {
        int d = z ? it : (Dmax - 1 - it);
        int start = lvl[d], cnt = lvl[d + 1] - start;
        int ntiles = (cnt + 15) >> 4;

        for (int tile = ty; tile < ntiles; tile += GYM) {
            __syncthreads();
            if (tid < 16) {
                int tr = tile * 16 + tid;
                int nd = (tr < cnt) ? order[start + tr] : -1;
                ndl[tid] = nd;
                pl[tid] = (nd >= 0) ? parent[nd] : NN;
            }
            __syncthreads();

            if (z == 0) {
                // -------- prefetch all epilogue operands (node px i/o/u, acc_fc; parent px f/z) --------
                float pfi[4], pfo[4], pfu[4], pfc[4], pff[4], pfz[4];
#pragma unroll
                for (int i2 = 0; i2 < 4; ++i2) {
                    int slot = q * 4 + i2;
                    int ni = ndl[slot]; int p = pl[slot];
                    int nn = (ni < 0) ? NN : ni;
                    size_t pxb = (size_t)nn * PXC, nb = (size_t)nn * 512;
                    size_t ppx = (size_t)p * PXC;
                    pfi[i2] = bfu(px[pxb + col]);
                    pfo[i2] = bfu(px[pxb + 1024 + col]);
                    pfu[i2] = bfu(px[pxb + 2048 + col]);
                    pfc[i2] = cldf(acc_fc + nb + col);
                    pff[i2] = bfu(px[ppx + 512 + col]);
                    pfz[i2] = bfu(px[ppx + 1536 + col]);
                }
                // ---------- cs s1: stage AH/AZ (sc1; atomic-fed), gates i,o,u -> c(reg), h->Gh ----------
                for (int e = tid; e < 1024; e += 512) {
                    int slot = e >> 6, c8 = e & 63;
                    int nd = ndl[slot]; int nn = (nd < 0) ? NN : nd;
                    int boff = slot * 1024 + ((c8 * 16) ^ ((slot & 7) << 4));
                    *(bf16x8*)(LB + boff) = cvt8a(acc_h + (size_t)nn * 512 + c8 * 8);
                    *(bf16x8*)(LB + 16384 + boff) = cvt8a(acc_zc + (size_t)nn * 512 + c8 * 8);
                }
                __syncthreads();
                f32x4 ai = {}, ao = {}, au = {};
#pragma unroll 4
                for (int ko = 0; ko < 512; ko += 32) {
                    int abo = ((ko + q * 8) * 2) ^ rsw;
                    bf16x8 ah = *(const bf16x8*)(LB + r * 1024 + abo);
                    bf16x8 az = *(const bf16x8*)(LB + 16384 + r * 1024 + abo);
                    ai = __builtin_amdgcn_mfma_f32_16x16x32_bf16(ah, *(const bf16x8*)(p1a + ko), ai, 0, 0, 0);
                    ao = __builtin_amdgcn_mfma_f32_16x16x32_bf16(ah, *(const bf16x8*)(p1b + ko), ao, 0, 0, 0);
                    au = __builtin_amdgcn_mfma_f32_16x16x32_bf16(az, *(const bf16x8*)(p1c + ko), au, 0, 0, 0);
                }
                float ccv[4];
#pragma unroll
                for (int i2 = 0; i2 < 4; ++i2) {
                    int slot = q * 4 + i2;
                    int ni = ndl[slot];
                    ccv[i2] = 0.f;
                    if (ni < 0) continue;
                    int p = pl[slot];
                    float ig = sigf(pfi[i2] + ai[i2] + ba);
                    float og = sigf(pfo[i2] + ao[i2] + bb);
                    float uu = tanhq(pfu[i2] + au[i2] + bc);
                    float cc = ig * uu + pfc[i2];
                    float h = og * tanhq(cc);
                    ccv[i2] = cc;
                    cst16(&Gh[(size_t)ni * 3072 + 1024 + col], f2bf(h));
                    atomicAdd(&acc_h[(size_t)p * 512 + col], h);
                    if (ni == 0) {
                        if (isbf) ((u16*)outv)[col] = f2bf(h);
                        else ((float*)outv)[col] = h;
                    }
                }
                ++mtgt; mini_bar(MF, cgi, mtgt);
                // ---------- cs s2: stage HT (plain; rows written once, pre-mini-bar), f,z -> scatter ----------
                for (int e = tid; e < 1024; e += 512) {
                    int slot = e >> 6, c8 = e & 63;
                    int nd = ndl[slot]; int nn = (nd < 0) ? NN : nd;
                    int boff = slot * 1024 + ((c8 * 16) ^ ((slot & 7) << 4));
                    *(bf16x8*)(LB + boff) = *(const bf16x8*)(Gh + (size_t)nn * 3072 + 1024 + c8 * 8);
                }
                __syncthreads();
                f32x4 af0 = {}, af1 = {}, az0 = {}, az1 = {};
#pragma unroll 4
                for (int ko = 0; ko < 256; ko += 32) {
                    int ab0 = ((ko + q * 8) * 2) ^ rsw;
                    int ab1 = ((ko + 256 + q * 8) * 2) ^ rsw;
                    bf16x8 h0 = *(const bf16x8*)(LB + r * 1024 + ab0);
                    bf16x8 h1 = *(const bf16x8*)(LB + r * 1024 + ab1);
                    af0 = __builtin_amdgcn_mfma_f32_16x16x32_bf16(h0, *(const bf16x8*)(p2a + ko), af0, 0, 0, 0);
                    az0 = __builtin_amdgcn_mfma_f32_16x16x32_bf16(h0, *(const bf16x8*)(p2b + ko), az0, 0, 0, 0);
                    af1 = __builtin_amdgcn_mfma_f32_16x16x32_bf16(h1, *(const bf16x8*)(p2a + 256 + ko), af1, 0, 0, 0);
                    az1 = __builtin_amdgcn_mfma_f32_16x16x32_bf16(h1, *(const bf16x8*)(p2b + 256 + ko), az1, 0, 0, 0);
                }
                f32x4 af = af0 + af1, az = az0 + az1;
#pragma unroll
                for (int i2 = 0; i2 < 4; ++i2) {
                    int slot = q * 4 + i2;
                    int ni = ndl[slot];
                    if (ni < 0) continue;
                    int p = pl[slot];
                    size_t pb = (size_t)p * 512;
                    float cT = ccv[i2];
                    float f = sigf(pff[i2] + af[i2] + bd);
                    atomicAdd(&acc_fc[pb + col], f * cT);
                    float zf = sigf(pfz[i2] + az[i2] + be);
                    atomicAdd(&acc_zc[pb + col], zf * tanhq(cT));
                }
            } else {
                // -------- prefetch all epilogue operands (node qx i/o/f/z/u; parent Call) --------
                float pqi[4], pqo[4], pqf[4], pqz[4], pqu[4], ppc[4];
#pragma unroll
                for (int i2 = 0; i2 < 4; ++i2) {
                    int slot = q * 4 + i2;
                    int ni = ndl[slot]; int p = pl[slot];
                    int nn = (ni < 0) ? NN : ni;
                    size_t qb = (size_t)nn * PXC;
                    pqi[i2] = bfu(qx[qb + col]);
                    pqo[i2] = bfu(qx[qb + 512 + col]);
                    pqf[i2] = bfu(qx[qb + 1024 + col]);
                    pqz[i2] = bfu(qx[qb + 1536 + col]);
                    pqu[i2] = bfu(qx[qb + 2048 + col]);
                    ppc[i2] = Call[(size_t)p * 512 + col];   // write-once + reuse: plain
                }
                // ---------- ch s1: stage AP=HB[parent] (plain), gates i,o,f,z -> regs; ZB ----------
                for (int e = tid; e < 1024; e += 512) {
                    int slot = e >> 6, c8 = e & 63;
                    int boff = slot * 1024 + ((c8 * 16) ^ ((slot & 7) << 4));
                    *(bf16x8*)(LB + boff) = *(const bf16x8*)(HB + (size_t)pl[slot] * 512 + c8 * 8);
                }
                __syncthreads();
                f32x4 gi = {}, go = {}, gf = {}, gz = {};
#pragma unroll 4
                for (int ko = 0; ko < 512; ko += 32) {
                    int abo = ((ko + q * 8) * 2) ^ rsw;
                    bf16x8 a = *(const bf16x8*)(LB + r * 1024 + abo);
                    gi = __builtin_amdgcn_mfma_f32_16x16x32_bf16(a, *(const bf16x8*)(p1a + ko), gi, 0, 0, 0);
                    go = __builtin_amdgcn_mfma_f32_16x16x32_bf16(a, *(const bf16x8*)(p1b + ko), go, 0, 0, 0);
                    gf = __builtin_amdgcn_mfma_f32_16x16x32_bf16(a, *(const bf16x8*)(p1c + ko), gf, 0, 0, 0);
                    gz = __builtin_amdgcn_mfma_f32_16x16x32_bf16(a, *(const bf16x8*)(p1d + ko), gz, 0, 0, 0);
                }
                float siR[4], soR[4], sfR[4];
#pragma unroll
                for (int i2 = 0; i2 < 4; ++i2) {
                    int slot = q * 4 + i2;
                    int ni = ndl[slot];
                    siR[i2] = 0.f; soR[i2] = 0.f; sfR[i2] = 0.f;
                    if (ni < 0) continue;
                    size_t nb = (size_t)ni * 512;
                    float si = sigf(pqi[i2] + gi[i2] + ba);
                    float so = sigf(pqo[i2] + go[i2] + bb);
                    float sf = sigf(pqf[i2] + gf[i2] + bc);
                    float zg = sigf(pqz[i2] + gz[i2] + bd);
                    siR[i2] = si; soR[i2] = so; sfR[i2] = sf;
                    cst16(&ZB[nb + col], f2bf(zg * tanhq(ppc[i2])));
                }
                ++mtgt; mini_bar(MF, cgi, mtgt);
                // ---------- ch s2: stage ZT (plain; written pre-mini-bar), u gate -> c,h ----------
                for (int e = tid; e < 1024; e += 512) {
                    int slot = e >> 6, c8 = e & 63;
                    int nd = ndl[slot]; int nn = (nd < 0) ? NN : nd;
                    int boff = slot * 1024 + ((c8 * 16) ^ ((slot & 7) << 4));
                    *(bf16x8*)(LB + boff) = *(const bf16x8*)(ZB + (size_t)nn * 512 + c8 * 8);
                }
                __syncthreads();
                f32x4 a0 = {}, a1 = {}, a2 = {}, a3 = {};
#pragma unroll 4
                for (int ko = 0; ko < 128; ko += 32) {
                    int b0 = ((ko + q * 8) * 2) ^ rsw;
                    int b1 = ((ko + 128 + q * 8) * 2) ^ rsw;
                    int b2 = ((ko + 256 + q * 8) * 2) ^ rsw;
                    int b3 = ((ko + 384 + q * 8) * 2) ^ rsw;
                    a0 = __builtin_amdgcn_mfma_f32_16x16x32_bf16(*(const bf16x8*)(LB + r * 1024 + b0),
                                                                 *(const bf16x8*)(p2a + ko), a0, 0, 0, 0);
                    a1 = __builtin_amdgcn_mfma_f32_16x16x32_bf16(*(const bf16x8*)(LB + r * 1024 + b1),
                                                                 *(const bf16x8*)(p2a + 128 + ko), a1, 0, 0, 0);
                    a2 = __builtin_amdgcn_mfma_f32_16x16x32_bf16(*(const bf16x8*)(LB + r * 1024 + b2),
                                                                 *(const bf16x8*)(p2a + 256 + ko), a2, 0, 0, 0);
                    a3 = __builtin_amdgcn_mfma_f32_16x16x32_bf16(*(const bf16x8*)(LB + r * 1024 + b3),
                                                                 *(const bf16x8*)(p2a + 384 + ko), a3, 0, 0, 0);
                }
                f32x4 auv = (a0 + a1) + (a2 + a3);
#pragma unroll
                for (int i2 = 0; i2 < 4; ++i2) {
                    int slot = q * 4 + i2;
                    int ni = ndl[slot];
                    if (ni < 0) continue;
                    size_t nb = (size_t)ni * 512;
                    float uu = tanhq(pqu[i2] + auv[i2] + be);
                    float cc = siR[i2] * uu + sfR[i2] * ppc[i2];
                    float h = soR[i2] * tanhq(cc);
                    cstf(&Call[nb + col], cc);
                    cst16(&HB[nb + col], f2bf(h));
                }
            }
        }
        ++tgt; grid_bar(BAR, bid, tgt);
    }
}

// ---------------- fallback per-level kernels (round-3, verified) ----------------
__global__ __launch_bounds__(512) void comb_s1(
    int iter,
    const int* __restrict__ order, const int* __restrict__ lvl, const int* __restrict__ parent,
    float* acc_h, const float* __restrict__ acc_fc, const float* __restrict__ acc_zc,
    const u16* __restrict__ Wio_o, const u16* __restrict__ Wio_n,
    const u16* __restrict__ Wum_o, const u16* __restrict__ Wum_n,
    const u16* __restrict__ bio, const u16* __restrict__ bum,
    const u16* __restrict__ px,
    const u16* __restrict__ HB, const float* __restrict__ Call,
    const u16* __restrict__ Wh_o, const u16* __restrict__ Wh_n,
    const u16* __restrict__ bh,
    const u16* __restrict__ qx, u16* __restrict__ ZB,
    float* __restrict__ G,
    void* __restrict__ outv, const int* __restrict__ fcnt)
{
    __shared__ __align__(16) u16 LS[16384];
    __shared__ int ndl[16], pl[16];
    bool isbf = (*fcnt > 2048);
    int tid = threadIdx.x;
    int w = tid >> 6, lane = tid & 63;
    int r = lane & 15, q = lane >> 4;
    int rsw = (r & 7) << 4;
    int col = (blockIdx.x * 8 + w) * 16 + r;
    u16* Gh = (u16*)G;
    char* LB = (char*)LS;
    int Dmax = lvl[80];
    int d = blockIdx.z ? iter : (Dmax - 1 - iter);
    if (d < 0 || d >= Dmax) return;
    int start = lvl[d], cnt = lvl[d + 1] - start;
    if (cnt <= 0) return;
    int ntiles = (cnt + 15) >> 4;

    if (blockIdx.z == 0) {
        const u16* Wio = isbf ? Wio_o : Wio_n;
        const u16* Wum = isbf ? Wum_o : Wum_n;
        const u16* pbi = Wio + (size_t)col * 512 + q * 8;
        const u16* pbo = Wio + (size_t)(512 + col) * 512 + q * 8;
        const u16* pbu = Wum + (size_t)col * 512 + q * 8;
        for (int tile = blockIdx.y; tile < ntiles; tile += GY) {
            __syncthreads();
            if (tid < 16) {
                int tr = tile * 16 + tid;
                int nd = (tr < cnt) ? order[start + tr] : -1;
                ndl[tid] = nd;
                pl[tid] = (nd >= 0) ? parent[nd] : NN;
            }
            __syncthreads();
            for (int e = tid; e < 1024; e += 512) {
                int slot = e >> 6, c8 = e & 63;
                int nd = ndl[slot]; int nn = (nd < 0) ? NN : nd;
                int boff = slot * 1024 + ((c8 * 16) ^ ((slot & 7) << 4));
                *(bf16x8*)(LB + boff) = cvt8(acc_h + (size_t)nn * 512 + c8 * 8);
                *(bf16x8*)(LB + 16384 + boff) = cvt8(acc_zc + (size_t)nn * 512 + c8 * 8);
            }
            __syncthreads();
            f32x4 ai = {}, ao = {}, au = {};
#pragma unroll 4
            for (int ko = 0; ko < 512; ko += 32) {
                int abo = ((ko + q * 8) * 2) ^ rsw;
                bf16x8 ah = *(const bf16x8*)(LB + r * 1024 + abo);
                bf16x8 az = *(const bf16x8*)(LB + 16384 + r * 1024 + abo);
                ai = __builtin_amdgcn_mfma_f32_16x16x32_bf16(ah, *(const bf16x8*)(pbi + ko), ai, 0, 0, 0);
                ao = __builtin_amdgcn_mfma_f32_16x16x32_bf16(ah, *(const bf16x8*)(pbo + ko), ao, 0, 0, 0);
                au = __builtin_amdgcn_mfma_f32_16x16x32_bf16(az, *(const bf16x8*)(pbu + ko), au, 0, 0, 0);
            }
            float bi_ = bfu(bio[col]), bo_ = bfu(bio[512 + col]), bu_ = bfu(bum[col]);
#pragma unroll
            for (int i2 = 0; i2 < 4; ++i2) {
                int slot = q * 4 + i2;
                int ni = ndl[slot];
                if (ni < 0) continue;
                int p = pl[slot];
                size_t pxb = (size_t)ni * PXC, nb = (size_t)ni * 512;
                float ig = sigf(bfu(px[pxb + col]) + ai[i2] + bi_);
                float og = sigf(bfu(px[pxb + 1024 + col]) + ao[i2] + bo_);
                float uu = tanhq(bfu(px[pxb + 2048 + col]) + au[i2] + bu_);
                float cc = ig * uu + acc_fc[nb + col];
                float h = og * tanhq(cc);
                G[(size_t)ni * 1536 + col] = cc;
                Gh[(size_t)ni * 3072 + 1024 + col] = f2bf(h);
                atomicAdd(&acc_h[(size_t)p * 512 + col], h);
                if (ni == 0) {
                    if (isbf) ((u16*)outv)[col] = f2bf(h);
                    else ((float*)outv)[col] = h;
                }
            }
        }
    } else {
        const u16* Wh = isbf ? Wh_o : Wh_n;
        const u16* pbi = Wh + (size_t)col * 512 + q * 8;
        const u16* pbo = Wh + (size_t)(512 + col) * 512 + q * 8;
        const u16* pbf = Wh + (size_t)(1024 + col) * 512 + q * 8;
        const u16* pbz = Wh + (size_t)(1536 + col) * 512 + q * 8;
        for (int tile = blockIdx.y; tile < ntiles; tile += GY) {
            __syncthreads();
            if (tid < 16) {
                int tr = tile * 16 + tid;
                int nd = (tr < cnt) ? order[start + tr] : -1;
                ndl[tid] = nd;
                pl[tid] = (nd >= 0) ? parent[nd] : NN;
            }
            __syncthreads();
            for (int e = tid; e < 1024; e += 512) {
                int slot = e >> 6, c8 = e & 63;
                int boff = slot * 1024 + ((c8 * 16) ^ ((slot & 7) << 4));
                *(bf16x8*)(LB + boff) = *(const bf16x8*)(HB + (size_t)pl[slot] * 512 + c8 * 8);
            }
            __syncthreads();
            f32x4 gi = {}, go = {}, gf = {}, gz = {};
#pragma unroll 4
            for (int ko = 0; ko < 512; ko += 32) {
                int abo = ((ko + q * 8) * 2) ^ rsw;
                bf16x8 a = *(const bf16x8*)(LB + r * 1024 + abo);
                gi = __builtin_amdgcn_mfma_f32_16x16x32_bf16(a, *(const bf16x8*)(pbi + ko), gi, 0, 0, 0);
                go = __builtin_amdgcn_mfma_f32_16x16x32_bf16(a, *(const bf16x8*)(pbo + ko), go, 0, 0, 0);
                gf = __builtin_amdgcn_mfma_f32_16x16x32_bf16(a, *(const bf16x8*)(pbf + ko), gf, 0, 0, 0);
                gz = __builtin_amdgcn_mfma_f32_16x16x32_bf16(a, *(const bf16x8*)(pbz + ko), gz, 0, 0, 0);
            }
            float bi_ = bfu(bh[col]), bo_ = bfu(bh[512 + col]);
            float bf_ = bfu(bh[1024 + col]), bz_ = bfu(bh[1536 + col]);
#pragma unroll
            for (int i2 = 0; i2 < 4; ++i2) {
                int slot = q * 4 + i2;
                int ni = ndl[slot];
                if (ni < 0) continue;
                int p = pl[slot];
                size_t qb = (size_t)ni * PXC, gb = (size_t)ni * 1536, nb = (size_t)ni * 512;
                float si = sigf(bfu(qx[qb + col]) + gi[i2] + bi_);
                float so = sigf(bfu(qx[qb + 512 + col]) + go[i2] + bo_);
                float sf = sigf(bfu(qx[qb + 1024 + col]) + gf[i2] + bf_);
                float zg = sigf(bfu(qx[qb + 1536 + col]) + gz[i2] + bz_);
                G[gb + col] = si;
                G[gb + 512 + col] = so;
                G[gb + 1024 + col] = sf;
                ZB[nb + col] = f2bf(zg * tanhq(Call[(size_t)p * 512 + col]));
            }
        }
    }
}

__global__ __launch_bounds__(512) void comb_s2(
    int iter,
    const int* __restrict__ order, const int* __restrict__ lvl, const int* __restrict__ parent,
    const u16* __restrict__ Wfz_o, const u16* __restrict__ Wfz_n,
    const u16* __restrict__ bfz,
    const u16* __restrict__ px,
    float* __restrict__ acc_fc, float* __restrict__ acc_zc,
    const u16* __restrict__ ZB, const u16* __restrict__ qx,
    const u16* __restrict__ Wum_o, const u16* __restrict__ Wum_n,
    const u16* __restrict__ bum,
    float* __restrict__ Call, u16* __restrict__ HB,
    float* __restrict__ G, const int* __restrict__ fcnt)
{
    __shared__ __align__(16) u16 LS[8192];
    __shared__ int ndl[16], pl[16];
    bool isbf = (*fcnt > 2048);
    int tid = threadIdx.x;
    int w = tid >> 6, lane = tid & 63;
    int r = lane & 15, q = lane >> 4;
    int rsw = (r & 7) << 4;
    int col = (blockIdx.x * 8 + w) * 16 + r;
    const u16* Gh = (const u16*)G;
    char* LB = (char*)LS;
    int Dmax = lvl[80];
    int d = blockIdx.z ? iter : (Dmax - 1 - iter);
    if (d < 0 || d >= Dmax) return;
    int start = lvl[d], cnt = lvl[d + 1] - start;
    if (cnt <= 0) return;
    int ntiles = (cnt + 15) >> 4;

    if (blockIdx.z == 0) {
        const u16* Wfz = isbf ? Wfz_o : Wfz_n;
        const u16* pbf = Wfz + (size_t)col * 512 + q * 8;
        const u16* pbz = Wfz + (size_t)(512 + col) * 512 + q * 8;
        for (int tile = blockIdx.y; tile < ntiles; tile += GY) {
            __syncthreads();
            if (tid < 16) {
                int tr = tile * 16 + tid;
                int nd = (tr < cnt) ? order[start + tr] : -1;
                ndl[tid] = nd;
                pl[tid] = (nd >= 0) ? parent[nd] : NN;
            }
            __syncthreads();
            for (int e = tid; e < 1024; e += 512) {
                int slot = e >> 6, c8 = e & 63;
                int nd = ndl[slot]; int nn = (nd < 0) ? NN : nd;
                int boff = slot * 1024 + ((c8 * 16) ^ ((slot & 7) << 4));
                *(bf16x8*)(LB + boff) = *(const bf16x8*)(Gh + (size_t)nn * 3072 + 1024 + c8 * 8);
            }
            __syncthreads();
            f32x4 af0 = {}, af1 = {}, az0 = {}, az1 = {};
#pragma unroll 4
            for (int ko = 0; ko < 256; ko += 32) {
                int ab0 = ((ko + q * 8) * 2) ^ rsw;
                int ab1 = ((ko + 256 + q * 8) * 2) ^ rsw;
                bf16x8 h0 = *(const bf16x8*)(LB + r * 1024 + ab0);
                bf16x8 h1 = *(const bf16x8*)(LB + r * 1024 + ab1);
                af0 = __builtin_amdgcn_mfma_f32_16x16x32_bf16(h0, *(const bf16x8*)(pbf + ko), af0, 0, 0, 0);
                az0 = __builtin_amdgcn_mfma_f32_16x16x32_bf16(h0, *(const bf16x8*)(pbz + ko), az0, 0, 0, 0);
                af1 = __builtin_amdgcn_mfma_f32_16x16x32_bf16(h1, *(const bf16x8*)(pbf + 256 + ko), af1, 0, 0, 0);
                az1 = __builtin_amdgcn_mfma_f32_16x16x32_bf16(h1, *(const bf16x8*)(pbz + 256 + ko), az1, 0, 0, 0);
            }
            f32x4 af = af0 + af1, az = az0 + az1;
            float bf_ = bfu(bfz[col]), bz_ = bfu(bfz[512 + col]);
#pragma unroll
            for (int i2 = 0; i2 < 4; ++i2) {
                int slot = q * 4 + i2;
                int ni = ndl[slot];
                if (ni < 0) continue;
                int p = pl[slot];
                size_t pb = (size_t)p * 512, ppx = (size_t)p * PXC;
                float cT = G[(size_t)ni * 1536 + col];
                float f = sigf(bfu(px[ppx + 512 + col]) + af[i2] + bf_);
                atomicAdd(&acc_fc[pb + col], f * cT);
                float zf = sigf(bfu(px[ppx + 1536 + col]) + az[i2] + bz_);
                atomicAdd(&acc_zc[pb + col], zf * tanhq(cT));
            }
        }
    } else {
        const u16* Wum = isbf ? Wum_o : Wum_n;
        const u16* pbu = Wum + (size_t)col * 512 + q * 8;
        for (int tile = blockIdx.y; tile < ntiles; tile += GY) {
            __syncthreads();
            if (tid < 16) {
                int tr = tile * 16 + tid;
                int nd = (tr < cnt) ? order[start + tr] : -1;
                ndl[tid] = nd;
                pl[tid] = (nd >= 0) ? parent[nd] : NN;
            }
            __syncthreads();
            for (int e = tid; e < 1024; e += 512) {
                int slot = e >> 6, c8 = e & 63;
                int nd = ndl[slot]; int nn = (nd < 0) ? NN : nd;
                int boff = slot * 1024 + ((c8 * 16) ^ ((slot & 7) << 4));
                *(bf16x8*)(LB + boff) = *(const bf16x8*)(ZB + (size_t)nn * 512 + c8 * 8);
            }
            __syncthreads();
            f32x4 a0 = {}, a1 = {}, a2 = {}, a3 = {};
#pragma unroll 4
            for (int ko = 0; ko < 128; ko += 32) {
                int b0 = ((ko + q * 8) * 2) ^ rsw;
                int b1 = ((ko + 128 + q * 8) * 2) ^ rsw;
                int b2 = ((ko + 256 + q * 8) * 2) ^ rsw;
                int b3 = ((ko + 384 + q * 8) * 2) ^ rsw;
                a0 = __builtin_amdgcn_mfma_f32_16x16x32_bf16(*(const bf16x8*)(LB + r * 1024 + b0),
                                                             *(const bf16x8*)(pbu + ko), a0, 0, 0, 0);
                a1 = __builtin_amdgcn_mfma_f32_16x16x32_bf16(*(const bf16x8*)(LB + r * 1024 + b1),
                                                             *(const bf16x8*)(pbu + 128 + ko), a1, 0, 0, 0);
                a2 = __builtin_amdgcn_mfma_f32_16x16x32_bf16(*(const bf16x8*)(LB + r * 1024 + b2),
                                                             *(const bf16x8*)(pbu + 256 + ko), a2, 0, 0, 0);
                a3 = __builtin_amdgcn_mfma_f32_16x16x32_bf16(*(const bf16x8*)(LB + r * 1024 + b3),
                                                             *(const bf16x8*)(pbu + 384 + ko), a3, 0, 0, 0);
            }
            f32x4 au = (a0 + a1) + (a2 + a3);
            float bu_ = bfu(bum[col]);
#pragma unroll
            for (int i2 = 0; i2 < 4; ++i2) {
                int slot = q * 4 + i2;
                int ni = ndl[slot];
                if (ni < 0) continue;
                int p = pl[slot];
                size_t qb = (size_t)ni * PXC, gb = (size_t)ni * 1536, nb = (size_t)ni * 512;
                float uu = tanhq(bfu(qx[qb + 2048 + col]) + au[i2] + bu_);
                float si = G[gb + col];
                float so = G[gb + 512 + col];
                float sf = G[gb + 1024 + col];
                float pc = Call[(size_t)p * 512 + col];
                float cc = si * uu + sf * pc;
                float h = so * tanhq(cc);
                Call[nb + col] = cc;
                HB[nb + col] = f2bf(h);
            }
        }
    }
}

// ---------------- final max reduce ----------------
__global__ __launch_bounds__(256) void k_maxA(const u16* __restrict__ HB, float* __restrict__ pmax) {
    int b = blockIdx.x, t = threadIdx.x;
    float m1 = -1e30f, m2 = -1e30f;
    for (int rr = b * 128; rr < b * 128 + 128; ++rr) {
        m1 = fmaxf(m1, bfu(HB[(size_t)rr * 512 + t]));
        m2 = fmaxf(m2, bfu(HB[(size_t)rr * 512 + t + 256]));
    }
    pmax[(size_t)b * 512 + t] = m1; pmax[(size_t)b * 512 + t + 256] = m2;
}
__global__ void k_maxB(const float* __restrict__ pmax, void* __restrict__ outv,
                       const int* __restrict__ fcnt) {
    int j = threadIdx.x;
    float m = -1e30f;
    for (int b = 0; b < 64; ++b) m = fmaxf(m, pmax[(size_t)b * 512 + j]);
    bool isbf = (*fcnt > 2048);
    if (isbf) ((u16*)outv)[512 + j] = f2bf(m);
    else ((float*)outv)[512 + j] = m;
}

__global__ void k_wsfail(u16* out) {
    int i = blockIdx.x * 256 + threadIdx.x;
    if (i < 1024) out[i] = f2bf(12345.f);
}

// ---------------- launch ----------------
extern "C" void kernel_launch(void* const* d_in, const int* in_sizes, int n_in,
                              void* d_out, int out_size, void* d_ws, size_t ws_size,
                              hipStream_t stream) {
    char* base = (char*)d_ws;
    u16* px = (u16*)(base + OFF_PX);
    u16* qx = (u16*)(base + OFF_QX);
    float* acc_h = (float*)(base + OFF_ACCH);
    float* acc_fc = (float*)(base + OFF_ACCF);
    float* acc_zc = (float*)(base + OFF_ACCZ);
    float* Call = (float*)(base + OFF_C);
    u16* HB = (u16*)(base + OFF_HB);
    u16* ZB = (u16*)(base + OFF_ZB);
    float* G = (float*)(base + OFF_G);
    u16* NGI = (u16*)(base + OFF_G);
    u16* NW = (u16*)(base + OFF_NW);
    int* depth = (int*)(base + OFF_DEPTH);
    int* order = (int*)(base + OFF_ORDER);
    int* counts = (int*)(base + OFF_MISC);
    int* fcnt = counts + 128;
    int* pcnt = counts + 129;
    int* lvl = (int*)(base + OFF_LVL);
    u16* NB = (u16*)(base + OFF_NB);
    int* pnorm = (int*)(base + OFF_PN);
    float* pmax = (float*)(base + OFF_PMAX);
    u32* BAR = (u32*)(base + OFF_BAR);

    const u16* in_bf   = (const u16*)d_in[0];
    const u16* csWx_o  = (const u16*)d_in[2];
    const u16* csWio_o = (const u16*)d_in[4];
    const u16* csWfz_o = (const u16*)d_in[6];
    const u16* csWum_o = (const u16*)d_in[8];
    const u16* chWx_o  = (const u16*)d_in[10];
    const u16* chWh_o  = (const u16*)d_in[12];
    const u16* chWum_o = (const u16*)d_in[14];

    if (ws_size < WS_TOTAL) { k_wsfail<<<4, 256, 0, stream>>>((u16*)d_out); return; }

    hipMemsetAsync(base + OFF_MISC, 0, 1024, stream);
    hipMemsetAsync(base + OFF_ACCH, 0, 3 * SZ_ACC, stream);   // acc_h/fc/zc (+ sentinel rows)

    // dtype detect + barrier zero + fused setup
    k_detect<<<32, 256, 0, stream>>>((const u32*)d_in[0], (const u32*)d_in[1], fcnt, pcnt, BAR);
    k_pnorm_depth<<<32, 256, 0, stream>>>((const u32*)d_in[1], pcnt, pnorm, depth, HB, Call);
    k_levels<<<1, 1024, 0, stream>>>(depth, lvl, order);

    NormSrcs srcs;
    srcs.p[0] = d_in[0];  srcs.p[1] = d_in[2];  srcs.p[2] = d_in[10]; srcs.p[3] = d_in[4];
    srcs.p[4] = d_in[6];  srcs.p[5] = d_in[8];  srcs.p[6] = d_in[12]; srcs.p[7] = d_in[14];
    srcs.p[8] = d_in[3];  srcs.p[9] = d_in[5];  srcs.p[10] = d_in[7]; srcs.p[11] = d_in[9];
    srcs.p[12] = d_in[11]; srcs.p[13] = d_in[13]; srcs.p[14] = d_in[15];
    k_norm_all<<<2048, 256, 0, stream>>>(srcs, NGI, NW, NB, fcnt);

    // input projections
    dim3 gg(PXC / 256, NN / 64, 2);
    k_gemm_in<<<gg, 256, 0, stream>>>(in_bf, NGI,
                                      csWx_o, NW + NW_CSWX, chWx_o, NW + NW_CHWX,
                                      NB + NB_CSBX, NB + NB_CHBX, px, qx, fcnt);

    // persistent level loop (round-10 shape + epilogue prefetch + release fan-out);
    // fallback: per-level kernels
    {
        const u16* nWio = NW + NW_CSWIO; const u16* nWum = NW + NW_CSWUM;
        const u16* nWfz = NW + NW_CSWFZ; const u16* nWh = NW + NW_CHWH;
        const u16* nWu2 = NW + NW_CHWUM;
        const u16* b_io = NB + NB_CSBIO; const u16* b_um = NB + NB_CSBUM;
        const u16* b_fz = NB + NB_CSBFZ; const u16* b_h = NB + NB_CHBH;
        const u16* b_u2 = NB + NB_CHBUM;
        const int* order_c = order; const int* lvl_c = lvl; const int* par_c = pnorm;
        const u16* px_c = px; const u16* qx_c = qx;
        void* outp = d_out; const int* fcnt_c = fcnt;
        u32* bar_c = BAR;
        void* margs[] = {
            (void*)&order_c, (void*)&lvl_c, (void*)&par_c,
            (void*)&acc_h, (void*)&acc_fc, (void*)&acc_zc,
            (void*)&csWio_o, (void*)&nWio, (void*)&csWum_o, (void*)&nWum,
            (void*)&csWfz_o, (void*)&nWfz,
            (void*)&b_io, (void*)&b_um, (void*)&b_fz,
            (void*)&px_c, (void*)&HB, (void*)&Call,
            (void*)&chWh_o, (void*)&nWh, (void*)&chWum_o, (void*)&nWu2,
            (void*)&b_h, (void*)&b_u2,
            (void*)&qx_c, (void*)&ZB, (void*)&G,
            (void*)&outp, (void*)&fcnt_c, (void*)&bar_c
        };
        hipError_t ce = hipLaunchCooperativeKernel((const void*)comb_mega8,
                                                   dim3(256), dim3(512), margs, 0, stream);
        if (ce != hipSuccess) {
            (void)hipGetLastError();
            dim3 gl(4, GY, 2);
            for (int i = 0; i < MAXD; ++i) {
                comb_s1<<<gl, 512, 0, stream>>>(i, order, lvl, pnorm,
                                                acc_h, acc_fc, acc_zc,
                                                csWio_o, NW + NW_CSWIO, csWum_o, NW + NW_CSWUM,
                                                NB + NB_CSBIO, NB + NB_CSBUM, px,
                                                HB, Call, chWh_o, NW + NW_CHWH, NB + NB_CHBH,
                                                qx, ZB, G, d_out, fcnt);
                comb_s2<<<gl, 512, 0, stream>>>(i, order, lvl, pnorm,
                                                csWfz_o, NW + NW_CSWFZ, NB + NB_CSBFZ, px,
                                                acc_fc, acc_zc,
                                                ZB, qx, chWum_o, NW + NW_CHWUM, NB + NB_CHBUM,
                                                Call, HB, G, fcnt);
            }
        }
    }

    // brep
    k_maxA<<<64, 256, 0, stream>>>(HB, pmax);
    k_maxB<<<1, 512, 0, stream>>>(pmax, d_out, fcnt);
}

// Round 13
// 1121.150 us; speedup vs baseline: 2.3836x; 1.0057x over previous
//
#include <hip/hip_runtime.h>
#include <hip/hip_cooperative_groups.h>
#include <hip/hip_bf16.h>

typedef unsigned short u16;
typedef unsigned int u32;
typedef unsigned long long u64;

#define NN 8192
#define PXC 2560
#define MAXD 36
#define GY 64
#define GYM 32

typedef __attribute__((ext_vector_type(8))) short bf16x8;
typedef __attribute__((ext_vector_type(4))) float f32x4;

// ---------------- workspace layout (bytes) ----------------
static constexpr size_t SZ_PX  = (size_t)(NN + 1) * PXC * 2;
static constexpr size_t SZ_ACC = (size_t)(NN + 1) * 512 * 4;
static constexpr size_t SZ_HB  = (size_t)(NN + 1) * 512 * 2;
static constexpr size_t SZ_G   = (size_t)(NN + 1) * 1536 * 4;
static constexpr size_t SZ_NW  = (size_t)5242880 * 2;

static constexpr size_t OFF_PX    = 0;
static constexpr size_t OFF_QX    = OFF_PX + SZ_PX;
static constexpr size_t OFF_ACCH  = OFF_QX + SZ_PX;
static constexpr size_t OFF_ACCF  = OFF_ACCH + SZ_ACC;
static constexpr size_t OFF_ACCZ  = OFF_ACCF + SZ_ACC;
static constexpr size_t OFF_C     = OFF_ACCZ + SZ_ACC;         // c_all (chain), f32
static constexpr size_t OFF_HB    = OFF_C + SZ_ACC;            // h_all (chain), bf16
static constexpr size_t OFF_ZB    = OFF_HB + SZ_HB;            // chain ZB, bf16
static constexpr size_t OFF_G     = OFF_ZB + SZ_HB;            // per-node scratch / transient normalized inputs
static constexpr size_t OFF_NW    = OFF_G + SZ_G;
static constexpr size_t OFF_DEPTH = OFF_NW + SZ_NW;
static constexpr size_t OFF_ORDER = OFF_DEPTH + (size_t)NN * 4;
static constexpr size_t OFF_MISC  = OFF_ORDER + (size_t)NN * 4;
static constexpr size_t OFF_LVL   = OFF_MISC + 1024;
static constexpr size_t OFF_NB    = OFF_LVL + 512;
static constexpr size_t OFF_PN    = OFF_NB + 20480;
static constexpr size_t OFF_PMAX  = OFF_PN + (size_t)NN * 4;
static constexpr size_t OFF_BAR   = OFF_PMAX + (size_t)128 * 512 * 4;
static constexpr size_t WS_TOTAL  = OFF_BAR + 32768;

#define NW_CSWX  0
#define NW_CHWX  1310720
#define NW_CSWIO 2621440
#define NW_CSWFZ 3145728
#define NW_CSWUM 3670016
#define NW_CHWH  3932160
#define NW_CHWUM 4980736

#define NB_CSBX  0
#define NB_CSBIO 2560
#define NB_CSBFZ 3584
#define NB_CSBUM 4608
#define NB_CHBX  5120
#define NB_CHBH  7680
#define NB_CHBUM 9728

// ---------------- helpers ----------------
__device__ __forceinline__ float bfu(u16 u) { return __uint_as_float(((u32)u) << 16); }
__device__ __forceinline__ u16 f2bf(float f) {
    u32 u = __float_as_uint(f);
    u += 0x7fffu + ((u >> 16) & 1u);
    return (u16)(u >> 16);
}
__device__ __forceinline__ float sigf(float x) {
    x = fminf(fmaxf(x, -30.f), 30.f);
    return 1.f / (1.f + __expf(-x));
}
__device__ __forceinline__ float tanhq(float x) {
    x = fminf(fmaxf(x, -15.f), 15.f);
    return 1.f - 2.f / (__expf(2.f * x) + 1.f);
}
__device__ __forceinline__ bf16x8 cvt8(const float* p) {
    float4 a = *(const float4*)p;
    float4 b = *(const float4*)(p + 4);
    union { u32 u[4]; bf16x8 v; } r;
    r.u[0] = ((__float_as_uint(a.x) + 0x8000u) >> 16) | ((__float_as_uint(a.y) + 0x8000u) & 0xffff0000u);
    r.u[1] = ((__float_as_uint(a.z) + 0x8000u) >> 16) | ((__float_as_uint(a.w) + 0x8000u) & 0xffff0000u);
    r.u[2] = ((__float_as_uint(b.x) + 0x8000u) >> 16) | ((__float_as_uint(b.y) + 0x8000u) & 0xffff0000u);
    r.u[3] = ((__float_as_uint(b.z) + 0x8000u) >> 16) | ((__float_as_uint(b.w) + 0x8000u) & 0xffff0000u);
    return r.v;
}

// -------- agent-scope (XCD-coherent) accessors for mutable state --------
__device__ __forceinline__ u64 cld64(const void* p) {
    return __hip_atomic_load((const u64*)p, __ATOMIC_RELAXED, __HIP_MEMORY_SCOPE_AGENT);
}
__device__ __forceinline__ float cldf(const float* p) {
    return __hip_atomic_load(p, __ATOMIC_RELAXED, __HIP_MEMORY_SCOPE_AGENT);
}
__device__ __forceinline__ void cstf(float* p, float v) {
    __hip_atomic_store(p, v, __ATOMIC_RELAXED, __HIP_MEMORY_SCOPE_AGENT);
}
__device__ __forceinline__ void cst16(u16* p, u16 v) {
    __hip_atomic_store(p, v, __ATOMIC_RELAXED, __HIP_MEMORY_SCOPE_AGENT);
}
__device__ __forceinline__ bf16x8 cvt8a(const float* p) {  // 32B f32 coherent load -> bf16x8
    union { u64 u; u32 w[2]; } a, b, c, d;
    a.u = cld64(p); b.u = cld64(p + 2); c.u = cld64(p + 4); d.u = cld64(p + 6);
    union { u32 u[4]; bf16x8 v; } r;
    r.u[0] = ((a.w[0] + 0x8000u) >> 16) | ((a.w[1] + 0x8000u) & 0xffff0000u);
    r.u[1] = ((b.w[0] + 0x8000u) >> 16) | ((b.w[1] + 0x8000u) & 0xffff0000u);
    r.u[2] = ((c.w[0] + 0x8000u) >> 16) | ((c.w[1] + 0x8000u) & 0xffff0000u);
    r.u[3] = ((d.w[0] + 0x8000u) >> 16) | ((d.w[1] + 0x8000u) & 0xffff0000u);
    return r.v;
}

// ---- PER-PLANE contention-free barrier (128 blocks/plane), monotonic flags ----
// Planes are fully disjoint in mega9 (cs: acc_*/px/Gh/out[0:512]; ch: HB/Call/ZB/qx),
// so each plane syncs only its own 128 blocks: anti-correlated level sizes overlap
// instead of lockstep-stalling each other (makespan Σmax -> max(Σ,Σ)).
// Arrival: one relaxed store per block. Plane leader (bid==z) polls its plane's 128
// flags in parallel, then fans release across 8 per-plane 64B-spaced copies.
__device__ __forceinline__ void plane_bar(u32* B, int z, int bid, u32 tgt) {
    __syncthreads();                       // all waves drain their stores here
    int tid = threadIdx.x;
    if (tid == 0)
        __hip_atomic_store(B + 16 + bid * 16, tgt, __ATOMIC_RELAXED, __HIP_MEMORY_SCOPE_AGENT);
    if ((int)blockIdx.x == z) {            // plane leader: bid 0 (z=0) / bid 1 (z=1)
        if (tid < 128) {
            while (__hip_atomic_load(B + 16 + (2 * tid + z) * 16, __ATOMIC_RELAXED, __HIP_MEMORY_SCOPE_AGENT) < tgt)
                __builtin_amdgcn_s_sleep(1);
        }
        __syncthreads();
        if (tid < 8)
            __hip_atomic_store(B + 4608 + z * 128 + tid * 16, tgt, __ATOMIC_RELAXED, __HIP_MEMORY_SCOPE_AGENT);
    }
    if (tid == 0) {
        while (__hip_atomic_load(B + 4608 + z * 128 + (((u32)bid >> 3) & 7) * 16, __ATOMIC_RELAXED, __HIP_MEMORY_SCOPE_AGENT) < tgt)
            __builtin_amdgcn_s_sleep(1);
        asm volatile("" ::: "memory");
    }
    __syncthreads();
}

// 4-sibling mini-barrier: 4 private flags (16B apart), monotonic; no RMW.
__device__ __forceinline__ void mini_bar(u32* MF, int cgi, u32 tgt) {
    __syncthreads();                       // drains this block's stores
    if (threadIdx.x == 0) {
        __hip_atomic_store(MF + cgi * 4, tgt, __ATOMIC_RELAXED, __HIP_MEMORY_SCOPE_AGENT);
        for (;;) {
            u32 a = __hip_atomic_load(MF + 0,  __ATOMIC_RELAXED, __HIP_MEMORY_SCOPE_AGENT);
            u32 b = __hip_atomic_load(MF + 4,  __ATOMIC_RELAXED, __HIP_MEMORY_SCOPE_AGENT);
            u32 c = __hip_atomic_load(MF + 8,  __ATOMIC_RELAXED, __HIP_MEMORY_SCOPE_AGENT);
            u32 d = __hip_atomic_load(MF + 12, __ATOMIC_RELAXED, __HIP_MEMORY_SCOPE_AGENT);
            if (a >= tgt && b >= tgt && c >= tgt && d >= tgt) break;
            __builtin_amdgcn_s_sleep(1);
        }
        asm volatile("" ::: "memory");
    }
    __syncthreads();
}

// ---------------- dtype detection (+ barrier zeroing) ----------------
__global__ void k_detect(const u32* __restrict__ fin, const u32* __restrict__ pin,
                         int* __restrict__ fcnt, int* __restrict__ pcnt,
                         u32* __restrict__ barz) {
    int i = blockIdx.x * 256 + threadIdx.x;
    if (i < 8192) barz[i] = 0u;
    if (i < 4096) {
        u32 w = fin[i];
        int e = (w >> 7) & 0xFF;
        if (w != 0u && e >= 0x70 && e <= 0x8F) atomicAdd(fcnt, 1);
    }
    if (i >= 1 && i < 4096) {
        if (pin[2 * i - 1] != 0u) atomicAdd(pcnt, 1);
    }
}

// fused: parent normalize + depth chase + sentinel-row init
__global__ void k_pnorm_depth(const u32* __restrict__ pin, const int* __restrict__ pcnt,
                              int* __restrict__ pnorm, int* __restrict__ depth,
                              u16* __restrict__ HB, float* __restrict__ Call) {
    int i = blockIdx.x * 256 + threadIdx.x;
    if (i < 512) {
        HB[(size_t)NN * 512 + i] = 0;
        Call[(size_t)NN * 512 + i] = 0.f;
    }
    if (i >= NN) return;
    bool is64 = (*pcnt < 100);
    int p = (int)(is64 ? pin[2 * i] : pin[i]);
    pnorm[i] = p;
    int d = 0;
    while (p != NN && p >= 0 && p < NN && d < 9000) {
        d++;
        p = (int)(is64 ? pin[2 * p] : pin[p]);
    }
    depth[i] = d;
}

// fused hist + scan + scatter, single block; also computes D* -> lvl[80]
__global__ __launch_bounds__(1024) void k_levels(const int* __restrict__ depth,
                                                 int* __restrict__ lvl, int* __restrict__ order) {
    __shared__ int cnts[64];
    __shared__ int cur[64];
    int t = threadIdx.x;
    if (t < 64) cnts[t] = 0;
    __syncthreads();
    for (int i = t; i < NN; i += 1024) {
        int d = depth[i]; if (d > 63) d = 63;
        atomicAdd(&cnts[d], 1);
    }
    __syncthreads();
    if (t == 0) {
        int s = 0; lvl[0] = 0;
        for (int d = 0; d < 64; ++d) { cur[d] = s; s += cnts[d]; lvl[d + 1] = s; }
        int D = 1;
        for (int d = 63; d >= 0; --d) if (cnts[d] > 0) { D = d + 1; break; }
        lvl[80] = D;                        // number of nonempty levels
    }
    __syncthreads();
    for (int i = t; i < NN; i += 1024) {
        int d = depth[i]; if (d > 63) d = 63;
        int pos = atomicAdd(&cur[d], 1);
        order[pos] = i;
    }
}

struct NormSrcs { const void* p[15]; };
__global__ __launch_bounds__(256) void k_norm_all(NormSrcs s, u16* __restrict__ NGI,
                                                  u16* __restrict__ NW, u16* __restrict__ NB,
                                                  const int* __restrict__ fcnt) {
    const int cum[16] = {0, 1048576, 1376256, 1703936, 1835008, 1966080, 2031616, 2293760,
                         2359296, 2359936, 2360192, 2360448, 2360576, 2361216, 2361728, 2361856};
    const int dof[15] = {0, NW_CSWX / 4, NW_CHWX / 4, NW_CSWIO / 4, NW_CSWFZ / 4, NW_CSWUM / 4,
                         NW_CHWH / 4, NW_CHWUM / 4, NB_CSBX / 4, NB_CSBIO / 4, NB_CSBFZ / 4,
                         NB_CSBUM / 4, NB_CHBX / 4, NB_CHBH / 4, NB_CHBUM / 4};
    bool isbf = (*fcnt > 2048);
    int total = 2361856;
    int istart = isbf ? cum[8] : 0;
    for (int i = istart + blockIdx.x * 256 + threadIdx.x; i < total; i += gridDim.x * 256) {
        int seg = 0;
#pragma unroll
        for (int k = 1; k < 15; ++k) if (i >= cum[k]) seg = k;
        int off = i - cum[seg];
        u16* dbase = (seg == 0) ? NGI : (seg < 8 ? NW : NB);
        ushort4* dst = (ushort4*)dbase + dof[seg] + off;
        if (isbf) {
            *dst = ((const ushort4*)s.p[seg])[off];
        } else {
            float4 v = ((const float4*)s.p[seg])[off];
            ushort4 o; o.x = f2bf(v.x); o.y = f2bf(v.y); o.z = f2bf(v.z); o.w = f2bf(v.w);
            *dst = o;
        }
    }
}

// ---------------- input-projection GEMM ----------------
#define ASTR 528
__global__ __launch_bounds__(256) void k_gemm_in(
    const u16* __restrict__ Ao, const u16* __restrict__ An,
    const u16* __restrict__ Wcs_o, const u16* __restrict__ Wcs_n,
    const u16* __restrict__ Wch_o, const u16* __restrict__ Wch_n,
    const u16* __restrict__ bcs, const u16* __restrict__ bch,
    u16* __restrict__ Ccs, u16* __restrict__ Cch,
    const int* __restrict__ fcnt)
{
    __shared__ __align__(16) u16 AS[64 * ASTR];
    bool isbf = (*fcnt > 2048);
    int z = blockIdx.z;
    const u16* A = isbf ? Ao : An;
    const u16* W = z ? (isbf ? Wch_o : Wch_n) : (isbf ? Wcs_o : Wcs_n);
    const u16* bias = z ? bch : bcs;
    u16* C = z ? Cch : Ccs;

    int m0 = blockIdx.y * 64;
    for (int e = threadIdx.x; e < 64 * 64; e += 256) {
        int row = e >> 6, c8 = e & 63;
        *(uint4*)&AS[row * ASTR + c8 * 8] = *(const uint4*)(A + (size_t)(m0 + row) * 512 + c8 * 8);
    }
    __syncthreads();

    int wv = threadIdx.x >> 6;
    int lane = threadIdx.x & 63;
    int r = lane & 15, q = lane >> 4;
    int n0 = blockIdx.x * 256 + wv * 64;
    const u16* pb[4];
#pragma unroll
    for (int jt = 0; jt < 4; ++jt) pb[jt] = W + (size_t)(n0 + jt * 16 + r) * 512 + q * 8;
    f32x4 acc[4][4] = {};
#pragma unroll 2
    for (int k0 = 0; k0 < 512; k0 += 32) {
        bf16x8 a[4], b[4];
#pragma unroll
        for (int mi = 0; mi < 4; ++mi)
            a[mi] = *(const bf16x8*)&AS[(mi * 16 + r) * ASTR + k0 + q * 8];
#pragma unroll
        for (int jt = 0; jt < 4; ++jt) b[jt] = *(const bf16x8*)(pb[jt] + k0);
#pragma unroll
        for (int mi = 0; mi < 4; ++mi)
#pragma unroll
            for (int jt = 0; jt < 4; ++jt)
                acc[mi][jt] = __builtin_amdgcn_mfma_f32_16x16x32_bf16(a[mi], b[jt], acc[mi][jt], 0, 0, 0);
    }
#pragma unroll
    for (int jt = 0; jt < 4; ++jt) {
        int c = n0 + jt * 16 + r;
        float bv = bfu(bias[c]);
#pragma unroll
        for (int mi = 0; mi < 4; ++mi) {
            size_t b0 = (size_t)(m0 + mi * 16 + q * 4) * PXC + c;
#pragma unroll
            for (int i = 0; i < 4; ++i)
                C[b0 + (size_t)i * PXC] = f2bf(acc[mi][jt][i] + bv);
        }
    }
}

// ================= persistent level loop: round-12 verified shape + PER-PLANE barriers =================
// bid: z=bid&1 plane, cgi=(bid>>1)&3 col slice, ty=bid>>3 (0..31).
// Per tile: s1 -> 4-sibling mini-barrier -> s2.  ONE per-plane barrier per level.
// Planes are state-disjoint (cs: acc_*/px/Gh; ch: HB/Call/ZB/qx) and drift freely.
__global__ __launch_bounds__(512, 2) void comb_mega9(
    const int* __restrict__ order, const int* __restrict__ lvl, const int* __restrict__ parent,
    float* __restrict__ acc_h, float* __restrict__ acc_fc, float* __restrict__ acc_zc,
    const u16* __restrict__ Wio_o, const u16* __restrict__ Wio_n,
    const u16* __restrict__ Wum_o, const u16* __restrict__ Wum_n,
    const u16* __restrict__ Wfz_o, const u16* __restrict__ Wfz_n,
    const u16* __restrict__ bio, const u16* __restrict__ bum, const u16* __restrict__ bfz,
    const u16* __restrict__ px,
    u16* __restrict__ HB, float* __restrict__ Call,
    const u16* __restrict__ Wh_o, const u16* __restrict__ Wh_n,
    const u16* __restrict__ Wu2_o, const u16* __restrict__ Wu2_n,
    const u16* __restrict__ bh, const u16* __restrict__ bu2,
    const u16* __restrict__ qx, u16* __restrict__ ZB,
    float* __restrict__ G,
    void* __restrict__ outv, const int* __restrict__ fcnt,
    u32* __restrict__ BAR)
{
    __shared__ __align__(16) u16 LS[16384];   // 32KB: 2 x [16][512] bf16 panels
    __shared__ int ndl[16], pl[16];
    bool isbf = (*fcnt > 2048);
    int tid = threadIdx.x;
    int w = tid >> 6, lane = tid & 63;
    int r = lane & 15, q = lane >> 4;
    int rsw = (r & 7) << 4;
    int bid = blockIdx.x;
    int z = bid & 1;
    int cgi = (bid >> 1) & 3;
    int ty = bid >> 3;                        // 0..31
    int col = (cgi * 8 + w) * 16 + r;
    u16* Gh = (u16*)G;
    char* LB = (char*)LS;
    int Dmax = lvl[80];
    u32* MF = BAR + 5120 + (size_t)((z << 5) + ty) * 16;  // 4 flags, 16B apart
    u32 tgt = 0, mtgt = 0;

    // hoisted plane invariants
    const u16 *p1a, *p1b, *p1c, *p1d;
    const u16 *p2a, *p2b;
    float ba, bb, bc, bd, be;
    if (z == 0) {
        const u16* Wio = isbf ? Wio_o : Wio_n;
        const u16* Wum = isbf ? Wum_o : Wum_n;
        const u16* Wfz = isbf ? Wfz_o : Wfz_n;
        p1a = Wio + (size_t)col * 512 + q * 8;
        p1b = Wio + (size_t)(512 + col) * 512 + q * 8;
        p1c = Wum + (size_t)col * 512 + q * 8;
        p1d = p1c;
        p2a = Wfz + (size_t)col * 512 + q * 8;
        p2b = Wfz + (size_t)(512 + col) * 512 + q * 8;
        ba = bfu(bio[col]); bb = bfu(bio[512 + col]); bc = bfu(bum[col]);
        bd = bfu(bfz[col]); be = bfu(bfz[512 + col]);
    } else {
        const u16* Wh = isbf ? Wh_o : Wh_n;
        const u16* Wu = isbf ? Wu2_o : Wu2_n;
        p1a = Wh + (size_t)col * 512 + q * 8;
        p1b = Wh + (size_t)(512 + col) * 512 + q * 8;
        p1c = Wh + (size_t)(1024 + col) * 512 + q * 8;
        p1d = Wh + (size_t)(1536 + col) * 512 + q * 8;
        p2a = Wu + (size_t)col * 512 + q * 8;
        p2b = p2a;
        ba = bfu(bh[col]); bb = bfu(bh[512 + col]);
        bc = bfu(bh[1024 + col]); bd = bfu(bh[1536 + col]);
        be = bfu(bu2[col]);
    }

    for (int it = 0; it < Dmax; ++it) {
        int d = z ? it : (Dmax - 1 - it);
        int start = lvl[d], cnt = lvl[d + 1] - start;
        int ntiles = (cnt + 15) >> 4;

        for (int tile = ty; tile < ntiles; tile += GYM) {
            __syncthreads();
            if (tid < 16) {
                int tr = tile * 16 + tid;
                int nd = (tr < cnt) ? order[start + tr] : -1;
                ndl[tid] = nd;
                pl[tid] = (nd >= 0) ? parent[nd] : NN;
            }
            __syncthreads();

            if (z == 0) {
                // -------- prefetch all epilogue operands (node px i/o/u, acc_fc; parent px f/z) --------
                float pfi[4], pfo[4], pfu[4], pfc[4], pff[4], pfz[4];
#pragma unroll
                for (int i2 = 0; i2 < 4; ++i2) {
                    int slot = q * 4 + i2;
                    int ni = ndl[slot]; int p = pl[slot];
                    int nn = (ni < 0) ? NN : ni;
                    size_t pxb = (size_t)nn * PXC, nb = (size_t)nn * 512;
                    size_t ppx = (size_t)p * PXC;
                    pfi[i2] = bfu(px[pxb + col]);
                    pfo[i2] = bfu(px[pxb + 1024 + col]);
                    pfu[i2] = bfu(px[pxb + 2048 + col]);
                    pfc[i2] = cldf(acc_fc + nb + col);
                    pff[i2] = bfu(px[ppx + 512 + col]);
                    pfz[i2] = bfu(px[ppx + 1536 + col]);
                }
                // ---------- cs s1: stage AH/AZ (sc1; atomic-fed), gates i,o,u -> c(reg), h->Gh ----------
                for (int e = tid; e < 1024; e += 512) {
                    int slot = e >> 6, c8 = e & 63;
                    int nd = ndl[slot]; int nn = (nd < 0) ? NN : nd;
                    int boff = slot * 1024 + ((c8 * 16) ^ ((slot & 7) << 4));
                    *(bf16x8*)(LB + boff) = cvt8a(acc_h + (size_t)nn * 512 + c8 * 8);
                    *(bf16x8*)(LB + 16384 + boff) = cvt8a(acc_zc + (size_t)nn * 512 + c8 * 8);
                }
                __syncthreads();
                f32x4 ai = {}, ao = {}, au = {};
#pragma unroll 4
                for (int ko = 0; ko < 512; ko += 32) {
                    int abo = ((ko + q * 8) * 2) ^ rsw;
                    bf16x8 ah = *(const bf16x8*)(LB + r * 1024 + abo);
                    bf16x8 az = *(const bf16x8*)(LB + 16384 + r * 1024 + abo);
                    ai = __builtin_amdgcn_mfma_f32_16x16x32_bf16(ah, *(const bf16x8*)(p1a + ko), ai, 0, 0, 0);
                    ao = __builtin_amdgcn_mfma_f32_16x16x32_bf16(ah, *(const bf16x8*)(p1b + ko), ao, 0, 0, 0);
                    au = __builtin_amdgcn_mfma_f32_16x16x32_bf16(az, *(const bf16x8*)(p1c + ko), au, 0, 0, 0);
                }
                float ccv[4];
#pragma unroll
                for (int i2 = 0; i2 < 4; ++i2) {
                    int slot = q * 4 + i2;
                    int ni = ndl[slot];
                    ccv[i2] = 0.f;
                    if (ni < 0) continue;
                    int p = pl[slot];
                    float ig = sigf(pfi[i2] + ai[i2] + ba);
                    float og = sigf(pfo[i2] + ao[i2] + bb);
                    float uu = tanhq(pfu[i2] + au[i2] + bc);
                    float cc = ig * uu + pfc[i2];
                    float h = og * tanhq(cc);
                    ccv[i2] = cc;
                    cst16(&Gh[(size_t)ni * 3072 + 1024 + col], f2bf(h));
                    atomicAdd(&acc_h[(size_t)p * 512 + col], h);
                    if (ni == 0) {
                        if (isbf) ((u16*)outv)[col] = f2bf(h);
                        else ((float*)outv)[col] = h;
                    }
                }
                ++mtgt; mini_bar(MF, cgi, mtgt);
                // ---------- cs s2: stage HT (plain; rows written once, pre-mini-bar), f,z -> scatter ----------
                for (int e = tid; e < 1024; e += 512) {
                    int slot = e >> 6, c8 = e & 63;
                    int nd = ndl[slot]; int nn = (nd < 0) ? NN : nd;
                    int boff = slot * 1024 + ((c8 * 16) ^ ((slot & 7) << 4));
                    *(bf16x8*)(LB + boff) = *(const bf16x8*)(Gh + (size_t)nn * 3072 + 1024 + c8 * 8);
                }
                __syncthreads();
                f32x4 af0 = {}, af1 = {}, az0 = {}, az1 = {};
#pragma unroll 4
                for (int ko = 0; ko < 256; ko += 32) {
                    int ab0 = ((ko + q * 8) * 2) ^ rsw;
                    int ab1 = ((ko + 256 + q * 8) * 2) ^ rsw;
                    bf16x8 h0 = *(const bf16x8*)(LB + r * 1024 + ab0);
                    bf16x8 h1 = *(const bf16x8*)(LB + r * 1024 + ab1);
                    af0 = __builtin_amdgcn_mfma_f32_16x16x32_bf16(h0, *(const bf16x8*)(p2a + ko), af0, 0, 0, 0);
                    az0 = __builtin_amdgcn_mfma_f32_16x16x32_bf16(h0, *(const bf16x8*)(p2b + ko), az0, 0, 0, 0);
                    af1 = __builtin_amdgcn_mfma_f32_16x16x32_bf16(h1, *(const bf16x8*)(p2a + 256 + ko), af1, 0, 0, 0);
                    az1 = __builtin_amdgcn_mfma_f32_16x16x32_bf16(h1, *(const bf16x8*)(p2b + 256 + ko), az1, 0, 0, 0);
                }
                f32x4 af = af0 + af1, az = az0 + az1;
#pragma unroll
                for (int i2 = 0; i2 < 4; ++i2) {
                    int slot = q * 4 + i2;
                    int ni = ndl[slot];
                    if (ni < 0) continue;
                    int p = pl[slot];
                    size_t pb = (size_t)p * 512;
                    float cT = ccv[i2];
                    float f = sigf(pff[i2] + af[i2] + bd);
                    atomicAdd(&acc_fc[pb + col], f * cT);
                    float zf = sigf(pfz[i2] + az[i2] + be);
                    atomicAdd(&acc_zc[pb + col], zf * tanhq(cT));
                }
            } else {
                // -------- prefetch all epilogue operands (node qx i/o/f/z/u; parent Call) --------
                float pqi[4], pqo[4], pqf[4], pqz[4], pqu[4], ppc[4];
#pragma unroll
                for (int i2 = 0; i2 < 4; ++i2) {
                    int slot = q * 4 + i2;
                    int ni = ndl[slot]; int p = pl[slot];
                    int nn = (ni < 0) ? NN : ni;
                    size_t qb = (size_t)nn * PXC;
                    pqi[i2] = bfu(qx[qb + col]);
                    pqo[i2] = bfu(qx[qb + 512 + col]);
                    pqf[i2] = bfu(qx[qb + 1024 + col]);
                    pqz[i2] = bfu(qx[qb + 1536 + col]);
                    pqu[i2] = bfu(qx[qb + 2048 + col]);
                    ppc[i2] = Call[(size_t)p * 512 + col];   // write-once + reuse: plain
                }
                // ---------- ch s1: stage AP=HB[parent] (plain), gates i,o,f,z -> regs; ZB ----------
                for (int e = tid; e < 1024; e += 512) {
                    int slot = e >> 6, c8 = e & 63;
                    int boff = slot * 1024 + ((c8 * 16) ^ ((slot & 7) << 4));
                    *(bf16x8*)(LB + boff) = *(const bf16x8*)(HB + (size_t)pl[slot] * 512 + c8 * 8);
                }
                __syncthreads();
                f32x4 gi = {}, go = {}, gf = {}, gz = {};
#pragma unroll 4
                for (int ko = 0; ko < 512; ko += 32) {
                    int abo = ((ko + q * 8) * 2) ^ rsw;
                    bf16x8 a = *(const bf16x8*)(LB + r * 1024 + abo);
                    gi = __builtin_amdgcn_mfma_f32_16x16x32_bf16(a, *(const bf16x8*)(p1a + ko), gi, 0, 0, 0);
                    go = __builtin_amdgcn_mfma_f32_16x16x32_bf16(a, *(const bf16x8*)(p1b + ko), go, 0, 0, 0);
                    gf = __builtin_amdgcn_mfma_f32_16x16x32_bf16(a, *(const bf16x8*)(p1c + ko), gf, 0, 0, 0);
                    gz = __builtin_amdgcn_mfma_f32_16x16x32_bf16(a, *(const bf16x8*)(p1d + ko), gz, 0, 0, 0);
                }
                float siR[4], soR[4], sfR[4];
#pragma unroll
                for (int i2 = 0; i2 < 4; ++i2) {
                    int slot = q * 4 + i2;
                    int ni = ndl[slot];
                    siR[i2] = 0.f; soR[i2] = 0.f; sfR[i2] = 0.f;
                    if (ni < 0) continue;
                    size_t nb = (size_t)ni * 512;
                    float si = sigf(pqi[i2] + gi[i2] + ba);
                    float so = sigf(pqo[i2] + go[i2] + bb);
                    float sf = sigf(pqf[i2] + gf[i2] + bc);
                    float zg = sigf(pqz[i2] + gz[i2] + bd);
                    siR[i2] = si; soR[i2] = so; sfR[i2] = sf;
                    cst16(&ZB[nb + col], f2bf(zg * tanhq(ppc[i2])));
                }
                ++mtgt; mini_bar(MF, cgi, mtgt);
                // ---------- ch s2: stage ZT (plain; written pre-mini-bar), u gate -> c,h ----------
                for (int e = tid; e < 1024; e += 512) {
                    int slot = e >> 6, c8 = e & 63;
                    int nd = ndl[slot]; int nn = (nd < 0) ? NN : nd;
                    int boff = slot * 1024 + ((c8 * 16) ^ ((slot & 7) << 4));
                    *(bf16x8*)(LB + boff) = *(const bf16x8*)(ZB + (size_t)nn * 512 + c8 * 8);
                }
                __syncthreads();
                f32x4 a0 = {}, a1 = {}, a2 = {}, a3 = {};
#pragma unroll 4
                for (int ko = 0; ko < 128; ko += 32) {
                    int b0 = ((ko + q * 8) * 2) ^ rsw;
                    int b1 = ((ko + 128 + q * 8) * 2) ^ rsw;
                    int b2 = ((ko + 256 + q * 8) * 2) ^ rsw;
                    int b3 = ((ko + 384 + q * 8) * 2) ^ rsw;
                    a0 = __builtin_amdgcn_mfma_f32_16x16x32_bf16(*(const bf16x8*)(LB + r * 1024 + b0),
                                                                 *(const bf16x8*)(p2a + ko), a0, 0, 0, 0);
                    a1 = __builtin_amdgcn_mfma_f32_16x16x32_bf16(*(const bf16x8*)(LB + r * 1024 + b1),
                                                                 *(const bf16x8*)(p2a + 128 + ko), a1, 0, 0, 0);
                    a2 = __builtin_amdgcn_mfma_f32_16x16x32_bf16(*(const bf16x8*)(LB + r * 1024 + b2),
                                                                 *(const bf16x8*)(p2a + 256 + ko), a2, 0, 0, 0);
                    a3 = __builtin_amdgcn_mfma_f32_16x16x32_bf16(*(const bf16x8*)(LB + r * 1024 + b3),
                                                                 *(const bf16x8*)(p2a + 384 + ko), a3, 0, 0, 0);
                }
                f32x4 auv = (a0 + a1) + (a2 + a3);
#pragma unroll
                for (int i2 = 0; i2 < 4; ++i2) {
                    int slot = q * 4 + i2;
                    int ni = ndl[slot];
                    if (ni < 0) continue;
                    size_t nb = (size_t)ni * 512;
                    float uu = tanhq(pqu[i2] + auv[i2] + be);
                    float cc = siR[i2] * uu + sfR[i2] * ppc[i2];
                    float h = soR[i2] * tanhq(cc);
                    cstf(&Call[nb + col], cc);
                    cst16(&HB[nb + col], f2bf(h));
                }
            }
        }
        ++tgt; plane_bar(BAR, z, bid, tgt);
    }
}

// ---------------- fallback per-level kernels (round-3, verified) ----------------
__global__ __launch_bounds__(512) void comb_s1(
    int iter,
    const int* __restrict__ order, const int* __restrict__ lvl, const int* __restrict__ parent,
    float* acc_h, const float* __restrict__ acc_fc, const float* __restrict__ acc_zc,
    const u16* __restrict__ Wio_o, const u16* __restrict__ Wio_n,
    const u16* __restrict__ Wum_o, const u16* __restrict__ Wum_n,
    const u16* __restrict__ bio, const u16* __restrict__ bum,
    const u16* __restrict__ px,
    const u16* __restrict__ HB, const float* __restrict__ Call,
    const u16* __restrict__ Wh_o, const u16* __restrict__ Wh_n,
    const u16* __restrict__ bh,
    const u16* __restrict__ qx, u16* __restrict__ ZB,
    float* __restrict__ G,
    void* __restrict__ outv, const int* __restrict__ fcnt)
{
    __shared__ __align__(16) u16 LS[16384];
    __shared__ int ndl[16], pl[16];
    bool isbf = (*fcnt > 2048);
    int tid = threadIdx.x;
    int w = tid >> 6, lane = tid & 63;
    int r = lane & 15, q = lane >> 4;
    int rsw = (r & 7) << 4;
    int col = (blockIdx.x * 8 + w) * 16 + r;
    u16* Gh = (u16*)G;
    char* LB = (char*)LS;
    int Dmax = lvl[80];
    int d = blockIdx.z ? iter : (Dmax - 1 - iter);
    if (d < 0 || d >= Dmax) return;
    int start = lvl[d], cnt = lvl[d + 1] - start;
    if (cnt <= 0) return;
    int ntiles = (cnt + 15) >> 4;

    if (blockIdx.z == 0) {
        const u16* Wio = isbf ? Wio_o : Wio_n;
        const u16* Wum = isbf ? Wum_o : Wum_n;
        const u16* pbi = Wio + (size_t)col * 512 + q * 8;
        const u16* pbo = Wio + (size_t)(512 + col) * 512 + q * 8;
        const u16* pbu = Wum + (size_t)col * 512 + q * 8;
        for (int tile = blockIdx.y; tile < ntiles; tile += GY) {
            __syncthreads();
            if (tid < 16) {
                int tr = tile * 16 + tid;
                int nd = (tr < cnt) ? order[start + tr] : -1;
                ndl[tid] = nd;
                pl[tid] = (nd >= 0) ? parent[nd] : NN;
            }
            __syncthreads();
            for (int e = tid; e < 1024; e += 512) {
                int slot = e >> 6, c8 = e & 63;
                int nd = ndl[slot]; int nn = (nd < 0) ? NN : nd;
                int boff = slot * 1024 + ((c8 * 16) ^ ((slot & 7) << 4));
                *(bf16x8*)(LB + boff) = cvt8(acc_h + (size_t)nn * 512 + c8 * 8);
                *(bf16x8*)(LB + 16384 + boff) = cvt8(acc_zc + (size_t)nn * 512 + c8 * 8);
            }
            __syncthreads();
            f32x4 ai = {}, ao = {}, au = {};
#pragma unroll 4
            for (int ko = 0; ko < 512; ko += 32) {
                int abo = ((ko + q * 8) * 2) ^ rsw;
                bf16x8 ah = *(const bf16x8*)(LB + r * 1024 + abo);
                bf16x8 az = *(const bf16x8*)(LB + 16384 + r * 1024 + abo);
                ai = __builtin_amdgcn_mfma_f32_16x16x32_bf16(ah, *(const bf16x8*)(pbi + ko), ai, 0, 0, 0);
                ao = __builtin_amdgcn_mfma_f32_16x16x32_bf16(ah, *(const bf16x8*)(pbo + ko), ao, 0, 0, 0);
                au = __builtin_amdgcn_mfma_f32_16x16x32_bf16(az, *(const bf16x8*)(pbu + ko), au, 0, 0, 0);
            }
            float bi_ = bfu(bio[col]), bo_ = bfu(bio[512 + col]), bu_ = bfu(bum[col]);
#pragma unroll
            for (int i2 = 0; i2 < 4; ++i2) {
                int slot = q * 4 + i2;
                int ni = ndl[slot];
                if (ni < 0) continue;
                int p = pl[slot];
                size_t pxb = (size_t)ni * PXC, nb = (size_t)ni * 512;
                float ig = sigf(bfu(px[pxb + col]) + ai[i2] + bi_);
                float og = sigf(bfu(px[pxb + 1024 + col]) + ao[i2] + bo_);
                float uu = tanhq(bfu(px[pxb + 2048 + col]) + au[i2] + bu_);
                float cc = ig * uu + acc_fc[nb + col];
                float h = og * tanhq(cc);
                G[(size_t)ni * 1536 + col] = cc;
                Gh[(size_t)ni * 3072 + 1024 + col] = f2bf(h);
                atomicAdd(&acc_h[(size_t)p * 512 + col], h);
                if (ni == 0) {
                    if (isbf) ((u16*)outv)[col] = f2bf(h);
                    else ((float*)outv)[col] = h;
                }
            }
        }
    } else {
        const u16* Wh = isbf ? Wh_o : Wh_n;
        const u16* pbi = Wh + (size_t)col * 512 + q * 8;
        const u16* pbo = Wh + (size_t)(512 + col) * 512 + q * 8;
        const u16* pbf = Wh + (size_t)(1024 + col) * 512 + q * 8;
        const u16* pbz = Wh + (size_t)(1536 + col) * 512 + q * 8;
        for (int tile = blockIdx.y; tile < ntiles; tile += GY) {
            __syncthreads();
            if (tid < 16) {
                int tr = tile * 16 + tid;
                int nd = (tr < cnt) ? order[start + tr] : -1;
                ndl[tid] = nd;
                pl[tid] = (nd >= 0) ? parent[nd] : NN;
            }
            __syncthreads();
            for (int e = tid; e < 1024; e += 512) {
                int slot = e >> 6, c8 = e & 63;
                int boff = slot * 1024 + ((c8 * 16) ^ ((slot & 7) << 4));
                *(bf16x8*)(LB + boff) = *(const bf16x8*)(HB + (size_t)pl[slot] * 512 + c8 * 8);
            }
            __syncthreads();
            f32x4 gi = {}, go = {}, gf = {}, gz = {};
#pragma unroll 4
            for (int ko = 0; ko < 512; ko += 32) {
                int abo = ((ko + q * 8) * 2) ^ rsw;
                bf16x8 a = *(const bf16x8*)(LB + r * 1024 + abo);
                gi = __builtin_amdgcn_mfma_f32_16x16x32_bf16(a, *(const bf16x8*)(pbi + ko), gi, 0, 0, 0);
                go = __builtin_amdgcn_mfma_f32_16x16x32_bf16(a, *(const bf16x8*)(pbo + ko), go, 0, 0, 0);
                gf = __builtin_amdgcn_mfma_f32_16x16x32_bf16(a, *(const bf16x8*)(pbf + ko), gf, 0, 0, 0);
                gz = __builtin_amdgcn_mfma_f32_16x16x32_bf16(a, *(const bf16x8*)(pbz + ko), gz, 0, 0, 0);
            }
            float bi_ = bfu(bh[col]), bo_ = bfu(bh[512 + col]);
            float bf_ = bfu(bh[1024 + col]), bz_ = bfu(bh[1536 + col]);
#pragma unroll
            for (int i2 = 0; i2 < 4; ++i2) {
                int slot = q * 4 + i2;
                int ni = ndl[slot];
                if (ni < 0) continue;
                int p = pl[slot];
                size_t qb = (size_t)ni * PXC, gb = (size_t)ni * 1536, nb = (size_t)ni * 512;
                float si = sigf(bfu(qx[qb + col]) + gi[i2] + bi_);
                float so = sigf(bfu(qx[qb + 512 + col]) + go[i2] + bo_);
                float sf = sigf(bfu(qx[qb + 1024 + col]) + gf[i2] + bf_);
                float zg = sigf(bfu(qx[qb + 1536 + col]) + gz[i2] + bz_);
                G[gb + col] = si;
                G[gb + 512 + col] = so;
                G[gb + 1024 + col] = sf;
                ZB[nb + col] = f2bf(zg * tanhq(Call[(size_t)p * 512 + col]));
            }
        }
    }
}

__global__ __launch_bounds__(512) void comb_s2(
    int iter,
    const int* __restrict__ order, const int* __restrict__ lvl, const int* __restrict__ parent,
    const u16* __restrict__ Wfz_o, const u16* __restrict__ Wfz_n,
    const u16* __restrict__ bfz,
    const u16* __restrict__ px,
    float* __restrict__ acc_fc, float* __restrict__ acc_zc,
    const u16* __restrict__ ZB, const u16* __restrict__ qx,
    const u16* __restrict__ Wum_o, const u16* __restrict__ Wum_n,
    const u16* __restrict__ bum,
    float* __restrict__ Call, u16* __restrict__ HB,
    float* __restrict__ G, const int* __restrict__ fcnt)
{
    __shared__ __align__(16) u16 LS[8192];
    __shared__ int ndl[16], pl[16];
    bool isbf = (*fcnt > 2048);
    int tid = threadIdx.x;
    int w = tid >> 6, lane = tid & 63;
    int r = lane & 15, q = lane >> 4;
    int rsw = (r & 7) << 4;
    int col = (blockIdx.x * 8 + w) * 16 + r;
    const u16* Gh = (const u16*)G;
    char* LB = (char*)LS;
    int Dmax = lvl[80];
    int d = blockIdx.z ? iter : (Dmax - 1 - iter);
    if (d < 0 || d >= Dmax) return;
    int start = lvl[d], cnt = lvl[d + 1] - start;
    if (cnt <= 0) return;
    int ntiles = (cnt + 15) >> 4;

    if (blockIdx.z == 0) {
        const u16* Wfz = isbf ? Wfz_o : Wfz_n;
        const u16* pbf = Wfz + (size_t)col * 512 + q * 8;
        const u16* pbz = Wfz + (size_t)(512 + col) * 512 + q * 8;
        for (int tile = blockIdx.y; tile < ntiles; tile += GY) {
            __syncthreads();
            if (tid < 16) {
                int tr = tile * 16 + tid;
                int nd = (tr < cnt) ? order[start + tr] : -1;
                ndl[tid] = nd;
                pl[tid] = (nd >= 0) ? parent[nd] : NN;
            }
            __syncthreads();
            for (int e = tid; e < 1024; e += 512) {
                int slot = e >> 6, c8 = e & 63;
                int nd = ndl[slot]; int nn = (nd < 0) ? NN : nd;
                int boff = slot * 1024 + ((c8 * 16) ^ ((slot & 7) << 4));
                *(bf16x8*)(LB + boff) = *(const bf16x8*)(Gh + (size_t)nn * 3072 + 1024 + c8 * 8);
            }
            __syncthreads();
            f32x4 af0 = {}, af1 = {}, az0 = {}, az1 = {};
#pragma unroll 4
            for (int ko = 0; ko < 256; ko += 32) {
                int ab0 = ((ko + q * 8) * 2) ^ rsw;
                int ab1 = ((ko + 256 + q * 8) * 2) ^ rsw;
                bf16x8 h0 = *(const bf16x8*)(LB + r * 1024 + ab0);
                bf16x8 h1 = *(const bf16x8*)(LB + r * 1024 + ab1);
                af0 = __builtin_amdgcn_mfma_f32_16x16x32_bf16(h0, *(const bf16x8*)(pbf + ko), af0, 0, 0, 0);
                az0 = __builtin_amdgcn_mfma_f32_16x16x32_bf16(h0, *(const bf16x8*)(pbz + ko), az0, 0, 0, 0);
                af1 = __builtin_amdgcn_mfma_f32_16x16x32_bf16(h1, *(const bf16x8*)(pbf + 256 + ko), af1, 0, 0, 0);
                az1 = __builtin_amdgcn_mfma_f32_16x16x32_bf16(h1, *(const bf16x8*)(pbz + 256 + ko), az1, 0, 0, 0);
            }
            f32x4 af = af0 + af1, az = az0 + az1;
            float bf_ = bfu(bfz[col]), bz_ = bfu(bfz[512 + col]);
#pragma unroll
            for (int i2 = 0; i2 < 4; ++i2) {
                int slot = q * 4 + i2;
                int ni = ndl[slot];
                if (ni < 0) continue;
                int p = pl[slot];
                size_t pb = (size_t)p * 512, ppx = (size_t)p * PXC;
                float cT = G[(size_t)ni * 1536 + col];
                float f = sigf(bfu(px[ppx + 512 + col]) + af[i2] + bf_);
                atomicAdd(&acc_fc[pb + col], f * cT);
                float zf = sigf(bfu(px[ppx + 1536 + col]) + az[i2] + bz_);
                atomicAdd(&acc_zc[pb + col], zf * tanhq(cT));
            }
        }
    } else {
        const u16* Wum = isbf ? Wum_o : Wum_n;
        const u16* pbu = Wum + (size_t)col * 512 + q * 8;
        for (int tile = blockIdx.y; tile < ntiles; tile += GY) {
            __syncthreads();
            if (tid < 16) {
                int tr = tile * 16 + tid;
                int nd = (tr < cnt) ? order[start + tr] : -1;
                ndl[tid] = nd;
                pl[tid] = (nd >= 0) ? parent[nd] : NN;
            }
            __syncthreads();
            for (int e = tid; e < 1024; e += 512) {
                int slot = e >> 6, c8 = e & 63;
                int nd = ndl[slot]; int nn = (nd < 0) ? NN : nd;
                int boff = slot * 1024 + ((c8 * 16) ^ ((slot & 7) << 4));
                *(bf16x8*)(LB + boff) = *(const bf16x8*)(ZB + (size_t)nn * 512 + c8 * 8);
            }
            __syncthreads();
            f32x4 a0 = {}, a1 = {}, a2 = {}, a3 = {};
#pragma unroll 4
            for (int ko = 0; ko < 128; ko += 32) {
                int b0 = ((ko + q * 8) * 2) ^ rsw;
                int b1 = ((ko + 128 + q * 8) * 2) ^ rsw;
                int b2 = ((ko + 256 + q * 8) * 2) ^ rsw;
                int b3 = ((ko + 384 + q * 8) * 2) ^ rsw;
                a0 = __builtin_amdgcn_mfma_f32_16x16x32_bf16(*(const bf16x8*)(LB + r * 1024 + b0),
                                                             *(const bf16x8*)(pbu + ko), a0, 0, 0, 0);
                a1 = __builtin_amdgcn_mfma_f32_16x16x32_bf16(*(const bf16x8*)(LB + r * 1024 + b1),
                                                             *(const bf16x8*)(pbu + 128 + ko), a1, 0, 0, 0);
                a2 = __builtin_amdgcn_mfma_f32_16x16x32_bf16(*(const bf16x8*)(LB + r * 1024 + b2),
                                                             *(const bf16x8*)(pbu + 256 + ko), a2, 0, 0, 0);
                a3 = __builtin_amdgcn_mfma_f32_16x16x32_bf16(*(const bf16x8*)(LB + r * 1024 + b3),
                                                             *(const bf16x8*)(pbu + 384 + ko), a3, 0, 0, 0);
            }
            f32x4 au = (a0 + a1) + (a2 + a3);
            float bu_ = bfu(bum[col]);
#pragma unroll
            for (int i2 = 0; i2 < 4; ++i2) {
                int slot = q * 4 + i2;
                int ni = ndl[slot];
                if (ni < 0) continue;
                int p = pl[slot];
                size_t qb = (size_t)ni * PXC, gb = (size_t)ni * 1536, nb = (size_t)ni * 512;
                float uu = tanhq(bfu(qx[qb + 2048 + col]) + au[i2] + bu_);
                float si = G[gb + col];
                float so = G[gb + 512 + col];
                float sf = G[gb + 1024 + col];
                float pc = Call[(size_t)p * 512 + col];
                float cc = si * uu + sf * pc;
                float h = so * tanhq(cc);
                Call[nb + col] = cc;
                HB[nb + col] = f2bf(h);
            }
        }
    }
}

// ---------------- final max reduce ----------------
__global__ __launch_bounds__(256) void k_maxA(const u16* __restrict__ HB, float* __restrict__ pmax) {
    int b = blockIdx.x, t = threadIdx.x;
    float m1 = -1e30f, m2 = -1e30f;
    for (int rr = b * 128; rr < b * 128 + 128; ++rr) {
        m1 = fmaxf(m1, bfu(HB[(size_t)rr * 512 + t]));
        m2 = fmaxf(m2, bfu(HB[(size_t)rr * 512 + t + 256]));
    }
    pmax[(size_t)b * 512 + t] = m1; pmax[(size_t)b * 512 + t + 256] = m2;
}
__global__ void k_maxB(const float* __restrict__ pmax, void* __restrict__ outv,
                       const int* __restrict__ fcnt) {
    int j = threadIdx.x;
    float m = -1e30f;
    for (int b = 0; b < 64; ++b) m = fmaxf(m, pmax[(size_t)b * 512 + j]);
    bool isbf = (*fcnt > 2048);
    if (isbf) ((u16*)outv)[512 + j] = f2bf(m);
    else ((float*)outv)[512 + j] = m;
}

__global__ void k_wsfail(u16* out) {
    int i = blockIdx.x * 256 + threadIdx.x;
    if (i < 1024) out[i] = f2bf(12345.f);
}

// ---------------- launch ----------------
extern "C" void kernel_launch(void* const* d_in, const int* in_sizes, int n_in,
                              void* d_out, int out_size, void* d_ws, size_t ws_size,
                              hipStream_t stream) {
    char* base = (char*)d_ws;
    u16* px = (u16*)(base + OFF_PX);
    u16* qx = (u16*)(base + OFF_QX);
    float* acc_h = (float*)(base + OFF_ACCH);
    float* acc_fc = (float*)(base + OFF_ACCF);
    float* acc_zc = (float*)(base + OFF_ACCZ);
    float* Call = (float*)(base + OFF_C);
    u16* HB = (u16*)(base + OFF_HB);
    u16* ZB = (u16*)(base + OFF_ZB);
    float* G = (float*)(base + OFF_G);
    u16* NGI = (u16*)(base + OFF_G);
    u16* NW = (u16*)(base + OFF_NW);
    int* depth = (int*)(base + OFF_DEPTH);
    int* order = (int*)(base + OFF_ORDER);
    int* counts = (int*)(base + OFF_MISC);
    int* fcnt = counts + 128;
    int* pcnt = counts + 129;
    int* lvl = (int*)(base + OFF_LVL);
    u16* NB = (u16*)(base + OFF_NB);
    int* pnorm = (int*)(base + OFF_PN);
    float* pmax = (float*)(base + OFF_PMAX);
    u32* BAR = (u32*)(base + OFF_BAR);

    const u16* in_bf   = (const u16*)d_in[0];
    const u16* csWx_o  = (const u16*)d_in[2];
    const u16* csWio_o = (const u16*)d_in[4];
    const u16* csWfz_o = (const u16*)d_in[6];
    const u16* csWum_o = (const u16*)d_in[8];
    const u16* chWx_o  = (const u16*)d_in[10];
    const u16* chWh_o  = (const u16*)d_in[12];
    const u16* chWum_o = (const u16*)d_in[14];

    if (ws_size < WS_TOTAL) { k_wsfail<<<4, 256, 0, stream>>>((u16*)d_out); return; }

    hipMemsetAsync(base + OFF_MISC, 0, 1024, stream);
    hipMemsetAsync(base + OFF_ACCH, 0, 3 * SZ_ACC, stream);   // acc_h/fc/zc (+ sentinel rows)

    // dtype detect + barrier zero + fused setup
    k_detect<<<32, 256, 0, stream>>>((const u32*)d_in[0], (const u32*)d_in[1], fcnt, pcnt, BAR);
    k_pnorm_depth<<<32, 256, 0, stream>>>((const u32*)d_in[1], pcnt, pnorm, depth, HB, Call);
    k_levels<<<1, 1024, 0, stream>>>(depth, lvl, order);

    NormSrcs srcs;
    srcs.p[0] = d_in[0];  srcs.p[1] = d_in[2];  srcs.p[2] = d_in[10]; srcs.p[3] = d_in[4];
    srcs.p[4] = d_in[6];  srcs.p[5] = d_in[8];  srcs.p[6] = d_in[12]; srcs.p[7] = d_in[14];
    srcs.p[8] = d_in[3];  srcs.p[9] = d_in[5];  srcs.p[10] = d_in[7]; srcs.p[11] = d_in[9];
    srcs.p[12] = d_in[11]; srcs.p[13] = d_in[13]; srcs.p[14] = d_in[15];
    k_norm_all<<<2048, 256, 0, stream>>>(srcs, NGI, NW, NB, fcnt);

    // input projections
    dim3 gg(PXC / 256, NN / 64, 2);
    k_gemm_in<<<gg, 256, 0, stream>>>(in_bf, NGI,
                                      csWx_o, NW + NW_CSWX, chWx_o, NW + NW_CHWX,
                                      NB + NB_CSBX, NB + NB_CHBX, px, qx, fcnt);

    // persistent level loop (round-12 shape + per-plane barriers); fallback: per-level kernels
    {
        const u16* nWio = NW + NW_CSWIO; const u16* nWum = NW + NW_CSWUM;
        const u16* nWfz = NW + NW_CSWFZ; const u16* nWh = NW + NW_CHWH;
        const u16* nWu2 = NW + NW_CHWUM;
        const u16* b_io = NB + NB_CSBIO; const u16* b_um = NB + NB_CSBUM;
        const u16* b_fz = NB + NB_CSBFZ; const u16* b_h = NB + NB_CHBH;
        const u16* b_u2 = NB + NB_CHBUM;
        const int* order_c = order; const int* lvl_c = lvl; const int* par_c = pnorm;
        const u16* px_c = px; const u16* qx_c = qx;
        void* outp = d_out; const int* fcnt_c = fcnt;
        u32* bar_c = BAR;
        void* margs[] = {
            (void*)&order_c, (void*)&lvl_c, (void*)&par_c,
            (void*)&acc_h, (void*)&acc_fc, (void*)&acc_zc,
            (void*)&csWio_o, (void*)&nWio, (void*)&csWum_o, (void*)&nWum,
            (void*)&csWfz_o, (void*)&nWfz,
            (void*)&b_io, (void*)&b_um, (void*)&b_fz,
            (void*)&px_c, (void*)&HB, (void*)&Call,
            (void*)&chWh_o, (void*)&nWh, (void*)&chWum_o, (void*)&nWu2,
            (void*)&b_h, (void*)&b_u2,
            (void*)&qx_c, (void*)&ZB, (void*)&G,
            (void*)&outp, (void*)&fcnt_c, (void*)&bar_c
        };
        hipError_t ce = hipLaunchCooperativeKernel((const void*)comb_mega9,
                                                   dim3(256), dim3(512), margs, 0, stream);
        if (ce != hipSuccess) {
            (void)hipGetLastError();
            dim3 gl(4, GY, 2);
            for (int i = 0; i < MAXD; ++i) {
                comb_s1<<<gl, 512, 0, stream>>>(i, order, lvl, pnorm,
                                                acc_h, acc_fc, acc_zc,
                                                csWio_o, NW + NW_CSWIO, csWum_o, NW + NW_CSWUM,
                                                NB + NB_CSBIO, NB + NB_CSBUM, px,
                                                HB, Call, chWh_o, NW + NW_CHWH, NB + NB_CHBH,
                                                qx, ZB, G, d_out, fcnt);
                comb_s2<<<gl, 512, 0, stream>>>(i, order, lvl, pnorm,
                                                csWfz_o, NW + NW_CSWFZ, NB + NB_CSBFZ, px,
                                                acc_fc, acc_zc,
                                                ZB, qx, chWum_o, NW + NW_CHWUM, NB + NB_CHBUM,
                                                Call, HB, G, fcnt);
            }
        }
    }

    // brep
    k_maxA<<<64, 256, 0, stream>>>(HB, pmax);
    k_maxB<<<1, 512, 0, stream>>>(pmax, d_out, fcnt);
}

// Round 14
// 1093.604 us; speedup vs baseline: 2.4436x; 1.0252x over previous
//
#include <hip/hip_runtime.h>
#include <hip/hip_cooperative_groups.h>
#include <hip/hip_bf16.h>

typedef unsigned short u16;
typedef unsigned int u32;
typedef unsigned long long u64;

#define NN 8192
#define PXC 2560
#define MAXD 36
#define GY 64
#define GYM 32

typedef __attribute__((ext_vector_type(8))) short bf16x8;
typedef __attribute__((ext_vector_type(4))) float f32x4;

// ---------------- workspace layout (bytes) ----------------
static constexpr size_t SZ_PX  = (size_t)(NN + 1) * PXC * 2;
static constexpr size_t SZ_ACC = (size_t)(NN + 1) * 512 * 4;
static constexpr size_t SZ_HB  = (size_t)(NN + 1) * 512 * 2;
static constexpr size_t SZ_G   = (size_t)(NN + 1) * 1536 * 4;
static constexpr size_t SZ_NW  = (size_t)5242880 * 2;

static constexpr size_t OFF_PX    = 0;
static constexpr size_t OFF_QX    = OFF_PX + SZ_PX;
static constexpr size_t OFF_ACCH  = OFF_QX + SZ_PX;
static constexpr size_t OFF_ACCF  = OFF_ACCH + SZ_ACC;
static constexpr size_t OFF_ACCZ  = OFF_ACCF + SZ_ACC;
static constexpr size_t OFF_C     = OFF_ACCZ + SZ_ACC;         // c_all (chain), f32
static constexpr size_t OFF_HB    = OFF_C + SZ_ACC;            // h_all (chain), bf16
static constexpr size_t OFF_ZB    = OFF_HB + SZ_HB;            // chain ZB, bf16
static constexpr size_t OFF_G     = OFF_ZB + SZ_HB;            // per-node scratch / transient normalized inputs
static constexpr size_t OFF_NW    = OFF_G + SZ_G;
static constexpr size_t OFF_DEPTH = OFF_NW + SZ_NW;
static constexpr size_t OFF_ORDER = OFF_DEPTH + (size_t)NN * 4;
static constexpr size_t OFF_MISC  = OFF_ORDER + (size_t)NN * 4;
static constexpr size_t OFF_LVL   = OFF_MISC + 1024;
static constexpr size_t OFF_NB    = OFF_LVL + 512;
static constexpr size_t OFF_PN    = OFF_NB + 20480;
static constexpr size_t OFF_PMAX  = OFF_PN + (size_t)NN * 4;
static constexpr size_t OFF_BAR   = OFF_PMAX + (size_t)128 * 512 * 4;
static constexpr size_t WS_TOTAL  = OFF_BAR + 32768;

#define NW_CSWX  0
#define NW_CHWX  1310720
#define NW_CSWIO 2621440
#define NW_CSWFZ 3145728
#define NW_CSWUM 3670016
#define NW_CHWH  3932160
#define NW_CHWUM 4980736

#define NB_CSBX  0
#define NB_CSBIO 2560
#define NB_CSBFZ 3584
#define NB_CSBUM 4608
#define NB_CHBX  5120
#define NB_CHBH  7680
#define NB_CHBUM 9728

// ---------------- helpers ----------------
__device__ __forceinline__ float bfu(u16 u) { return __uint_as_float(((u32)u) << 16); }
__device__ __forceinline__ u16 f2bf(float f) {
    u32 u = __float_as_uint(f);
    u += 0x7fffu + ((u >> 16) & 1u);
    return (u16)(u >> 16);
}
__device__ __forceinline__ float sigf(float x) {
    x = fminf(fmaxf(x, -30.f), 30.f);
    return 1.f / (1.f + __expf(-x));
}
__device__ __forceinline__ float tanhq(float x) {
    x = fminf(fmaxf(x, -15.f), 15.f);
    return 1.f - 2.f / (__expf(2.f * x) + 1.f);
}
__device__ __forceinline__ bf16x8 cvt8(const float* p) {
    float4 a = *(const float4*)p;
    float4 b = *(const float4*)(p + 4);
    union { u32 u[4]; bf16x8 v; } r;
    r.u[0] = ((__float_as_uint(a.x) + 0x8000u) >> 16) | ((__float_as_uint(a.y) + 0x8000u) & 0xffff0000u);
    r.u[1] = ((__float_as_uint(a.z) + 0x8000u) >> 16) | ((__float_as_uint(a.w) + 0x8000u) & 0xffff0000u);
    r.u[2] = ((__float_as_uint(b.x) + 0x8000u) >> 16) | ((__float_as_uint(b.y) + 0x8000u) & 0xffff0000u);
    r.u[3] = ((__float_as_uint(b.z) + 0x8000u) >> 16) | ((__float_as_uint(b.w) + 0x8000u) & 0xffff0000u);
    return r.v;
}

// -------- agent-scope (XCD-coherent) accessors for mutable state --------
__device__ __forceinline__ u64 cld64(const void* p) {
    return __hip_atomic_load((const u64*)p, __ATOMIC_RELAXED, __HIP_MEMORY_SCOPE_AGENT);
}
__device__ __forceinline__ float cldf(const float* p) {
    return __hip_atomic_load(p, __ATOMIC_RELAXED, __HIP_MEMORY_SCOPE_AGENT);
}
__device__ __forceinline__ void cstf(float* p, float v) {
    __hip_atomic_store(p, v, __ATOMIC_RELAXED, __HIP_MEMORY_SCOPE_AGENT);
}
__device__ __forceinline__ void cst16(u16* p, u16 v) {
    __hip_atomic_store(p, v, __ATOMIC_RELAXED, __HIP_MEMORY_SCOPE_AGENT);
}
__device__ __forceinline__ bf16x8 cvt8a(const float* p) {  // 32B f32 coherent load -> bf16x8
    union { u64 u; u32 w[2]; } a, b, c, d;
    a.u = cld64(p); b.u = cld64(p + 2); c.u = cld64(p + 4); d.u = cld64(p + 6);
    union { u32 u[4]; bf16x8 v; } r;
    r.u[0] = ((a.w[0] + 0x8000u) >> 16) | ((a.w[1] + 0x8000u) & 0xffff0000u);
    r.u[1] = ((b.w[0] + 0x8000u) >> 16) | ((b.w[1] + 0x8000u) & 0xffff0000u);
    r.u[2] = ((c.w[0] + 0x8000u) >> 16) | ((c.w[1] + 0x8000u) & 0xffff0000u);
    r.u[3] = ((d.w[0] + 0x8000u) >> 16) | ((d.w[1] + 0x8000u) & 0xffff0000u);
    return r.v;
}

// ---- PER-PLANE contention-free barrier (128 blocks/plane), monotonic flags ----
__device__ __forceinline__ void plane_bar(u32* B, int z, int bid, u32 tgt) {
    __syncthreads();                       // all waves drain their stores here
    int tid = threadIdx.x;
    if (tid == 0)
        __hip_atomic_store(B + 16 + bid * 16, tgt, __ATOMIC_RELAXED, __HIP_MEMORY_SCOPE_AGENT);
    if ((int)blockIdx.x == z) {            // plane leader: bid 0 (z=0) / bid 1 (z=1)
        if (tid < 128) {
            while (__hip_atomic_load(B + 16 + (2 * tid + z) * 16, __ATOMIC_RELAXED, __HIP_MEMORY_SCOPE_AGENT) < tgt)
                __builtin_amdgcn_s_sleep(1);
        }
        __syncthreads();
        if (tid < 8)
            __hip_atomic_store(B + 4608 + z * 128 + tid * 16, tgt, __ATOMIC_RELAXED, __HIP_MEMORY_SCOPE_AGENT);
    }
    if (tid == 0) {
        while (__hip_atomic_load(B + 4608 + z * 128 + (((u32)bid >> 3) & 7) * 16, __ATOMIC_RELAXED, __HIP_MEMORY_SCOPE_AGENT) < tgt)
            __builtin_amdgcn_s_sleep(1);
        asm volatile("" ::: "memory");
    }
    __syncthreads();
}

// 4-sibling mini-barrier: 4 private flags (16B apart), monotonic; no RMW.
__device__ __forceinline__ void mini_bar(u32* MF, int cgi, u32 tgt) {
    __syncthreads();                       // drains this block's stores
    if (threadIdx.x == 0) {
        __hip_atomic_store(MF + cgi * 4, tgt, __ATOMIC_RELAXED, __HIP_MEMORY_SCOPE_AGENT);
        for (;;) {
            u32 a = __hip_atomic_load(MF + 0,  __ATOMIC_RELAXED, __HIP_MEMORY_SCOPE_AGENT);
            u32 b = __hip_atomic_load(MF + 4,  __ATOMIC_RELAXED, __HIP_MEMORY_SCOPE_AGENT);
            u32 c = __hip_atomic_load(MF + 8,  __ATOMIC_RELAXED, __HIP_MEMORY_SCOPE_AGENT);
            u32 d = __hip_atomic_load(MF + 12, __ATOMIC_RELAXED, __HIP_MEMORY_SCOPE_AGENT);
            if (a >= tgt && b >= tgt && c >= tgt && d >= tgt) break;
            __builtin_amdgcn_s_sleep(1);
        }
        asm volatile("" ::: "memory");
    }
    __syncthreads();
}

// ---------------- dtype detection (+ barrier zeroing) ----------------
__global__ void k_detect(const u32* __restrict__ fin, const u32* __restrict__ pin,
                         int* __restrict__ fcnt, int* __restrict__ pcnt,
                         u32* __restrict__ barz) {
    int i = blockIdx.x * 256 + threadIdx.x;
    if (i < 8192) barz[i] = 0u;
    if (i < 4096) {
        u32 w = fin[i];
        int e = (w >> 7) & 0xFF;
        if (w != 0u && e >= 0x70 && e <= 0x8F) atomicAdd(fcnt, 1);
    }
    if (i >= 1 && i < 4096) {
        if (pin[2 * i - 1] != 0u) atomicAdd(pcnt, 1);
    }
}

// fused: parent normalize + depth chase + sentinel-row init
__global__ void k_pnorm_depth(const u32* __restrict__ pin, const int* __restrict__ pcnt,
                              int* __restrict__ pnorm, int* __restrict__ depth,
                              u16* __restrict__ HB, float* __restrict__ Call) {
    int i = blockIdx.x * 256 + threadIdx.x;
    if (i < 512) {
        HB[(size_t)NN * 512 + i] = 0;
        Call[(size_t)NN * 512 + i] = 0.f;
    }
    if (i >= NN) return;
    bool is64 = (*pcnt < 100);
    int p = (int)(is64 ? pin[2 * i] : pin[i]);
    pnorm[i] = p;
    int d = 0;
    while (p != NN && p >= 0 && p < NN && d < 9000) {
        d++;
        p = (int)(is64 ? pin[2 * p] : pin[p]);
    }
    depth[i] = d;
}

// fused hist + scan + scatter, single block; also computes D* -> lvl[80]
__global__ __launch_bounds__(1024) void k_levels(const int* __restrict__ depth,
                                                 int* __restrict__ lvl, int* __restrict__ order) {
    __shared__ int cnts[64];
    __shared__ int cur[64];
    int t = threadIdx.x;
    if (t < 64) cnts[t] = 0;
    __syncthreads();
    for (int i = t; i < NN; i += 1024) {
        int d = depth[i]; if (d > 63) d = 63;
        atomicAdd(&cnts[d], 1);
    }
    __syncthreads();
    if (t == 0) {
        int s = 0; lvl[0] = 0;
        for (int d = 0; d < 64; ++d) { cur[d] = s; s += cnts[d]; lvl[d + 1] = s; }
        int D = 1;
        for (int d = 63; d >= 0; --d) if (cnts[d] > 0) { D = d + 1; break; }
        lvl[80] = D;                        // number of nonempty levels
    }
    __syncthreads();
    for (int i = t; i < NN; i += 1024) {
        int d = depth[i]; if (d > 63) d = 63;
        int pos = atomicAdd(&cur[d], 1);
        order[pos] = i;
    }
}

struct NormSrcs { const void* p[15]; };
__global__ __launch_bounds__(256) void k_norm_all(NormSrcs s, u16* __restrict__ NGI,
                                                  u16* __restrict__ NW, u16* __restrict__ NB,
                                                  const int* __restrict__ fcnt) {
    const int cum[16] = {0, 1048576, 1376256, 1703936, 1835008, 1966080, 2031616, 2293760,
                         2359296, 2359936, 2360192, 2360448, 2360576, 2361216, 2361728, 2361856};
    const int dof[15] = {0, NW_CSWX / 4, NW_CHWX / 4, NW_CSWIO / 4, NW_CSWFZ / 4, NW_CSWUM / 4,
                         NW_CHWH / 4, NW_CHWUM / 4, NB_CSBX / 4, NB_CSBIO / 4, NB_CSBFZ / 4,
                         NB_CSBUM / 4, NB_CHBX / 4, NB_CHBH / 4, NB_CHBUM / 4};
    bool isbf = (*fcnt > 2048);
    int total = 2361856;
    int istart = isbf ? cum[8] : 0;
    for (int i = istart + blockIdx.x * 256 + threadIdx.x; i < total; i += gridDim.x * 256) {
        int seg = 0;
#pragma unroll
        for (int k = 1; k < 15; ++k) if (i >= cum[k]) seg = k;
        int off = i - cum[seg];
        u16* dbase = (seg == 0) ? NGI : (seg < 8 ? NW : NB);
        ushort4* dst = (ushort4*)dbase + dof[seg] + off;
        if (isbf) {
            *dst = ((const ushort4*)s.p[seg])[off];
        } else {
            float4 v = ((const float4*)s.p[seg])[off];
            ushort4 o; o.x = f2bf(v.x); o.y = f2bf(v.y); o.z = f2bf(v.z); o.w = f2bf(v.w);
            *dst = o;
        }
    }
}

// ---------------- input-projection GEMM: grid (5, 128, 2), 512 threads (8 waves) ----------------
// 8 waves share one 64x512 A-tile in LDS (was 4): same LDS footprint now feeds 2x the
// waves -> ~16 waves/CU (was 8), doubling L2-latency hiding on the streamed B reads.
#define ASTR 528
__global__ __launch_bounds__(512) void k_gemm_in(
    const u16* __restrict__ Ao, const u16* __restrict__ An,
    const u16* __restrict__ Wcs_o, const u16* __restrict__ Wcs_n,
    const u16* __restrict__ Wch_o, const u16* __restrict__ Wch_n,
    const u16* __restrict__ bcs, const u16* __restrict__ bch,
    u16* __restrict__ Ccs, u16* __restrict__ Cch,
    const int* __restrict__ fcnt)
{
    __shared__ __align__(16) u16 AS[64 * ASTR];
    bool isbf = (*fcnt > 2048);
    int z = blockIdx.z;
    const u16* A = isbf ? Ao : An;
    const u16* W = z ? (isbf ? Wch_o : Wch_n) : (isbf ? Wcs_o : Wcs_n);
    const u16* bias = z ? bch : bcs;
    u16* C = z ? Cch : Ccs;

    int m0 = blockIdx.y * 64;
    for (int e = threadIdx.x; e < 64 * 64; e += 512) {
        int row = e >> 6, c8 = e & 63;
        *(uint4*)&AS[row * ASTR + c8 * 8] = *(const uint4*)(A + (size_t)(m0 + row) * 512 + c8 * 8);
    }
    __syncthreads();

    int wv = threadIdx.x >> 6;                // 0..7
    int lane = threadIdx.x & 63;
    int r = lane & 15, q = lane >> 4;
    int n0 = blockIdx.x * 512 + wv * 64;
    const u16* pb[4];
#pragma unroll
    for (int jt = 0; jt < 4; ++jt) pb[jt] = W + (size_t)(n0 + jt * 16 + r) * 512 + q * 8;
    f32x4 acc[4][4] = {};
#pragma unroll 2
    for (int k0 = 0; k0 < 512; k0 += 32) {
        bf16x8 a[4], b[4];
#pragma unroll
        for (int mi = 0; mi < 4; ++mi)
            a[mi] = *(const bf16x8*)&AS[(mi * 16 + r) * ASTR + k0 + q * 8];
#pragma unroll
        for (int jt = 0; jt < 4; ++jt) b[jt] = *(const bf16x8*)(pb[jt] + k0);
#pragma unroll
        for (int mi = 0; mi < 4; ++mi)
#pragma unroll
            for (int jt = 0; jt < 4; ++jt)
                acc[mi][jt] = __builtin_amdgcn_mfma_f32_16x16x32_bf16(a[mi], b[jt], acc[mi][jt], 0, 0, 0);
    }
#pragma unroll
    for (int jt = 0; jt < 4; ++jt) {
        int c = n0 + jt * 16 + r;
        float bv = bfu(bias[c]);
#pragma unroll
        for (int mi = 0; mi < 4; ++mi) {
            size_t b0 = (size_t)(m0 + mi * 16 + q * 4) * PXC + c;
#pragma unroll
            for (int i = 0; i < 4; ++i)
                C[b0 + (size_t)i * PXC] = f2bf(acc[mi][jt][i] + bv);
        }
    }
}

// ================= persistent level loop: round-13 verified (mega9, per-plane barriers) =================
__global__ __launch_bounds__(512, 2) void comb_mega9(
    const int* __restrict__ order, const int* __restrict__ lvl, const int* __restrict__ parent,
    float* __restrict__ acc_h, float* __restrict__ acc_fc, float* __restrict__ acc_zc,
    const u16* __restrict__ Wio_o, const u16* __restrict__ Wio_n,
    const u16* __restrict__ Wum_o, const u16* __restrict__ Wum_n,
    const u16* __restrict__ Wfz_o, const u16* __restrict__ Wfz_n,
    const u16* __restrict__ bio, const u16* __restrict__ bum, const u16* __restrict__ bfz,
    const u16* __restrict__ px,
    u16* __restrict__ HB, float* __restrict__ Call,
    const u16* __restrict__ Wh_o, const u16* __restrict__ Wh_n,
    const u16* __restrict__ Wu2_o, const u16* __restrict__ Wu2_n,
    const u16* __restrict__ bh, const u16* __restrict__ bu2,
    const u16* __restrict__ qx, u16* __restrict__ ZB,
    float* __restrict__ G,
    void* __restrict__ outv, const int* __restrict__ fcnt,
    u32* __restrict__ BAR)
{
    __shared__ __align__(16) u16 LS[16384];   // 32KB: 2 x [16][512] bf16 panels
    __shared__ int ndl[16], pl[16];
    bool isbf = (*fcnt > 2048);
    int tid = threadIdx.x;
    int w = tid >> 6, lane = tid & 63;
    int r = lane & 15, q = lane >> 4;
    int rsw = (r & 7) << 4;
    int bid = blockIdx.x;
    int z = bid & 1;
    int cgi = (bid >> 1) & 3;
    int ty = bid >> 3;                        // 0..31
    int col = (cgi * 8 + w) * 16 + r;
    u16* Gh = (u16*)G;
    char* LB = (char*)LS;
    int Dmax = lvl[80];
    u32* MF = BAR + 5120 + (size_t)((z << 5) + ty) * 16;  // 4 flags, 16B apart
    u32 tgt = 0, mtgt = 0;

    // hoisted plane invariants
    const u16 *p1a, *p1b, *p1c, *p1d;
    const u16 *p2a, *p2b;
    float ba, bb, bc, bd, be;
    if (z == 0) {
        const u16* Wio = isbf ? Wio_o : Wio_n;
        const u16* Wum = isbf ? Wum_o : Wum_n;
        const u16* Wfz = isbf ? Wfz_o : Wfz_n;
        p1a = Wio + (size_t)col * 512 + q * 8;
        p1b = Wio + (size_t)(512 + col) * 512 + q * 8;
        p1c = Wum + (size_t)col * 512 + q * 8;
        p1d = p1c;
        p2a = Wfz + (size_t)col * 512 + q * 8;
        p2b = Wfz + (size_t)(512 + col) * 512 + q * 8;
        ba = bfu(bio[col]); bb = bfu(bio[512 + col]); bc = bfu(bum[col]);
        bd = bfu(bfz[col]); be = bfu(bfz[512 + col]);
    } else {
        const u16* Wh = isbf ? Wh_o : Wh_n;
        const u16* Wu = isbf ? Wu2_o : Wu2_n;
        p1a = Wh + (size_t)col * 512 + q * 8;
        p1b = Wh + (size_t)(512 + col) * 512 + q * 8;
        p1c = Wh + (size_t)(1024 + col) * 512 + q * 8;
        p1d = Wh + (size_t)(1536 + col) * 512 + q * 8;
        p2a = Wu + (size_t)col * 512 + q * 8;
        p2b = p2a;
        ba = bfu(bh[col]); bb = bfu(bh[512 + col]);
        bc = bfu(bh[1024 + col]); bd = bfu(bh[1536 + col]);
        be = bfu(bu2[col]);
    }

    for (int it = 0; it < Dmax; ++it) {
        int d = z ? it : (Dmax - 1 - it);
        int start = lvl[d], cnt = lvl[d + 1] - start;
        int ntiles = (cnt + 15) >> 4;

        for (int tile = ty; tile < ntiles; tile += GYM) {
            __syncthreads();
            if (tid < 16) {
                int tr = tile * 16 + tid;
                int nd = (tr < cnt) ? order[start + tr] : -1;
                ndl[tid] = nd;
                pl[tid] = (nd >= 0) ? parent[nd] : NN;
            }
            __syncthreads();

            if (z == 0) {
                // -------- prefetch all epilogue operands (node px i/o/u, acc_fc; parent px f/z) --------
                float pfi[4], pfo[4], pfu[4], pfc[4], pff[4], pfz[4];
#pragma unroll
                for (int i2 = 0; i2 < 4; ++i2) {
                    int slot = q * 4 + i2;
                    int ni = ndl[slot]; int p = pl[slot];
                    int nn = (ni < 0) ? NN : ni;
                    size_t pxb = (size_t)nn * PXC, nb = (size_t)nn * 512;
                    size_t ppx = (size_t)p * PXC;
                    pfi[i2] = bfu(px[pxb + col]);
                    pfo[i2] = bfu(px[pxb + 1024 + col]);
                    pfu[i2] = bfu(px[pxb + 2048 + col]);
                    pfc[i2] = cldf(acc_fc + nb + col);
                    pff[i2] = bfu(px[ppx + 512 + col]);
                    pfz[i2] = bfu(px[ppx + 1536 + col]);
                }
                // ---------- cs s1: stage AH/AZ (sc1; atomic-fed), gates i,o,u -> c(reg), h->Gh ----------
                for (int e = tid; e < 1024; e += 512) {
                    int slot = e >> 6, c8 = e & 63;
                    int nd = ndl[slot]; int nn = (nd < 0) ? NN : nd;
                    int boff = slot * 1024 + ((c8 * 16) ^ ((slot & 7) << 4));
                    *(bf16x8*)(LB + boff) = cvt8a(acc_h + (size_t)nn * 512 + c8 * 8);
                    *(bf16x8*)(LB + 16384 + boff) = cvt8a(acc_zc + (size_t)nn * 512 + c8 * 8);
                }
                __syncthreads();
                f32x4 ai = {}, ao = {}, au = {};
#pragma unroll 4
                for (int ko = 0; ko < 512; ko += 32) {
                    int abo = ((ko + q * 8) * 2) ^ rsw;
                    bf16x8 ah = *(const bf16x8*)(LB + r * 1024 + abo);
                    bf16x8 az = *(const bf16x8*)(LB + 16384 + r * 1024 + abo);
                    ai = __builtin_amdgcn_mfma_f32_16x16x32_bf16(ah, *(const bf16x8*)(p1a + ko), ai, 0, 0, 0);
                    ao = __builtin_amdgcn_mfma_f32_16x16x32_bf16(ah, *(const bf16x8*)(p1b + ko), ao, 0, 0, 0);
                    au = __builtin_amdgcn_mfma_f32_16x16x32_bf16(az, *(const bf16x8*)(p1c + ko), au, 0, 0, 0);
                }
                float ccv[4];
#pragma unroll
                for (int i2 = 0; i2 < 4; ++i2) {
                    int slot = q * 4 + i2;
                    int ni = ndl[slot];
                    ccv[i2] = 0.f;
                    if (ni < 0) continue;
                    int p = pl[slot];
                    float ig = sigf(pfi[i2] + ai[i2] + ba);
                    float og = sigf(pfo[i2] + ao[i2] + bb);
                    float uu = tanhq(pfu[i2] + au[i2] + bc);
                    float cc = ig * uu + pfc[i2];
                    float h = og * tanhq(cc);
                    ccv[i2] = cc;
                    cst16(&Gh[(size_t)ni * 3072 + 1024 + col], f2bf(h));
                    atomicAdd(&acc_h[(size_t)p * 512 + col], h);
                    if (ni == 0) {
                        if (isbf) ((u16*)outv)[col] = f2bf(h);
                        else ((float*)outv)[col] = h;
                    }
                }
                ++mtgt; mini_bar(MF, cgi, mtgt);
                // ---------- cs s2: stage HT (plain; rows written once, pre-mini-bar), f,z -> scatter ----------
                for (int e = tid; e < 1024; e += 512) {
                    int slot = e >> 6, c8 = e & 63;
                    int nd = ndl[slot]; int nn = (nd < 0) ? NN : nd;
                    int boff = slot * 1024 + ((c8 * 16) ^ ((slot & 7) << 4));
                    *(bf16x8*)(LB + boff) = *(const bf16x8*)(Gh + (size_t)nn * 3072 + 1024 + c8 * 8);
                }
                __syncthreads();
                f32x4 af0 = {}, af1 = {}, az0 = {}, az1 = {};
#pragma unroll 4
                for (int ko = 0; ko < 256; ko += 32) {
                    int ab0 = ((ko + q * 8) * 2) ^ rsw;
                    int ab1 = ((ko + 256 + q * 8) * 2) ^ rsw;
                    bf16x8 h0 = *(const bf16x8*)(LB + r * 1024 + ab0);
                    bf16x8 h1 = *(const bf16x8*)(LB + r * 1024 + ab1);
                    af0 = __builtin_amdgcn_mfma_f32_16x16x32_bf16(h0, *(const bf16x8*)(p2a + ko), af0, 0, 0, 0);
                    az0 = __builtin_amdgcn_mfma_f32_16x16x32_bf16(h0, *(const bf16x8*)(p2b + ko), az0, 0, 0, 0);
                    af1 = __builtin_amdgcn_mfma_f32_16x16x32_bf16(h1, *(const bf16x8*)(p2a + 256 + ko), af1, 0, 0, 0);
                    az1 = __builtin_amdgcn_mfma_f32_16x16x32_bf16(h1, *(const bf16x8*)(p2b + 256 + ko), az1, 0, 0, 0);
                }
                f32x4 af = af0 + af1, az = az0 + az1;
#pragma unroll
                for (int i2 = 0; i2 < 4; ++i2) {
                    int slot = q * 4 + i2;
                    int ni = ndl[slot];
                    if (ni < 0) continue;
                    int p = pl[slot];
                    size_t pb = (size_t)p * 512;
                    float cT = ccv[i2];
                    float f = sigf(pff[i2] + af[i2] + bd);
                    atomicAdd(&acc_fc[pb + col], f * cT);
                    float zf = sigf(pfz[i2] + az[i2] + be);
                    atomicAdd(&acc_zc[pb + col], zf * tanhq(cT));
                }
            } else {
                // -------- prefetch all epilogue operands (node qx i/o/f/z/u; parent Call) --------
                float pqi[4], pqo[4], pqf[4], pqz[4], pqu[4], ppc[4];
#pragma unroll
                for (int i2 = 0; i2 < 4; ++i2) {
                    int slot = q * 4 + i2;
                    int ni = ndl[slot]; int p = pl[slot];
                    int nn = (ni < 0) ? NN : ni;
                    size_t qb = (size_t)nn * PXC;
                    pqi[i2] = bfu(qx[qb + col]);
                    pqo[i2] = bfu(qx[qb + 512 + col]);
                    pqf[i2] = bfu(qx[qb + 1024 + col]);
                    pqz[i2] = bfu(qx[qb + 1536 + col]);
                    pqu[i2] = bfu(qx[qb + 2048 + col]);
                    ppc[i2] = Call[(size_t)p * 512 + col];   // write-once + reuse: plain
                }
                // ---------- ch s1: stage AP=HB[parent] (plain), gates i,o,f,z -> regs; ZB ----------
                for (int e = tid; e < 1024; e += 512) {
                    int slot = e >> 6, c8 = e & 63;
                    int boff = slot * 1024 + ((c8 * 16) ^ ((slot & 7) << 4));
                    *(bf16x8*)(LB + boff) = *(const bf16x8*)(HB + (size_t)pl[slot] * 512 + c8 * 8);
                }
                __syncthreads();
                f32x4 gi = {}, go = {}, gf = {}, gz = {};
#pragma unroll 4
                for (int ko = 0; ko < 512; ko += 32) {
                    int abo = ((ko + q * 8) * 2) ^ rsw;
                    bf16x8 a = *(const bf16x8*)(LB + r * 1024 + abo);
                    gi = __builtin_amdgcn_mfma_f32_16x16x32_bf16(a, *(const bf16x8*)(p1a + ko), gi, 0, 0, 0);
                    go = __builtin_amdgcn_mfma_f32_16x16x32_bf16(a, *(const bf16x8*)(p1b + ko), go, 0, 0, 0);
                    gf = __builtin_amdgcn_mfma_f32_16x16x32_bf16(a, *(const bf16x8*)(p1c + ko), gf, 0, 0, 0);
                    gz = __builtin_amdgcn_mfma_f32_16x16x32_bf16(a, *(const bf16x8*)(p1d + ko), gz, 0, 0, 0);
                }
                float siR[4], soR[4], sfR[4];
#pragma unroll
                for (int i2 = 0; i2 < 4; ++i2) {
                    int slot = q * 4 + i2;
                    int ni = ndl[slot];
                    siR[i2] = 0.f; soR[i2] = 0.f; sfR[i2] = 0.f;
                    if (ni < 0) continue;
                    size_t nb = (size_t)ni * 512;
                    float si = sigf(pqi[i2] + gi[i2] + ba);
                    float so = sigf(pqo[i2] + go[i2] + bb);
                    float sf = sigf(pqf[i2] + gf[i2] + bc);
                    float zg = sigf(pqz[i2] + gz[i2] + bd);
                    siR[i2] = si; soR[i2] = so; sfR[i2] = sf;
                    cst16(&ZB[nb + col], f2bf(zg * tanhq(ppc[i2])));
                }
                ++mtgt; mini_bar(MF, cgi, mtgt);
                // ---------- ch s2: stage ZT (plain; written pre-mini-bar), u gate -> c,h ----------
                for (int e = tid; e < 1024; e += 512) {
                    int slot = e >> 6, c8 = e & 63;
                    int nd = ndl[slot]; int nn = (nd < 0) ? NN : nd;
                    int boff = slot * 1024 + ((c8 * 16) ^ ((slot & 7) << 4));
                    *(bf16x8*)(LB + boff) = *(const bf16x8*)(ZB + (size_t)nn * 512 + c8 * 8);
                }
                __syncthreads();
                f32x4 a0 = {}, a1 = {}, a2 = {}, a3 = {};
#pragma unroll 4
                for (int ko = 0; ko < 128; ko += 32) {
                    int b0 = ((ko + q * 8) * 2) ^ rsw;
                    int b1 = ((ko + 128 + q * 8) * 2) ^ rsw;
                    int b2 = ((ko + 256 + q * 8) * 2) ^ rsw;
                    int b3 = ((ko + 384 + q * 8) * 2) ^ rsw;
                    a0 = __builtin_amdgcn_mfma_f32_16x16x32_bf16(*(const bf16x8*)(LB + r * 1024 + b0),
                                                                 *(const bf16x8*)(p2a + ko), a0, 0, 0, 0);
                    a1 = __builtin_amdgcn_mfma_f32_16x16x32_bf16(*(const bf16x8*)(LB + r * 1024 + b1),
                                                                 *(const bf16x8*)(p2a + 128 + ko), a1, 0, 0, 0);
                    a2 = __builtin_amdgcn_mfma_f32_16x16x32_bf16(*(const bf16x8*)(LB + r * 1024 + b2),
                                                                 *(const bf16x8*)(p2a + 256 + ko), a2, 0, 0, 0);
                    a3 = __builtin_amdgcn_mfma_f32_16x16x32_bf16(*(const bf16x8*)(LB + r * 1024 + b3),
                                                                 *(const bf16x8*)(p2a + 384 + ko), a3, 0, 0, 0);
                }
                f32x4 auv = (a0 + a1) + (a2 + a3);
#pragma unroll
                for (int i2 = 0; i2 < 4; ++i2) {
                    int slot = q * 4 + i2;
                    int ni = ndl[slot];
                    if (ni < 0) continue;
                    size_t nb = (size_t)ni * 512;
                    float uu = tanhq(pqu[i2] + auv[i2] + be);
                    float cc = siR[i2] * uu + sfR[i2] * ppc[i2];
                    float h = soR[i2] * tanhq(cc);
                    cstf(&Call[nb + col], cc);
                    cst16(&HB[nb + col], f2bf(h));
                }
            }
        }
        ++tgt; plane_bar(BAR, z, bid, tgt);
    }
}

// ---------------- fallback per-level kernels (round-3, verified) ----------------
__global__ __launch_bounds__(512) void comb_s1(
    int iter,
    const int* __restrict__ order, const int* __restrict__ lvl, const int* __restrict__ parent,
    float* acc_h, const float* __restrict__ acc_fc, const float* __restrict__ acc_zc,
    const u16* __restrict__ Wio_o, const u16* __restrict__ Wio_n,
    const u16* __restrict__ Wum_o, const u16* __restrict__ Wum_n,
    const u16* __restrict__ bio, const u16* __restrict__ bum,
    const u16* __restrict__ px,
    const u16* __restrict__ HB, const float* __restrict__ Call,
    const u16* __restrict__ Wh_o, const u16* __restrict__ Wh_n,
    const u16* __restrict__ bh,
    const u16* __restrict__ qx, u16* __restrict__ ZB,
    float* __restrict__ G,
    void* __restrict__ outv, const int* __restrict__ fcnt)
{
    __shared__ __align__(16) u16 LS[16384];
    __shared__ int ndl[16], pl[16];
    bool isbf = (*fcnt > 2048);
    int tid = threadIdx.x;
    int w = tid >> 6, lane = tid & 63;
    int r = lane & 15, q = lane >> 4;
    int rsw = (r & 7) << 4;
    int col = (blockIdx.x * 8 + w) * 16 + r;
    u16* Gh = (u16*)G;
    char* LB = (char*)LS;
    int Dmax = lvl[80];
    int d = blockIdx.z ? iter : (Dmax - 1 - iter);
    if (d < 0 || d >= Dmax) return;
    int start = lvl[d], cnt = lvl[d + 1] - start;
    if (cnt <= 0) return;
    int ntiles = (cnt + 15) >> 4;

    if (blockIdx.z == 0) {
        const u16* Wio = isbf ? Wio_o : Wio_n;
        const u16* Wum = isbf ? Wum_o : Wum_n;
        const u16* pbi = Wio + (size_t)col * 512 + q * 8;
        const u16* pbo = Wio + (size_t)(512 + col) * 512 + q * 8;
        const u16* pbu = Wum + (size_t)col * 512 + q * 8;
        for (int tile = blockIdx.y; tile < ntiles; tile += GY) {
            __syncthreads();
            if (tid < 16) {
                int tr = tile * 16 + tid;
                int nd = (tr < cnt) ? order[start + tr] : -1;
                ndl[tid] = nd;
                pl[tid] = (nd >= 0) ? parent[nd] : NN;
            }
            __syncthreads();
            for (int e = tid; e < 1024; e += 512) {
                int slot = e >> 6, c8 = e & 63;
                int nd = ndl[slot]; int nn = (nd < 0) ? NN : nd;
                int boff = slot * 1024 + ((c8 * 16) ^ ((slot & 7) << 4));
                *(bf16x8*)(LB + boff) = cvt8(acc_h + (size_t)nn * 512 + c8 * 8);
                *(bf16x8*)(LB + 16384 + boff) = cvt8(acc_zc + (size_t)nn * 512 + c8 * 8);
            }
            __syncthreads();
            f32x4 ai = {}, ao = {}, au = {};
#pragma unroll 4
            for (int ko = 0; ko < 512; ko += 32) {
                int abo = ((ko + q * 8) * 2) ^ rsw;
                bf16x8 ah = *(const bf16x8*)(LB + r * 1024 + abo);
                bf16x8 az = *(const bf16x8*)(LB + 16384 + r * 1024 + abo);
                ai = __builtin_amdgcn_mfma_f32_16x16x32_bf16(ah, *(const bf16x8*)(pbi + ko), ai, 0, 0, 0);
                ao = __builtin_amdgcn_mfma_f32_16x16x32_bf16(ah, *(const bf16x8*)(pbo + ko), ao, 0, 0, 0);
                au = __builtin_amdgcn_mfma_f32_16x16x32_bf16(az, *(const bf16x8*)(pbu + ko), au, 0, 0, 0);
            }
            float bi_ = bfu(bio[col]), bo_ = bfu(bio[512 + col]), bu_ = bfu(bum[col]);
#pragma unroll
            for (int i2 = 0; i2 < 4; ++i2) {
                int slot = q * 4 + i2;
                int ni = ndl[slot];
                if (ni < 0) continue;
                int p = pl[slot];
                size_t pxb = (size_t)ni * PXC, nb = (size_t)ni * 512;
                float ig = sigf(bfu(px[pxb + col]) + ai[i2] + bi_);
                float og = sigf(bfu(px[pxb + 1024 + col]) + ao[i2] + bo_);
                float uu = tanhq(bfu(px[pxb + 2048 + col]) + au[i2] + bu_);
                float cc = ig * uu + acc_fc[nb + col];
                float h = og * tanhq(cc);
                G[(size_t)ni * 1536 + col] = cc;
                Gh[(size_t)ni * 3072 + 1024 + col] = f2bf(h);
                atomicAdd(&acc_h[(size_t)p * 512 + col], h);
                if (ni == 0) {
                    if (isbf) ((u16*)outv)[col] = f2bf(h);
                    else ((float*)outv)[col] = h;
                }
            }
        }
    } else {
        const u16* Wh = isbf ? Wh_o : Wh_n;
        const u16* pbi = Wh + (size_t)col * 512 + q * 8;
        const u16* pbo = Wh + (size_t)(512 + col) * 512 + q * 8;
        const u16* pbf = Wh + (size_t)(1024 + col) * 512 + q * 8;
        const u16* pbz = Wh + (size_t)(1536 + col) * 512 + q * 8;
        for (int tile = blockIdx.y; tile < ntiles; tile += GY) {
            __syncthreads();
            if (tid < 16) {
                int tr = tile * 16 + tid;
                int nd = (tr < cnt) ? order[start + tr] : -1;
                ndl[tid] = nd;
                pl[tid] = (nd >= 0) ? parent[nd] : NN;
            }
            __syncthreads();
            for (int e = tid; e < 1024; e += 512) {
                int slot = e >> 6, c8 = e & 63;
                int boff = slot * 1024 + ((c8 * 16) ^ ((slot & 7) << 4));
                *(bf16x8*)(LB + boff) = *(const bf16x8*)(HB + (size_t)pl[slot] * 512 + c8 * 8);
            }
            __syncthreads();
            f32x4 gi = {}, go = {}, gf = {}, gz = {};
#pragma unroll 4
            for (int ko = 0; ko < 512; ko += 32) {
                int abo = ((ko + q * 8) * 2) ^ rsw;
                bf16x8 a = *(const bf16x8*)(LB + r * 1024 + abo);
                gi = __builtin_amdgcn_mfma_f32_16x16x32_bf16(a, *(const bf16x8*)(pbi + ko), gi, 0, 0, 0);
                go = __builtin_amdgcn_mfma_f32_16x16x32_bf16(a, *(const bf16x8*)(pbo + ko), go, 0, 0, 0);
                gf = __builtin_amdgcn_mfma_f32_16x16x32_bf16(a, *(const bf16x8*)(pbf + ko), gf, 0, 0, 0);
                gz = __builtin_amdgcn_mfma_f32_16x16x32_bf16(a, *(const bf16x8*)(pbz + ko), gz, 0, 0, 0);
            }
            float bi_ = bfu(bh[col]), bo_ = bfu(bh[512 + col]);
            float bf_ = bfu(bh[1024 + col]), bz_ = bfu(bh[1536 + col]);
#pragma unroll
            for (int i2 = 0; i2 < 4; ++i2) {
                int slot = q * 4 + i2;
                int ni = ndl[slot];
                if (ni < 0) continue;
                int p = pl[slot];
                size_t qb = (size_t)ni * PXC, gb = (size_t)ni * 1536, nb = (size_t)ni * 512;
                float si = sigf(bfu(qx[qb + col]) + gi[i2] + bi_);
                float so = sigf(bfu(qx[qb + 512 + col]) + go[i2] + bo_);
                float sf = sigf(bfu(qx[qb + 1024 + col]) + gf[i2] + bf_);
                float zg = sigf(bfu(qx[qb + 1536 + col]) + gz[i2] + bz_);
                G[gb + col] = si;
                G[gb + 512 + col] = so;
                G[gb + 1024 + col] = sf;
                ZB[nb + col] = f2bf(zg * tanhq(Call[(size_t)p * 512 + col]));
            }
        }
    }
}

__global__ __launch_bounds__(512) void comb_s2(
    int iter,
    const int* __restrict__ order, const int* __restrict__ lvl, const int* __restrict__ parent,
    const u16* __restrict__ Wfz_o, const u16* __restrict__ Wfz_n,
    const u16* __restrict__ bfz,
    const u16* __restrict__ px,
    float* __restrict__ acc_fc, float* __restrict__ acc_zc,
    const u16* __restrict__ ZB, const u16* __restrict__ qx,
    const u16* __restrict__ Wum_o, const u16* __restrict__ Wum_n,
    const u16* __restrict__ bum,
    float* __restrict__ Call, u16* __restrict__ HB,
    float* __restrict__ G, const int* __restrict__ fcnt)
{
    __shared__ __align__(16) u16 LS[8192];
    __shared__ int ndl[16], pl[16];
    bool isbf = (*fcnt > 2048);
    int tid = threadIdx.x;
    int w = tid >> 6, lane = tid & 63;
    int r = lane & 15, q = lane >> 4;
    int rsw = (r & 7) << 4;
    int col = (blockIdx.x * 8 + w) * 16 + r;
    const u16* Gh = (const u16*)G;
    char* LB = (char*)LS;
    int Dmax = lvl[80];
    int d = blockIdx.z ? iter : (Dmax - 1 - iter);
    if (d < 0 || d >= Dmax) return;
    int start = lvl[d], cnt = lvl[d + 1] - start;
    if (cnt <= 0) return;
    int ntiles = (cnt + 15) >> 4;

    if (blockIdx.z == 0) {
        const u16* Wfz = isbf ? Wfz_o : Wfz_n;
        const u16* pbf = Wfz + (size_t)col * 512 + q * 8;
        const u16* pbz = Wfz + (size_t)(512 + col) * 512 + q * 8;
        for (int tile = blockIdx.y; tile < ntiles; tile += GY) {
            __syncthreads();
            if (tid < 16) {
                int tr = tile * 16 + tid;
                int nd = (tr < cnt) ? order[start + tr] : -1;
                ndl[tid] = nd;
                pl[tid] = (nd >= 0) ? parent[nd] : NN;
            }
            __syncthreads();
            for (int e = tid; e < 1024; e += 512) {
                int slot = e >> 6, c8 = e & 63;
                int nd = ndl[slot]; int nn = (nd < 0) ? NN : nd;
                int boff = slot * 1024 + ((c8 * 16) ^ ((slot & 7) << 4));
                *(bf16x8*)(LB + boff) = *(const bf16x8*)(Gh + (size_t)nn * 3072 + 1024 + c8 * 8);
            }
            __syncthreads();
            f32x4 af0 = {}, af1 = {}, az0 = {}, az1 = {};
#pragma unroll 4
            for (int ko = 0; ko < 256; ko += 32) {
                int ab0 = ((ko + q * 8) * 2) ^ rsw;
                int ab1 = ((ko + 256 + q * 8) * 2) ^ rsw;
                bf16x8 h0 = *(const bf16x8*)(LB + r * 1024 + ab0);
                bf16x8 h1 = *(const bf16x8*)(LB + r * 1024 + ab1);
                af0 = __builtin_amdgcn_mfma_f32_16x16x32_bf16(h0, *(const bf16x8*)(pbf + ko), af0, 0, 0, 0);
                az0 = __builtin_amdgcn_mfma_f32_16x16x32_bf16(h0, *(const bf16x8*)(pbz + ko), az0, 0, 0, 0);
                af1 = __builtin_amdgcn_mfma_f32_16x16x32_bf16(h1, *(const bf16x8*)(pbf + 256 + ko), af1, 0, 0, 0);
                az1 = __builtin_amdgcn_mfma_f32_16x16x32_bf16(h1, *(const bf16x8*)(pbz + 256 + ko), az1, 0, 0, 0);
            }
            f32x4 af = af0 + af1, az = az0 + az1;
            float bf_ = bfu(bfz[col]), bz_ = bfu(bfz[512 + col]);
#pragma unroll
            for (int i2 = 0; i2 < 4; ++i2) {
                int slot = q * 4 + i2;
                int ni = ndl[slot];
                if (ni < 0) continue;
                int p = pl[slot];
                size_t pb = (size_t)p * 512, ppx = (size_t)p * PXC;
                float cT = G[(size_t)ni * 1536 + col];
                float f = sigf(bfu(px[ppx + 512 + col]) + af[i2] + bf_);
                atomicAdd(&acc_fc[pb + col], f * cT);
                float zf = sigf(bfu(px[ppx + 1536 + col]) + az[i2] + bz_);
                atomicAdd(&acc_zc[pb + col], zf * tanhq(cT));
            }
        }
    } else {
        const u16* Wum = isbf ? Wum_o : Wum_n;
        const u16* pbu = Wum + (size_t)col * 512 + q * 8;
        for (int tile = blockIdx.y; tile < ntiles; tile += GY) {
            __syncthreads();
            if (tid < 16) {
                int tr = tile * 16 + tid;
                int nd = (tr < cnt) ? order[start + tr] : -1;
                ndl[tid] = nd;
                pl[tid] = (nd >= 0) ? parent[nd] : NN;
            }
            __syncthreads();
            for (int e = tid; e < 1024; e += 512) {
                int slot = e >> 6, c8 = e & 63;
                int nd = ndl[slot]; int nn = (nd < 0) ? NN : nd;
                int boff = slot * 1024 + ((c8 * 16) ^ ((slot & 7) << 4));
                *(bf16x8*)(LB + boff) = *(const bf16x8*)(ZB + (size_t)nn * 512 + c8 * 8);
            }
            __syncthreads();
            f32x4 a0 = {}, a1 = {}, a2 = {}, a3 = {};
#pragma unroll 4
            for (int ko = 0; ko < 128; ko += 32) {
                int b0 = ((ko + q * 8) * 2) ^ rsw;
                int b1 = ((ko + 128 + q * 8) * 2) ^ rsw;
                int b2 = ((ko + 256 + q * 8) * 2) ^ rsw;
                int b3 = ((ko + 384 + q * 8) * 2) ^ rsw;
                a0 = __builtin_amdgcn_mfma_f32_16x16x32_bf16(*(const bf16x8*)(LB + r * 1024 + b0),
                                                             *(const bf16x8*)(pbu + ko), a0, 0, 0, 0);
                a1 = __builtin_amdgcn_mfma_f32_16x16x32_bf16(*(const bf16x8*)(LB + r * 1024 + b1),
                                                             *(const bf16x8*)(pbu + 128 + ko), a1, 0, 0, 0);
                a2 = __builtin_amdgcn_mfma_f32_16x16x32_bf16(*(const bf16x8*)(LB + r * 1024 + b2),
                                                             *(const bf16x8*)(pbu + 256 + ko), a2, 0, 0, 0);
                a3 = __builtin_amdgcn_mfma_f32_16x16x32_bf16(*(const bf16x8*)(LB + r * 1024 + b3),
                                                             *(const bf16x8*)(pbu + 384 + ko), a3, 0, 0, 0);
            }
            f32x4 au = (a0 + a1) + (a2 + a3);
            float bu_ = bfu(bum[col]);
#pragma unroll
            for (int i2 = 0; i2 < 4; ++i2) {
                int slot = q * 4 + i2;
                int ni = ndl[slot];
                if (ni < 0) continue;
                int p = pl[slot];
                size_t qb = (size_t)ni * PXC, gb = (size_t)ni * 1536, nb = (size_t)ni * 512;
                float uu = tanhq(bfu(qx[qb + 2048 + col]) + au[i2] + bu_);
                float si = G[gb + col];
                float so = G[gb + 512 + col];
                float sf = G[gb + 1024 + col];
                float pc = Call[(size_t)p * 512 + col];
                float cc = si * uu + sf * pc;
                float h = so * tanhq(cc);
                Call[nb + col] = cc;
                HB[nb + col] = f2bf(h);
            }
        }
    }
}

// ---------------- final max reduce ----------------
__global__ __launch_bounds__(256) void k_maxA(const u16* __restrict__ HB, float* __restrict__ pmax) {
    int b = blockIdx.x, t = threadIdx.x;
    float m1 = -1e30f, m2 = -1e30f;
    for (int rr = b * 128; rr < b * 128 + 128; ++rr) {
        m1 = fmaxf(m1, bfu(HB[(size_t)rr * 512 + t]));
        m2 = fmaxf(m2, bfu(HB[(size_t)rr * 512 + t + 256]));
    }
    pmax[(size_t)b * 512 + t] = m1; pmax[(size_t)b * 512 + t + 256] = m2;
}
__global__ void k_maxB(const float* __restrict__ pmax, void* __restrict__ outv,
                       const int* __restrict__ fcnt) {
    int j = threadIdx.x;
    float m = -1e30f;
    for (int b = 0; b < 64; ++b) m = fmaxf(m, pmax[(size_t)b * 512 + j]);
    bool isbf = (*fcnt > 2048);
    if (isbf) ((u16*)outv)[512 + j] = f2bf(m);
    else ((float*)outv)[512 + j] = m;
}

__global__ void k_wsfail(u16* out) {
    int i = blockIdx.x * 256 + threadIdx.x;
    if (i < 1024) out[i] = f2bf(12345.f);
}

// ---------------- launch ----------------
extern "C" void kernel_launch(void* const* d_in, const int* in_sizes, int n_in,
                              void* d_out, int out_size, void* d_ws, size_t ws_size,
                              hipStream_t stream) {
    char* base = (char*)d_ws;
    u16* px = (u16*)(base + OFF_PX);
    u16* qx = (u16*)(base + OFF_QX);
    float* acc_h = (float*)(base + OFF_ACCH);
    float* acc_fc = (float*)(base + OFF_ACCF);
    float* acc_zc = (float*)(base + OFF_ACCZ);
    float* Call = (float*)(base + OFF_C);
    u16* HB = (u16*)(base + OFF_HB);
    u16* ZB = (u16*)(base + OFF_ZB);
    float* G = (float*)(base + OFF_G);
    u16* NGI = (u16*)(base + OFF_G);
    u16* NW = (u16*)(base + OFF_NW);
    int* depth = (int*)(base + OFF_DEPTH);
    int* order = (int*)(base + OFF_ORDER);
    int* counts = (int*)(base + OFF_MISC);
    int* fcnt = counts + 128;
    int* pcnt = counts + 129;
    int* lvl = (int*)(base + OFF_LVL);
    u16* NB = (u16*)(base + OFF_NB);
    int* pnorm = (int*)(base + OFF_PN);
    float* pmax = (float*)(base + OFF_PMAX);
    u32* BAR = (u32*)(base + OFF_BAR);

    const u16* in_bf   = (const u16*)d_in[0];
    const u16* csWx_o  = (const u16*)d_in[2];
    const u16* csWio_o = (const u16*)d_in[4];
    const u16* csWfz_o = (const u16*)d_in[6];
    const u16* csWum_o = (const u16*)d_in[8];
    const u16* chWx_o  = (const u16*)d_in[10];
    const u16* chWh_o  = (const u16*)d_in[12];
    const u16* chWum_o = (const u16*)d_in[14];

    if (ws_size < WS_TOTAL) { k_wsfail<<<4, 256, 0, stream>>>((u16*)d_out); return; }

    hipMemsetAsync(base + OFF_MISC, 0, 1024, stream);
    hipMemsetAsync(base + OFF_ACCH, 0, 3 * SZ_ACC, stream);   // acc_h/fc/zc (+ sentinel rows)

    // dtype detect + barrier zero + fused setup
    k_detect<<<32, 256, 0, stream>>>((const u32*)d_in[0], (const u32*)d_in[1], fcnt, pcnt, BAR);
    k_pnorm_depth<<<32, 256, 0, stream>>>((const u32*)d_in[1], pcnt, pnorm, depth, HB, Call);
    k_levels<<<1, 1024, 0, stream>>>(depth, lvl, order);

    NormSrcs srcs;
    srcs.p[0] = d_in[0];  srcs.p[1] = d_in[2];  srcs.p[2] = d_in[10]; srcs.p[3] = d_in[4];
    srcs.p[4] = d_in[6];  srcs.p[5] = d_in[8];  srcs.p[6] = d_in[12]; srcs.p[7] = d_in[14];
    srcs.p[8] = d_in[3];  srcs.p[9] = d_in[5];  srcs.p[10] = d_in[7]; srcs.p[11] = d_in[9];
    srcs.p[12] = d_in[11]; srcs.p[13] = d_in[13]; srcs.p[14] = d_in[15];
    k_norm_all<<<2048, 256, 0, stream>>>(srcs, NGI, NW, NB, fcnt);

    // input projections — 512-thread blocks, 8 waves sharing one A-tile (2x occupancy)
    dim3 gg(PXC / 512, NN / 64, 2);
    k_gemm_in<<<gg, 512, 0, stream>>>(in_bf, NGI,
                                      csWx_o, NW + NW_CSWX, chWx_o, NW + NW_CHWX,
                                      NB + NB_CSBX, NB + NB_CHBX, px, qx, fcnt);

    // persistent level loop (round-13 verified mega9); fallback: per-level kernels
    {
        const u16* nWio = NW + NW_CSWIO; const u16* nWum = NW + NW_CSWUM;
        const u16* nWfz = NW + NW_CSWFZ; const u16* nWh = NW + NW_CHWH;
        const u16* nWu2 = NW + NW_CHWUM;
        const u16* b_io = NB + NB_CSBIO; const u16* b_um = NB + NB_CSBUM;
        const u16* b_fz = NB + NB_CSBFZ; const u16* b_h = NB + NB_CHBH;
        const u16* b_u2 = NB + NB_CHBUM;
        const int* order_c = order; const int* lvl_c = lvl; const int* par_c = pnorm;
        const u16* px_c = px; const u16* qx_c = qx;
        void* outp = d_out; const int* fcnt_c = fcnt;
        u32* bar_c = BAR;
        void* margs[] = {
            (void*)&order_c, (void*)&lvl_c, (void*)&par_c,
            (void*)&acc_h, (void*)&acc_fc, (void*)&acc_zc,
            (void*)&csWio_o, (void*)&nWio, (void*)&csWum_o, (void*)&nWum,
            (void*)&csWfz_o, (void*)&nWfz,
            (void*)&b_io, (void*)&b_um, (void*)&b_fz,
            (void*)&px_c, (void*)&HB, (void*)&Call,
            (void*)&chWh_o, (void*)&nWh, (void*)&chWum_o, (void*)&nWu2,
            (void*)&b_h, (void*)&b_u2,
            (void*)&qx_c, (void*)&ZB, (void*)&G,
            (void*)&outp, (void*)&fcnt_c, (void*)&bar_c
        };
        hipError_t ce = hipLaunchCooperativeKernel((const void*)comb_mega9,
                                                   dim3(256), dim3(512), margs, 0, stream);
        if (ce != hipSuccess) {
            (void)hipGetLastError();
            dim3 gl(4, GY, 2);
            for (int i = 0; i < MAXD; ++i) {
                comb_s1<<<gl, 512, 0, stream>>>(i, order, lvl, pnorm,
                                                acc_h, acc_fc, acc_zc,
                                                csWio_o, NW + NW_CSWIO, csWum_o, NW + NW_CSWUM,
                                                NB + NB_CSBIO, NB + NB_CSBUM, px,
                                                HB, Call, chWh_o, NW + NW_CHWH, NB + NB_CHBH,
                                                qx, ZB, G, d_out, fcnt);
                comb_s2<<<gl, 512, 0, stream>>>(i, order, lvl, pnorm,
                                                csWfz_o, NW + NW_CSWFZ, NB + NB_CSBFZ, px,
                                                acc_fc, acc_zc,
                                                ZB, qx, chWum_o, NW + NW_CHWUM, NB + NB_CHBUM,
                                                Call, HB, G, fcnt);
            }
        }
    }

    // brep
    k_maxA<<<64, 256, 0, stream>>>(HB, pmax);
    k_maxB<<<1, 512, 0, stream>>>(pmax, d_out, fcnt);
}